// Round 1
// baseline (164822.375 us; speedup 1.0000x reference)
//
#include <hip/hip_runtime.h>

// LSTM decoder (B=16,T=1024,CI=512,AR=256,H=1024,DO=80) for MI355X.
// Plan: precompute prenet + x@Wih0^T as parallel bf16 MFMA GEMMs; run the
// 1024-step recurrence in ONE persistent kernel (256 WGs x 256 thr, 1 WG/CU,
// recurrent weights LDS-resident in bf16) with a custom all-to-all flag
// barrier (4 grid syncs per step); final out-projection GEMM afterwards.

typedef unsigned short u16;
typedef short bf16x8 __attribute__((ext_vector_type(8)));
typedef float f32x4 __attribute__((ext_vector_type(4)));

#define MFMA16(a, b, c) __builtin_amdgcn_mfma_f32_16x16x32_bf16((a), (b), (c), 0, 0, 0)

__device__ __forceinline__ u16 f2bf(float x) {
  unsigned u = __float_as_uint(x);
  return (u16)((u + 0x7fffu + ((u >> 16) & 1u)) >> 16);  // RNE
}
__device__ __forceinline__ float bf2f(u16 h) { return __uint_as_float(((unsigned)h) << 16); }
__device__ __forceinline__ float sigf(float x) { return 1.f / (1.f + __expf(-x)); }

// ---------------- prep kernels ----------------
__global__ __launch_bounds__(256) void cvt(const float* __restrict__ s, u16* __restrict__ d, int n) {
  int i = (blockIdx.x * 256 + threadIdx.x) * 4;
  if (i < n) {
    float4 v = *(const float4*)(s + i);
    unsigned lo = (unsigned)f2bf(v.x) | ((unsigned)f2bf(v.y) << 16);
    unsigned hi = (unsigned)f2bf(v.z) | ((unsigned)f2bf(v.w) << 16);
    *(uint2*)(d + i) = make_uint2(lo, hi);
  }
}

// Wpre1 (256x80) -> bf16 padded to (256x96) so prenet GEMM K is a mult of 32.
__global__ __launch_bounds__(256) void cvt_wpre1(const float* __restrict__ s, u16* __restrict__ d) {
  int i = blockIdx.x * 256 + threadIdx.x;  // < 256*96
  int r = i / 96, c = i - r * 96;
  d[i] = (c < 80) ? f2bf(s[r * 80 + c]) : (u16)0;
}

__global__ __launch_bounds__(256) void bsum(const float* __restrict__ a, const float* __restrict__ b,
                                            float* __restrict__ o) {
  int i = blockIdx.x * 256 + threadIdx.x;
  if (i < 4096) o[i] = a[i] + b[i];
}

// prev[t*16+b][c] = t==0 ? 0 : (targets[b][t-1][c]-mean)/scale, padded K=96
__global__ __launch_bounds__(256) void pack_prev(const float* __restrict__ tg, const float* __restrict__ mean,
                                                 const float* __restrict__ scale, u16* __restrict__ prevp) {
  int i = blockIdx.x * 256 + threadIdx.x;  // < 16384*96
  int row = i / 96, c = i - row * 96;
  int t = row >> 4, b = row & 15;
  float v = 0.f;
  if (c < 80 && t > 0) v = (tg[((size_t)b * 1024 + (t - 1)) * 80 + c] - mean[c]) / scale[c];
  prevp[i] = f2bf(v);
}

// x_all[t*16+b][0:512] = bf16(cond[b][t][:])   (x_all row stride 768)
__global__ __launch_bounds__(256) void pack_cond(const float* __restrict__ cond, u16* __restrict__ xall) {
  int i = (blockIdx.x * 256 + threadIdx.x) * 4;  // < 16384*512
  int row = i >> 9, c = i & 511;
  int t = row >> 4, b = row & 15;
  float4 v = *(const float4*)(cond + ((size_t)b * 1024 + t) * 512 + c);
  unsigned lo = (unsigned)f2bf(v.x) | ((unsigned)f2bf(v.y) << 16);
  unsigned hi = (unsigned)f2bf(v.z) | ((unsigned)f2bf(v.w) << 16);
  *(uint2*)(xall + (size_t)row * 768 + c) = make_uint2(lo, hi);
}

// ---------------- generic bf16 GEMM: C = act(A @ B^T + bias) ----------------
// A (M,K) bf16 row-major, B (N,K) bf16 row-major, C (M,N) bf16.
// 64x64 tile, 4 waves (2x2), K-chunk 32, LDS stride 40 (bank-conflict pad).
__global__ __launch_bounds__(256) void gemm_bt(const u16* __restrict__ A, int lda, const u16* __restrict__ B,
                                               int ldb, u16* __restrict__ C, int ldc,
                                               const float* __restrict__ bias, int K, int relu) {
  __shared__ u16 As[64 * 40];
  __shared__ u16 Bs[64 * 40];
  const int tid = threadIdx.x, lane = tid & 63, wv = tid >> 6;
  const int wr = wv >> 1, wc = wv & 1;
  const int m0 = blockIdx.x * 64, n0 = blockIdx.y * 64;
  const int lr = tid >> 2, lc = (tid & 3) * 8;
  f32x4 z = {0.f, 0.f, 0.f, 0.f};
  f32x4 acc[2][2] = {{z, z}, {z, z}};
  const u16* Ap = A + (size_t)(m0 + lr) * lda + lc;
  const u16* Bp = B + (size_t)(n0 + lr) * ldb + lc;
  for (int k0 = 0; k0 < K; k0 += 32) {
    int4 av = *(const int4*)(Ap + k0);
    int4 bv = *(const int4*)(Bp + k0);
    __syncthreads();
    *(int4*)(As + lr * 40 + lc) = av;
    *(int4*)(Bs + lr * 40 + lc) = bv;
    __syncthreads();
#pragma unroll
    for (int mi = 0; mi < 2; mi++) {
      bf16x8 af = *(const bf16x8*)(As + (wr * 32 + mi * 16 + (lane & 15)) * 40 + (lane >> 4) * 8);
#pragma unroll
      for (int ni = 0; ni < 2; ni++) {
        bf16x8 bf = *(const bf16x8*)(Bs + (wc * 32 + ni * 16 + (lane & 15)) * 40 + (lane >> 4) * 8);
        acc[mi][ni] = MFMA16(af, bf, acc[mi][ni]);
      }
    }
  }
#pragma unroll
  for (int mi = 0; mi < 2; mi++)
#pragma unroll
    for (int ni = 0; ni < 2; ni++) {
      int n = n0 + wc * 32 + ni * 16 + (lane & 15);
      float bs = bias ? bias[n] : 0.f;
#pragma unroll
      for (int r = 0; r < 4; r++) {
        int m = m0 + wr * 32 + mi * 16 + (lane >> 4) * 4 + r;
        float x = acc[mi][ni][r] + bs;
        if (relu) x = fmaxf(x, 0.f);
        C[(size_t)m * ldc + n] = f2bf(x);
      }
    }
}

// ---------------- final projection: out[b][t][:] = zs[t*16+b] @ Wout^T + bout ----------------
__global__ __launch_bounds__(256) void out_proj(const u16* __restrict__ zs, const u16* __restrict__ Wb,
                                                const float* __restrict__ bout, float* __restrict__ out) {
  int wv = threadIdx.x >> 6, lane = threadIdx.x & 63;
  int tile = blockIdx.x * 4 + wv;  // 5120 tiles = 1024 m-tiles x 5 n-tiles
  int mt = tile / 5, nt = tile - mt * 5;
  int m0 = mt * 16, n0 = nt * 16;
  const u16* ap = zs + (size_t)(m0 + (lane & 15)) * 1024 + (lane >> 4) * 8;
  const u16* bp = Wb + (size_t)(n0 + (lane & 15)) * 1024 + (lane >> 4) * 8;
  f32x4 acc = {0.f, 0.f, 0.f, 0.f};
  for (int k = 0; k < 1024; k += 32) {
    bf16x8 a = *(const bf16x8*)(ap + k);
    bf16x8 b = *(const bf16x8*)(bp + k);
    acc = MFMA16(a, b, acc);
  }
  int n = n0 + (lane & 15);
  float bb = bout[n];
#pragma unroll
  for (int r = 0; r < 4; r++) {
    int m = m0 + (lane >> 4) * 4 + r;
    int t = m >> 4, b = m & 15;
    out[(size_t)b * 81920 + t * 80 + n] = acc[r] + bb;
  }
}

// ---------------- persistent recurrent kernel ----------------
struct RecP {
  const u16 *g0, *whh0b, *wih1b, *whh1b, *wp0b, *wp1b;
  const float *bih1, *bhh1, *bp0, *bp1, *lng0, *lnb0, *lng1, *lnb1;
  u16 *za, *zb, *h0, *h1, *zs;
  int* flags;
};

#define NWG 256
#define SLICE 1032  // 1024 + 8 pad (breaks LDS bank conflicts on b128 reads)
#define SMEM_BYTES 139904

// All-to-all flag barrier: WG w release-stores flags[w*32]=epoch; thread i
// polls flags[i*32]. __threadfence gives agent-scope wb/inv for cross-XCD
// coherence of the plain activation loads/stores (G16).
__device__ __forceinline__ void gbar(int* flags, int e, int w, int tid) {
  __threadfence();
  __syncthreads();
  if (tid == 0) __hip_atomic_store(flags + w * 32, e, __ATOMIC_RELEASE, __HIP_MEMORY_SCOPE_AGENT);
  while (__hip_atomic_load(flags + tid * 32, __ATOMIC_RELAXED, __HIP_MEMORY_SCOPE_AGENT) < e)
    __builtin_amdgcn_s_sleep(2);
  __syncthreads();
  __threadfence();
}

__global__ __launch_bounds__(256, 1) void recurrent(RecP p) {
  extern __shared__ char smem[];
  u16* whh0_s = (u16*)smem;               // 16 x SLICE
  u16* wih1_s = whh0_s + 16 * SLICE;
  u16* whh1_s = wih1_s + 16 * SLICE;
  u16* wp_s = whh1_s + 16 * SLICE;        // Wp0 slice (WG 64..127) / Wp1 (128..191)
  float* partial = (float*)(wp_s + 16 * SLICE);  // 4*256
  float* gates2 = partial + 1024;                // 256
  float* c0s = gates2 + 256;                     // 64 (cell state layer0: [jj*16+b])
  float* c1s = c0s + 64;                         // 64
  float* red1 = c1s + 64;                        // 256
  float* red2 = red1 + 256;                      // 256
  float* musig = red2 + 256;                     // 32

  const int w = blockIdx.x, tid = threadIdx.x, lane = tid & 63, wv = tid >> 6;

  // ---- stage weights into LDS (once). WG w owns hidden cols j = 4w..4w+3;
  // slice row nl = g*4+jj  ->  global gate col n = g*1024 + 4w + jj.
  {
    int nl = tid >> 4, kp = tid & 15;
    int gN = (nl >> 2) * 1024 + (w << 2) + (nl & 3);
#pragma unroll
    for (int i = 0; i < 8; i++) {
      int k = kp * 64 + i * 8;
      *(int4*)(whh0_s + nl * SLICE + k) = *(const int4*)(p.whh0b + (size_t)gN * 1024 + k);
      *(int4*)(wih1_s + nl * SLICE + k) = *(const int4*)(p.wih1b + (size_t)gN * 1024 + k);
      *(int4*)(whh1_s + nl * SLICE + k) = *(const int4*)(p.whh1b + (size_t)gN * 1024 + k);
    }
    if (w >= 64 && w < 192) {
      const u16* wp = (w < 128) ? p.wp0b : p.wp1b;
      int idx = (w < 128) ? (w - 64) : (w - 128);
#pragma unroll
      for (int i = 0; i < 8; i++) {
        int k = kp * 64 + i * 8;
        *(int4*)(wp_s + nl * SLICE + k) = *(const int4*)(wp + (size_t)(idx * 16 + nl) * 1024 + k);
      }
    }
    if (tid < 64) { c0s[tid] = 0.f; c1s[tid] = 0.f; }
  }
  __syncthreads();

  int ep = 1;
  for (int t = 0; t < 1024; ++t) {
    // ---------- S1: gates0 = G0[t] + za @ Whh0^T ; cell0 -> h0 ----------
    {
      const int bn = lane & 15, q = lane >> 4;
      f32x4 acc = {0.f, 0.f, 0.f, 0.f};
      const u16* zap = p.za + bn * 1024;
      const u16* wrow = whh0_s + bn * SLICE;
#pragma unroll
      for (int c = 0; c < 8; c++) {
        int k = (wv << 8) + (c << 5) + (q << 3);
        bf16x8 a = *(const bf16x8*)(zap + k);
        bf16x8 b = *(const bf16x8*)(wrow + k);
        acc = MFMA16(a, b, acc);
      }
      *(f32x4*)(partial + (wv << 8) + (bn << 4) + (q << 2)) = acc;
    }
    __syncthreads();
    {
      int nl = tid >> 4, b = tid & 15;
      float s = partial[(nl << 4) + b] + partial[256 + (nl << 4) + b] + partial[512 + (nl << 4) + b] +
                partial[768 + (nl << 4) + b];
      int n = (nl >> 2) * 1024 + (w << 2) + (nl & 3);
      s += bf2f(p.g0[(size_t)((t << 4) | b) * 4096 + n]);  // G0 already has bih0+bhh0
      gates2[(nl << 4) + b] = s;
    }
    __syncthreads();
    if (tid < 64) {
      int jj = tid >> 4, b = tid & 15;
      float xi = gates2[(jj) * 16 + b];
      float xf = gates2[(4 + jj) * 16 + b];
      float xg = gates2[(8 + jj) * 16 + b];
      float xo = gates2[(12 + jj) * 16 + b];
      float c = c0s[(jj << 4) + b];
      float cn = sigf(xf) * c + sigf(xi) * tanhf(xg);
      c0s[(jj << 4) + b] = cn;
      p.h0[b * 1024 + (w << 2) + jj] = f2bf(sigf(xo) * tanhf(cn));
    }
    gbar(p.flags, ep++, w, tid);

    // ---------- S2: za = tanh(LN(h0)*g+b @ Wp0^T + bp0)  (WGs 64..127) ----------
    if (w >= 64 && w < 128) {
      int idx = w - 64;
      {
        int b = tid >> 4, sg = tid & 15;
        float sm = 0.f, sq = 0.f;
        const u16* hp = p.h0 + b * 1024 + sg * 64;
#pragma unroll
        for (int i = 0; i < 8; i++) {
          bf16x8 hv = *(const bf16x8*)(hp + i * 8);
#pragma unroll
          for (int j = 0; j < 8; j++) { float x = bf2f((u16)hv[j]); sm += x; sq += x * x; }
        }
        red1[(b << 4) + sg] = sm;
        red2[(b << 4) + sg] = sq;
      }
      __syncthreads();
      if (tid < 16) {
        float s = 0.f, q = 0.f;
        for (int i = 0; i < 16; i++) { s += red1[(tid << 4) + i]; q += red2[(tid << 4) + i]; }
        float mu = s * (1.f / 1024.f);
        float var = q * (1.f / 1024.f) - mu * mu;
        musig[tid] = mu;
        musig[16 + tid] = rsqrtf(var + 1e-5f);
      }
      __syncthreads();
      {
        const int bn = lane & 15, q = lane >> 4;
        float mu = musig[bn], rs = musig[16 + bn];
        f32x4 acc = {0.f, 0.f, 0.f, 0.f};
#pragma unroll
        for (int c = 0; c < 8; c++) {
          int k = (wv << 8) + (c << 5) + (q << 3);
          bf16x8 hv = *(const bf16x8*)(p.h0 + bn * 1024 + k);
          float4 ga = *(const float4*)(p.lng0 + k);
          float4 gb = *(const float4*)(p.lng0 + k + 4);
          float4 ba = *(const float4*)(p.lnb0 + k);
          float4 bb = *(const float4*)(p.lnb0 + k + 4);
          bf16x8 a;
          a[0] = (short)f2bf((bf2f((u16)hv[0]) - mu) * rs * ga.x + ba.x);
          a[1] = (short)f2bf((bf2f((u16)hv[1]) - mu) * rs * ga.y + ba.y);
          a[2] = (short)f2bf((bf2f((u16)hv[2]) - mu) * rs * ga.z + ba.z);
          a[3] = (short)f2bf((bf2f((u16)hv[3]) - mu) * rs * ga.w + ba.w);
          a[4] = (short)f2bf((bf2f((u16)hv[4]) - mu) * rs * gb.x + bb.x);
          a[5] = (short)f2bf((bf2f((u16)hv[5]) - mu) * rs * gb.y + bb.y);
          a[6] = (short)f2bf((bf2f((u16)hv[6]) - mu) * rs * gb.z + bb.z);
          a[7] = (short)f2bf((bf2f((u16)hv[7]) - mu) * rs * gb.w + bb.w);
          bf16x8 b = *(const bf16x8*)(wp_s + bn * SLICE + k);
          acc = MFMA16(a, b, acc);
        }
        *(f32x4*)(partial + (wv << 8) + (bn << 4) + (q << 2)) = acc;
      }
      __syncthreads();
      {
        int nl = tid >> 4, b = tid & 15;
        float s = partial[(nl << 4) + b] + partial[256 + (nl << 4) + b] + partial[512 + (nl << 4) + b] +
                  partial[768 + (nl << 4) + b];
        s += p.bp0[idx * 16 + nl];
        p.za[b * 1024 + idx * 16 + nl] = f2bf(tanhf(s));
      }
    }
    gbar(p.flags, ep++, w, tid);

    // ---------- S3: gates1 = za @ Wih1^T + zb @ Whh1^T + b ; cell1 -> h1 ----------
    {
      const int bn = lane & 15, q = lane >> 4;
      f32x4 acc = {0.f, 0.f, 0.f, 0.f};
#pragma unroll
      for (int c = 0; c < 8; c++) {
        int k = (wv << 8) + (c << 5) + (q << 3);
        bf16x8 a1 = *(const bf16x8*)(p.za + bn * 1024 + k);
        bf16x8 b1 = *(const bf16x8*)(wih1_s + bn * SLICE + k);
        acc = MFMA16(a1, b1, acc);
        bf16x8 a2 = *(const bf16x8*)(p.zb + bn * 1024 + k);
        bf16x8 b2 = *(const bf16x8*)(whh1_s + bn * SLICE + k);
        acc = MFMA16(a2, b2, acc);
      }
      *(f32x4*)(partial + (wv << 8) + (bn << 4) + (q << 2)) = acc;
    }
    __syncthreads();
    {
      int nl = tid >> 4, b = tid & 15;
      float s = partial[(nl << 4) + b] + partial[256 + (nl << 4) + b] + partial[512 + (nl << 4) + b] +
                partial[768 + (nl << 4) + b];
      int n = (nl >> 2) * 1024 + (w << 2) + (nl & 3);
      s += p.bih1[n] + p.bhh1[n];
      gates2[(nl << 4) + b] = s;
    }
    __syncthreads();
    if (tid < 64) {
      int jj = tid >> 4, b = tid & 15;
      float xi = gates2[(jj) * 16 + b];
      float xf = gates2[(4 + jj) * 16 + b];
      float xg = gates2[(8 + jj) * 16 + b];
      float xo = gates2[(12 + jj) * 16 + b];
      float c = c1s[(jj << 4) + b];
      float cn = sigf(xf) * c + sigf(xi) * tanhf(xg);
      c1s[(jj << 4) + b] = cn;
      p.h1[b * 1024 + (w << 2) + jj] = f2bf(sigf(xo) * tanhf(cn));
    }
    gbar(p.flags, ep++, w, tid);

    // ---------- S4: zb = tanh(LN(h1)*g+b @ Wp1^T + bp1); zs[t]=zb  (WGs 128..191) ----------
    if (w >= 128 && w < 192) {
      int idx = w - 128;
      {
        int b = tid >> 4, sg = tid & 15;
        float sm = 0.f, sq = 0.f;
        const u16* hp = p.h1 + b * 1024 + sg * 64;
#pragma unroll
        for (int i = 0; i < 8; i++) {
          bf16x8 hv = *(const bf16x8*)(hp + i * 8);
#pragma unroll
          for (int j = 0; j < 8; j++) { float x = bf2f((u16)hv[j]); sm += x; sq += x * x; }
        }
        red1[(b << 4) + sg] = sm;
        red2[(b << 4) + sg] = sq;
      }
      __syncthreads();
      if (tid < 16) {
        float s = 0.f, q = 0.f;
        for (int i = 0; i < 16; i++) { s += red1[(tid << 4) + i]; q += red2[(tid << 4) + i]; }
        float mu = s * (1.f / 1024.f);
        float var = q * (1.f / 1024.f) - mu * mu;
        musig[tid] = mu;
        musig[16 + tid] = rsqrtf(var + 1e-5f);
      }
      __syncthreads();
      {
        const int bn = lane & 15, q = lane >> 4;
        float mu = musig[bn], rs = musig[16 + bn];
        f32x4 acc = {0.f, 0.f, 0.f, 0.f};
#pragma unroll
        for (int c = 0; c < 8; c++) {
          int k = (wv << 8) + (c << 5) + (q << 3);
          bf16x8 hv = *(const bf16x8*)(p.h1 + bn * 1024 + k);
          float4 ga = *(const float4*)(p.lng1 + k);
          float4 gb = *(const float4*)(p.lng1 + k + 4);
          float4 ba = *(const float4*)(p.lnb1 + k);
          float4 bb = *(const float4*)(p.lnb1 + k + 4);
          bf16x8 a;
          a[0] = (short)f2bf((bf2f((u16)hv[0]) - mu) * rs * ga.x + ba.x);
          a[1] = (short)f2bf((bf2f((u16)hv[1]) - mu) * rs * ga.y + ba.y);
          a[2] = (short)f2bf((bf2f((u16)hv[2]) - mu) * rs * ga.z + ba.z);
          a[3] = (short)f2bf((bf2f((u16)hv[3]) - mu) * rs * ga.w + ba.w);
          a[4] = (short)f2bf((bf2f((u16)hv[4]) - mu) * rs * gb.x + bb.x);
          a[5] = (short)f2bf((bf2f((u16)hv[5]) - mu) * rs * gb.y + bb.y);
          a[6] = (short)f2bf((bf2f((u16)hv[6]) - mu) * rs * gb.z + bb.z);
          a[7] = (short)f2bf((bf2f((u16)hv[7]) - mu) * rs * gb.w + bb.w);
          bf16x8 b = *(const bf16x8*)(wp_s + bn * SLICE + k);
          acc = MFMA16(a, b, acc);
        }
        *(f32x4*)(partial + (wv << 8) + (bn << 4) + (q << 2)) = acc;
      }
      __syncthreads();
      {
        int nl = tid >> 4, b = tid & 15;
        float s = partial[(nl << 4) + b] + partial[256 + (nl << 4) + b] + partial[512 + (nl << 4) + b] +
                  partial[768 + (nl << 4) + b];
        s += p.bp1[idx * 16 + nl];
        u16 u = f2bf(tanhf(s));
        p.zb[b * 1024 + idx * 16 + nl] = u;
        p.zs[(size_t)((t << 4) | b) * 1024 + idx * 16 + nl] = u;
      }
    }
    gbar(p.flags, ep++, w, tid);
  }
}

// ---------------- host ----------------
extern "C" void kernel_launch(void* const* d_in, const int* in_sizes, int n_in, void* d_out, int out_size,
                              void* d_ws, size_t ws_size, hipStream_t stream) {
  const float* cond = (const float*)d_in[0];
  const float* targets = (const float*)d_in[1];
  const float* tmean = (const float*)d_in[2];
  const float* tscale = (const float*)d_in[3];
  const float* Wpre1 = (const float*)d_in[4];
  const float* bpre1 = (const float*)d_in[5];
  const float* Wpre2 = (const float*)d_in[6];
  const float* bpre2 = (const float*)d_in[7];
  const float* Wih0 = (const float*)d_in[8];
  const float* Whh0 = (const float*)d_in[9];
  const float* bih0 = (const float*)d_in[10];
  const float* bhh0 = (const float*)d_in[11];
  const float* lng0 = (const float*)d_in[12];
  const float* lnb0 = (const float*)d_in[13];
  const float* Wp0 = (const float*)d_in[14];
  const float* bp0 = (const float*)d_in[15];
  const float* Wih1 = (const float*)d_in[16];
  const float* Whh1 = (const float*)d_in[17];
  const float* bih1 = (const float*)d_in[18];
  const float* bhh1 = (const float*)d_in[19];
  const float* lng1 = (const float*)d_in[20];
  const float* lnb1 = (const float*)d_in[21];
  const float* Wp1 = (const float*)d_in[22];
  const float* bp1 = (const float*)d_in[23];
  const float* Wout = (const float*)d_in[24];
  const float* bout = (const float*)d_in[25];

  char* ws = (char*)d_ws;
  int* flags = (int*)(ws + 0);                 // 32 KB (256 flags, 128B stride)
  u16* za = (u16*)(ws + 32768);                // 16x1024 bf16
  u16* zb = (u16*)(ws + 65536);
  u16* h0 = (u16*)(ws + 98304);
  u16* h1 = (u16*)(ws + 131072);
  float* b0 = (float*)(ws + 163840);           // bih0+bhh0
  u16* woutb = (u16*)(ws + 180224);
  u16* wpre1b = (u16*)(ws + 344064);
  u16* wpre2b = (u16*)(ws + 393216);
  u16* wih0b = (u16*)(ws + 524288);
  u16* whh0b = (u16*)(ws + 6815744);
  u16* wih1b = (u16*)(ws + 15204352);
  u16* whh1b = (u16*)(ws + 23592960);
  u16* wp0b = (u16*)(ws + 31981568);
  u16* wp1b = (u16*)(ws + 34078720);
  u16* prevp = (u16*)(ws + 36175872);          // (T*B,96)
  u16* hpre = (u16*)(ws + 39321600);           // (T*B,256)
  u16* xall = (u16*)(ws + 47710208);           // (T*B,768)
  u16* g0 = (u16*)(ws + 72876032);             // (T*B,4096) = x@Wih0^T + b  (134 MB)
  u16* zs = (u16*)(ws + 207093760);            // (T*B,1024)

  // zero barrier flags + initial za/zb state (ws is poisoned 0xAA each run)
  hipMemsetAsync(ws, 0, 98304, stream);

  cvt_wpre1<<<96, 256, 0, stream>>>(Wpre1, wpre1b);
  cvt<<<64, 256, 0, stream>>>(Wpre2, wpre2b, 65536);
  cvt<<<3072, 256, 0, stream>>>(Wih0, wih0b, 3145728);
  cvt<<<4096, 256, 0, stream>>>(Whh0, whh0b, 4194304);
  cvt<<<4096, 256, 0, stream>>>(Wih1, wih1b, 4194304);
  cvt<<<4096, 256, 0, stream>>>(Whh1, whh1b, 4194304);
  cvt<<<1024, 256, 0, stream>>>(Wp0, wp0b, 1048576);
  cvt<<<1024, 256, 0, stream>>>(Wp1, wp1b, 1048576);
  cvt<<<80, 256, 0, stream>>>(Wout, woutb, 81920);
  bsum<<<16, 256, 0, stream>>>(bih0, bhh0, b0);
  pack_prev<<<6144, 256, 0, stream>>>(targets, tmean, tscale, prevp);
  pack_cond<<<8192, 256, 0, stream>>>(cond, xall);

  // prenet: hpre = relu(prev@Wpre1^T); x_all[:,512:] = relu(hpre@Wpre2^T)
  gemm_bt<<<dim3(256, 4), 256, 0, stream>>>(prevp, 96, wpre1b, 96, hpre, 256, bpre1, 96, 1);
  gemm_bt<<<dim3(256, 4), 256, 0, stream>>>(hpre, 256, wpre2b, 256, xall + 512, 768, bpre2, 256, 1);
  // G0 = x_all @ Wih0^T + (bih0+bhh0)
  gemm_bt<<<dim3(256, 64), 256, 0, stream>>>(xall, 768, wih0b, 768, g0, 4096, b0, 768, 0);

  RecP rp;
  rp.g0 = g0; rp.whh0b = whh0b; rp.wih1b = wih1b; rp.whh1b = whh1b; rp.wp0b = wp0b; rp.wp1b = wp1b;
  rp.bih1 = bih1; rp.bhh1 = bhh1; rp.bp0 = bp0; rp.bp1 = bp1;
  rp.lng0 = lng0; rp.lnb0 = lnb0; rp.lng1 = lng1; rp.lnb1 = lnb1;
  rp.za = za; rp.zb = zb; rp.h0 = h0; rp.h1 = h1; rp.zs = zs;
  rp.flags = flags;

  hipFuncSetAttribute(reinterpret_cast<const void*>(recurrent), hipFuncAttributeMaxDynamicSharedMemorySize,
                      SMEM_BYTES);
  // 256 WGs, 1/CU (137 KB LDS forces it) -> all co-resident for the flag barrier.
  recurrent<<<dim3(256), dim3(256), SMEM_BYTES, stream>>>(rp);

  out_proj<<<1280, 256, 0, stream>>>(zs, woutb, bout, (float*)d_out);
}

// Round 2
// 36134.433 us; speedup vs baseline: 4.5614x; 4.5614x over previous
//
#include <hip/hip_runtime.h>

// LSTM decoder (B=16,T=1024,CI=512,AR=256,H=1024,DO=80) for MI355X.
// R2: fence-free persistent recurrence. All cross-WG data (h0/za/zb/h1,
// barrier flags) moves via sc0+sc1 (L1/L2-bypass, write-through to the
// memory-side Infinity Cache = device coherence point) inline-asm accesses.
// Barrier: vmcnt(0) drain -> flag store -> wave0 polls 256 packed flags with
// one dwordx4/lane. No __threadfence (R1's buffer_wbl2/inv = ~49us/barrier).

typedef unsigned short u16;
typedef short bf16x8 __attribute__((ext_vector_type(8)));
typedef float f32x4 __attribute__((ext_vector_type(4)));

#define MFMA16(a, b, c) __builtin_amdgcn_mfma_f32_16x16x32_bf16((a), (b), (c), 0, 0, 0)

__device__ __forceinline__ u16 f2bf(float x) {
  unsigned u = __float_as_uint(x);
  return (u16)((u + 0x7fffu + ((u >> 16) & 1u)) >> 16);  // RNE
}
__device__ __forceinline__ float bf2f(u16 h) { return __uint_as_float(((unsigned)h) << 16); }
__device__ __forceinline__ float sigf(float x) { return 1.f / (1.f + __expf(-x)); }

// 8x dwordx4 bypass loads + single vmcnt inside ONE asm block (uses of dst
// cannot be scheduled before the waitcnt). 64B stride (GEMM-fragment walk).
#define LOAD8_S(dst, base)                                                          \
  asm volatile("global_load_dwordx4 %0, %8, off sc0 sc1\n\t"                        \
               "global_load_dwordx4 %1, %8, off offset:64 sc0 sc1\n\t"              \
               "global_load_dwordx4 %2, %8, off offset:128 sc0 sc1\n\t"             \
               "global_load_dwordx4 %3, %8, off offset:192 sc0 sc1\n\t"             \
               "global_load_dwordx4 %4, %8, off offset:256 sc0 sc1\n\t"             \
               "global_load_dwordx4 %5, %8, off offset:320 sc0 sc1\n\t"             \
               "global_load_dwordx4 %6, %8, off offset:384 sc0 sc1\n\t"             \
               "global_load_dwordx4 %7, %8, off offset:448 sc0 sc1\n\t"             \
               "s_waitcnt vmcnt(0)"                                                 \
               : "=v"(dst[0]), "=v"(dst[1]), "=v"(dst[2]), "=v"(dst[3]),            \
                 "=v"(dst[4]), "=v"(dst[5]), "=v"(dst[6]), "=v"(dst[7])             \
               : "v"((const void*)(base))                                           \
               : "memory")

// contiguous 128B variant (LN row scan), 16B stride
#define LOAD8_C(dst, base)                                                          \
  asm volatile("global_load_dwordx4 %0, %8, off sc0 sc1\n\t"                        \
               "global_load_dwordx4 %1, %8, off offset:16 sc0 sc1\n\t"              \
               "global_load_dwordx4 %2, %8, off offset:32 sc0 sc1\n\t"              \
               "global_load_dwordx4 %3, %8, off offset:48 sc0 sc1\n\t"              \
               "global_load_dwordx4 %4, %8, off offset:64 sc0 sc1\n\t"              \
               "global_load_dwordx4 %5, %8, off offset:80 sc0 sc1\n\t"              \
               "global_load_dwordx4 %6, %8, off offset:96 sc0 sc1\n\t"              \
               "global_load_dwordx4 %7, %8, off offset:112 sc0 sc1\n\t"             \
               "s_waitcnt vmcnt(0)"                                                 \
               : "=v"(dst[0]), "=v"(dst[1]), "=v"(dst[2]), "=v"(dst[3]),            \
                 "=v"(dst[4]), "=v"(dst[5]), "=v"(dst[6]), "=v"(dst[7])             \
               : "v"((const void*)(base))                                           \
               : "memory")

__device__ __forceinline__ void gstore16(u16* p, u16 v) {
  unsigned vv = v;
  asm volatile("global_store_short %0, %1, off sc0 sc1" ::"v"((void*)p), "v"(vv) : "memory");
}
__device__ __forceinline__ void gstore32(int* p, int v) {
  asm volatile("global_store_dword %0, %1, off sc0 sc1" ::"v"((void*)p), "v"(v) : "memory");
}

// ---------------- prep kernels ----------------
__global__ __launch_bounds__(256) void cvt(const float* __restrict__ s, u16* __restrict__ d, int n) {
  int i = (blockIdx.x * 256 + threadIdx.x) * 4;
  if (i < n) {
    float4 v = *(const float4*)(s + i);
    unsigned lo = (unsigned)f2bf(v.x) | ((unsigned)f2bf(v.y) << 16);
    unsigned hi = (unsigned)f2bf(v.z) | ((unsigned)f2bf(v.w) << 16);
    *(uint2*)(d + i) = make_uint2(lo, hi);
  }
}

__global__ __launch_bounds__(256) void cvt_wpre1(const float* __restrict__ s, u16* __restrict__ d) {
  int i = blockIdx.x * 256 + threadIdx.x;  // < 256*96
  int r = i / 96, c = i - r * 96;
  d[i] = (c < 80) ? f2bf(s[r * 80 + c]) : (u16)0;
}

__global__ __launch_bounds__(256) void bsum(const float* __restrict__ a, const float* __restrict__ b,
                                            float* __restrict__ o) {
  int i = blockIdx.x * 256 + threadIdx.x;
  if (i < 4096) o[i] = a[i] + b[i];
}

__global__ __launch_bounds__(256) void pack_prev(const float* __restrict__ tg, const float* __restrict__ mean,
                                                 const float* __restrict__ scale, u16* __restrict__ prevp) {
  int i = blockIdx.x * 256 + threadIdx.x;  // < 16384*96
  int row = i / 96, c = i - row * 96;
  int t = row >> 4, b = row & 15;
  float v = 0.f;
  if (c < 80 && t > 0) v = (tg[((size_t)b * 1024 + (t - 1)) * 80 + c] - mean[c]) / scale[c];
  prevp[i] = f2bf(v);
}

__global__ __launch_bounds__(256) void pack_cond(const float* __restrict__ cond, u16* __restrict__ xall) {
  int i = (blockIdx.x * 256 + threadIdx.x) * 4;  // < 16384*512
  int row = i >> 9, c = i & 511;
  int t = row >> 4, b = row & 15;
  float4 v = *(const float4*)(cond + ((size_t)b * 1024 + t) * 512 + c);
  unsigned lo = (unsigned)f2bf(v.x) | ((unsigned)f2bf(v.y) << 16);
  unsigned hi = (unsigned)f2bf(v.z) | ((unsigned)f2bf(v.w) << 16);
  *(uint2*)(xall + (size_t)row * 768 + c) = make_uint2(lo, hi);
}

// ---------------- generic bf16 GEMM: C = act(A @ B^T + bias) ----------------
__global__ __launch_bounds__(256) void gemm_bt(const u16* __restrict__ A, int lda, const u16* __restrict__ B,
                                               int ldb, u16* __restrict__ C, int ldc,
                                               const float* __restrict__ bias, int K, int relu) {
  __shared__ u16 As[64 * 40];
  __shared__ u16 Bs[64 * 40];
  const int tid = threadIdx.x, lane = tid & 63, wv = tid >> 6;
  const int wr = wv >> 1, wc = wv & 1;
  const int m0 = blockIdx.x * 64, n0 = blockIdx.y * 64;
  const int lr = tid >> 2, lc = (tid & 3) * 8;
  f32x4 z = {0.f, 0.f, 0.f, 0.f};
  f32x4 acc[2][2] = {{z, z}, {z, z}};
  const u16* Ap = A + (size_t)(m0 + lr) * lda + lc;
  const u16* Bp = B + (size_t)(n0 + lr) * ldb + lc;
  for (int k0 = 0; k0 < K; k0 += 32) {
    int4 av = *(const int4*)(Ap + k0);
    int4 bv = *(const int4*)(Bp + k0);
    __syncthreads();
    *(int4*)(As + lr * 40 + lc) = av;
    *(int4*)(Bs + lr * 40 + lc) = bv;
    __syncthreads();
#pragma unroll
    for (int mi = 0; mi < 2; mi++) {
      bf16x8 af = *(const bf16x8*)(As + (wr * 32 + mi * 16 + (lane & 15)) * 40 + (lane >> 4) * 8);
#pragma unroll
      for (int ni = 0; ni < 2; ni++) {
        bf16x8 bf = *(const bf16x8*)(Bs + (wc * 32 + ni * 16 + (lane & 15)) * 40 + (lane >> 4) * 8);
        acc[mi][ni] = MFMA16(af, bf, acc[mi][ni]);
      }
    }
  }
#pragma unroll
  for (int mi = 0; mi < 2; mi++)
#pragma unroll
    for (int ni = 0; ni < 2; ni++) {
      int n = n0 + wc * 32 + ni * 16 + (lane & 15);
      float bs = bias ? bias[n] : 0.f;
#pragma unroll
      for (int r = 0; r < 4; r++) {
        int m = m0 + wr * 32 + mi * 16 + (lane >> 4) * 4 + r;
        float x = acc[mi][ni][r] + bs;
        if (relu) x = fmaxf(x, 0.f);
        C[(size_t)m * ldc + n] = f2bf(x);
      }
    }
}

// ---------------- final projection ----------------
__global__ __launch_bounds__(256) void out_proj(const u16* __restrict__ zs, const u16* __restrict__ Wb,
                                                const float* __restrict__ bout, float* __restrict__ out) {
  int wv = threadIdx.x >> 6, lane = threadIdx.x & 63;
  int tile = blockIdx.x * 4 + wv;  // 5120 tiles = 1024 m-tiles x 5 n-tiles
  int mt = tile / 5, nt = tile - mt * 5;
  int m0 = mt * 16, n0 = nt * 16;
  const u16* ap = zs + (size_t)(m0 + (lane & 15)) * 1024 + (lane >> 4) * 8;
  const u16* bp = Wb + (size_t)(n0 + (lane & 15)) * 1024 + (lane >> 4) * 8;
  f32x4 acc = {0.f, 0.f, 0.f, 0.f};
  for (int k = 0; k < 1024; k += 32) {
    bf16x8 a = *(const bf16x8*)(ap + k);
    bf16x8 b = *(const bf16x8*)(bp + k);
    acc = MFMA16(a, b, acc);
  }
  int n = n0 + (lane & 15);
  float bb = bout[n];
#pragma unroll
  for (int r = 0; r < 4; r++) {
    int m = m0 + (lane >> 4) * 4 + r;
    int t = m >> 4, b = m & 15;
    out[(size_t)b * 81920 + t * 80 + n] = acc[r] + bb;
  }
}

// ---------------- persistent recurrent kernel ----------------
struct RecP {
  const u16 *g0, *whh0b, *wih1b, *whh1b, *wp0b, *wp1b;
  const float *bih1, *bhh1, *bp0, *bp1, *lng0, *lnb0, *lng1, *lnb1;
  u16 *za, *zb, *h0, *h1, *zs;
  int* flags;
};

#define SLICE 1032  // 1024 + 8 pad
#define SMEM_BYTES 139904

// Fence-free all-to-all barrier. Data stores are sc0/sc1 write-through, so
// vmcnt(0) retirement == visible at the Infinity Cache (device coherence pt).
__device__ __forceinline__ void gbar(int* flags, int e, int w, int tid) {
  asm volatile("s_waitcnt vmcnt(0)" ::: "memory");
  __syncthreads();
  if (tid == 0) gstore32(flags + w, e);
  if (tid < 64) {
    const int4* fp = (const int4*)flags + tid;
    int4 f;
    do {
      asm volatile("global_load_dwordx4 %0, %1, off sc0 sc1\n\ts_waitcnt vmcnt(0)"
                   : "=v"(f)
                   : "v"((const void*)fp)
                   : "memory");
    } while (f.x < e || f.y < e || f.z < e || f.w < e);
  }
  __syncthreads();
}

__global__ __launch_bounds__(256, 1) void recurrent(RecP p) {
  extern __shared__ char smem[];
  u16* whh0_s = (u16*)smem;  // 16 x SLICE
  u16* wih1_s = whh0_s + 16 * SLICE;
  u16* whh1_s = wih1_s + 16 * SLICE;
  u16* wp_s = whh1_s + 16 * SLICE;               // Wp0 (WG 64..127) / Wp1 (128..191)
  float* partial = (float*)(wp_s + 16 * SLICE);  // 4*256
  float* gates2 = partial + 1024;                // 256
  float* c0s = gates2 + 256;                     // 64
  float* c1s = c0s + 64;                         // 64
  float* red1 = c1s + 64;                        // 256
  float* red2 = red1 + 256;                      // 256
  float* musig = red2 + 256;                     // 32

  const int w = blockIdx.x, tid = threadIdx.x, lane = tid & 63, wv = tid >> 6;

  // stage weights into LDS once: WG w owns hidden cols j = 4w..4w+3
  {
    int nl = tid >> 4, kp = tid & 15;
    int gN = (nl >> 2) * 1024 + (w << 2) + (nl & 3);
#pragma unroll
    for (int i = 0; i < 8; i++) {
      int k = kp * 64 + i * 8;
      *(int4*)(whh0_s + nl * SLICE + k) = *(const int4*)(p.whh0b + (size_t)gN * 1024 + k);
      *(int4*)(wih1_s + nl * SLICE + k) = *(const int4*)(p.wih1b + (size_t)gN * 1024 + k);
      *(int4*)(whh1_s + nl * SLICE + k) = *(const int4*)(p.whh1b + (size_t)gN * 1024 + k);
    }
    if (w >= 64 && w < 192) {
      const u16* wp = (w < 128) ? p.wp0b : p.wp1b;
      int idx = (w < 128) ? (w - 64) : (w - 128);
#pragma unroll
      for (int i = 0; i < 8; i++) {
        int k = kp * 64 + i * 8;
        *(int4*)(wp_s + nl * SLICE + k) = *(const int4*)(wp + (size_t)(idx * 16 + nl) * 1024 + k);
      }
    }
    if (tid < 64) { c0s[tid] = 0.f; c1s[tid] = 0.f; }
  }
  __syncthreads();

  int ep = 1;
  for (int t = 0; t < 1024; ++t) {
    // ---------- S1: gates0 = G0[t] + za @ Whh0^T ; cell0 -> h0 ----------
    {
      const int bn = lane & 15, q = lane >> 4;
      f32x4 acc = {0.f, 0.f, 0.f, 0.f};
      bf16x8 av[8];
      LOAD8_S(av, p.za + bn * 1024 + (wv << 8) + (q << 3));
      const u16* wrow = whh0_s + bn * SLICE;
#pragma unroll
      for (int c = 0; c < 8; c++) {
        int k = (wv << 8) + (c << 5) + (q << 3);
        bf16x8 b = *(const bf16x8*)(wrow + k);
        acc = MFMA16(av[c], b, acc);
      }
      *(f32x4*)(partial + (wv << 8) + (bn << 4) + (q << 2)) = acc;
    }
    __syncthreads();
    {
      int nl = tid >> 4, b = tid & 15;
      float s = partial[(nl << 4) + b] + partial[256 + (nl << 4) + b] + partial[512 + (nl << 4) + b] +
                partial[768 + (nl << 4) + b];
      int n = (nl >> 2) * 1024 + (w << 2) + (nl & 3);
      s += bf2f(p.g0[(size_t)((t << 4) | b) * 4096 + n]);  // G0 has bih0+bhh0
      gates2[(nl << 4) + b] = s;
    }
    __syncthreads();
    if (tid < 64) {
      int jj = tid >> 4, b = tid & 15;
      float xi = gates2[(jj)*16 + b];
      float xf = gates2[(4 + jj) * 16 + b];
      float xg = gates2[(8 + jj) * 16 + b];
      float xo = gates2[(12 + jj) * 16 + b];
      float c = c0s[(jj << 4) + b];
      float cn = sigf(xf) * c + sigf(xi) * tanhf(xg);
      c0s[(jj << 4) + b] = cn;
      gstore16(p.h0 + b * 1024 + (w << 2) + jj, f2bf(sigf(xo) * tanhf(cn)));
    }
    gbar(p.flags, ep++, w, tid);

    // ---------- S2: za = tanh(LN(h0)@Wp0^T + bp0)  (WGs 64..127) ----------
    if (w >= 64 && w < 128) {
      int idx = w - 64;
      {
        int b = tid >> 4, sg = tid & 15;
        float sm = 0.f, sq = 0.f;
        bf16x8 hv[8];
        LOAD8_C(hv, p.h0 + b * 1024 + sg * 64);
#pragma unroll
        for (int i = 0; i < 8; i++)
#pragma unroll
          for (int j = 0; j < 8; j++) {
            float x = bf2f((u16)hv[i][j]);
            sm += x;
            sq += x * x;
          }
        red1[(b << 4) + sg] = sm;
        red2[(b << 4) + sg] = sq;
      }
      __syncthreads();
      if (tid < 16) {
        float s = 0.f, q = 0.f;
        for (int i = 0; i < 16; i++) {
          s += red1[(tid << 4) + i];
          q += red2[(tid << 4) + i];
        }
        float mu = s * (1.f / 1024.f);
        float var = q * (1.f / 1024.f) - mu * mu;
        musig[tid] = mu;
        musig[16 + tid] = rsqrtf(var + 1e-5f);
      }
      __syncthreads();
      {
        const int bn = lane & 15, q = lane >> 4;
        float mu = musig[bn], rs = musig[16 + bn];
        f32x4 acc = {0.f, 0.f, 0.f, 0.f};
        bf16x8 hvv[8];
        LOAD8_S(hvv, p.h0 + bn * 1024 + (wv << 8) + (q << 3));
#pragma unroll
        for (int c = 0; c < 8; c++) {
          int k = (wv << 8) + (c << 5) + (q << 3);
          float4 ga = *(const float4*)(p.lng0 + k);
          float4 gb = *(const float4*)(p.lng0 + k + 4);
          float4 ba = *(const float4*)(p.lnb0 + k);
          float4 bb = *(const float4*)(p.lnb0 + k + 4);
          bf16x8 a;
          a[0] = (short)f2bf((bf2f((u16)hvv[c][0]) - mu) * rs * ga.x + ba.x);
          a[1] = (short)f2bf((bf2f((u16)hvv[c][1]) - mu) * rs * ga.y + ba.y);
          a[2] = (short)f2bf((bf2f((u16)hvv[c][2]) - mu) * rs * ga.z + ba.z);
          a[3] = (short)f2bf((bf2f((u16)hvv[c][3]) - mu) * rs * ga.w + ba.w);
          a[4] = (short)f2bf((bf2f((u16)hvv[c][4]) - mu) * rs * gb.x + bb.x);
          a[5] = (short)f2bf((bf2f((u16)hvv[c][5]) - mu) * rs * gb.y + bb.y);
          a[6] = (short)f2bf((bf2f((u16)hvv[c][6]) - mu) * rs * gb.z + bb.z);
          a[7] = (short)f2bf((bf2f((u16)hvv[c][7]) - mu) * rs * gb.w + bb.w);
          bf16x8 b = *(const bf16x8*)(wp_s + bn * SLICE + k);
          acc = MFMA16(a, b, acc);
        }
        *(f32x4*)(partial + (wv << 8) + (bn << 4) + (q << 2)) = acc;
      }
      __syncthreads();
      {
        int nl = tid >> 4, b = tid & 15;
        float s = partial[(nl << 4) + b] + partial[256 + (nl << 4) + b] + partial[512 + (nl << 4) + b] +
                  partial[768 + (nl << 4) + b];
        s += p.bp0[idx * 16 + nl];
        gstore16(p.za + b * 1024 + idx * 16 + nl, f2bf(tanhf(s)));
      }
    }
    gbar(p.flags, ep++, w, tid);

    // ---------- S3: gates1 = za @ Wih1^T + zb @ Whh1^T + b ; cell1 -> h1 ----------
    {
      const int bn = lane & 15, q = lane >> 4;
      f32x4 acc = {0.f, 0.f, 0.f, 0.f};
      bf16x8 a1v[8], a2v[8];
      LOAD8_S(a1v, p.za + bn * 1024 + (wv << 8) + (q << 3));
      LOAD8_S(a2v, p.zb + bn * 1024 + (wv << 8) + (q << 3));
#pragma unroll
      for (int c = 0; c < 8; c++) {
        int k = (wv << 8) + (c << 5) + (q << 3);
        bf16x8 b1 = *(const bf16x8*)(wih1_s + bn * SLICE + k);
        acc = MFMA16(a1v[c], b1, acc);
        bf16x8 b2 = *(const bf16x8*)(whh1_s + bn * SLICE + k);
        acc = MFMA16(a2v[c], b2, acc);
      }
      *(f32x4*)(partial + (wv << 8) + (bn << 4) + (q << 2)) = acc;
    }
    __syncthreads();
    {
      int nl = tid >> 4, b = tid & 15;
      float s = partial[(nl << 4) + b] + partial[256 + (nl << 4) + b] + partial[512 + (nl << 4) + b] +
                partial[768 + (nl << 4) + b];
      int n = (nl >> 2) * 1024 + (w << 2) + (nl & 3);
      s += p.bih1[n] + p.bhh1[n];
      gates2[(nl << 4) + b] = s;
    }
    __syncthreads();
    if (tid < 64) {
      int jj = tid >> 4, b = tid & 15;
      float xi = gates2[(jj)*16 + b];
      float xf = gates2[(4 + jj) * 16 + b];
      float xg = gates2[(8 + jj) * 16 + b];
      float xo = gates2[(12 + jj) * 16 + b];
      float c = c1s[(jj << 4) + b];
      float cn = sigf(xf) * c + sigf(xi) * tanhf(xg);
      c1s[(jj << 4) + b] = cn;
      gstore16(p.h1 + b * 1024 + (w << 2) + jj, f2bf(sigf(xo) * tanhf(cn)));
    }
    gbar(p.flags, ep++, w, tid);

    // ---------- S4: zb = tanh(LN(h1)@Wp1^T + bp1); zs[t]=zb  (WGs 128..191) ----------
    if (w >= 128 && w < 192) {
      int idx = w - 128;
      {
        int b = tid >> 4, sg = tid & 15;
        float sm = 0.f, sq = 0.f;
        bf16x8 hv[8];
        LOAD8_C(hv, p.h1 + b * 1024 + sg * 64);
#pragma unroll
        for (int i = 0; i < 8; i++)
#pragma unroll
          for (int j = 0; j < 8; j++) {
            float x = bf2f((u16)hv[i][j]);
            sm += x;
            sq += x * x;
          }
        red1[(b << 4) + sg] = sm;
        red2[(b << 4) + sg] = sq;
      }
      __syncthreads();
      if (tid < 16) {
        float s = 0.f, q = 0.f;
        for (int i = 0; i < 16; i++) {
          s += red1[(tid << 4) + i];
          q += red2[(tid << 4) + i];
        }
        float mu = s * (1.f / 1024.f);
        float var = q * (1.f / 1024.f) - mu * mu;
        musig[tid] = mu;
        musig[16 + tid] = rsqrtf(var + 1e-5f);
      }
      __syncthreads();
      {
        const int bn = lane & 15, q = lane >> 4;
        float mu = musig[bn], rs = musig[16 + bn];
        f32x4 acc = {0.f, 0.f, 0.f, 0.f};
        bf16x8 hvv[8];
        LOAD8_S(hvv, p.h1 + bn * 1024 + (wv << 8) + (q << 3));
#pragma unroll
        for (int c = 0; c < 8; c++) {
          int k = (wv << 8) + (c << 5) + (q << 3);
          float4 ga = *(const float4*)(p.lng1 + k);
          float4 gb = *(const float4*)(p.lng1 + k + 4);
          float4 ba = *(const float4*)(p.lnb1 + k);
          float4 bb = *(const float4*)(p.lnb1 + k + 4);
          bf16x8 a;
          a[0] = (short)f2bf((bf2f((u16)hvv[c][0]) - mu) * rs * ga.x + ba.x);
          a[1] = (short)f2bf((bf2f((u16)hvv[c][1]) - mu) * rs * ga.y + ba.y);
          a[2] = (short)f2bf((bf2f((u16)hvv[c][2]) - mu) * rs * ga.z + ba.z);
          a[3] = (short)f2bf((bf2f((u16)hvv[c][3]) - mu) * rs * ga.w + ba.w);
          a[4] = (short)f2bf((bf2f((u16)hvv[c][4]) - mu) * rs * gb.x + bb.x);
          a[5] = (short)f2bf((bf2f((u16)hvv[c][5]) - mu) * rs * gb.y + bb.y);
          a[6] = (short)f2bf((bf2f((u16)hvv[c][6]) - mu) * rs * gb.z + bb.z);
          a[7] = (short)f2bf((bf2f((u16)hvv[c][7]) - mu) * rs * gb.w + bb.w);
          bf16x8 b = *(const bf16x8*)(wp_s + bn * SLICE + k);
          acc = MFMA16(a, b, acc);
        }
        *(f32x4*)(partial + (wv << 8) + (bn << 4) + (q << 2)) = acc;
      }
      __syncthreads();
      {
        int nl = tid >> 4, b = tid & 15;
        float s = partial[(nl << 4) + b] + partial[256 + (nl << 4) + b] + partial[512 + (nl << 4) + b] +
                  partial[768 + (nl << 4) + b];
        s += p.bp1[idx * 16 + nl];
        u16 u = f2bf(tanhf(s));
        gstore16(p.zb + b * 1024 + idx * 16 + nl, u);
        p.zs[(size_t)((t << 4) | b) * 1024 + idx * 16 + nl] = u;  // plain store: read post-kernel
      }
    }
    gbar(p.flags, ep++, w, tid);
  }
}

// ---------------- host ----------------
extern "C" void kernel_launch(void* const* d_in, const int* in_sizes, int n_in, void* d_out, int out_size,
                              void* d_ws, size_t ws_size, hipStream_t stream) {
  const float* cond = (const float*)d_in[0];
  const float* targets = (const float*)d_in[1];
  const float* tmean = (const float*)d_in[2];
  const float* tscale = (const float*)d_in[3];
  const float* Wpre1 = (const float*)d_in[4];
  const float* bpre1 = (const float*)d_in[5];
  const float* Wpre2 = (const float*)d_in[6];
  const float* bpre2 = (const float*)d_in[7];
  const float* Wih0 = (const float*)d_in[8];
  const float* Whh0 = (const float*)d_in[9];
  const float* bih0 = (const float*)d_in[10];
  const float* bhh0 = (const float*)d_in[11];
  const float* lng0 = (const float*)d_in[12];
  const float* lnb0 = (const float*)d_in[13];
  const float* Wp0 = (const float*)d_in[14];
  const float* bp0 = (const float*)d_in[15];
  const float* Wih1 = (const float*)d_in[16];
  const float* Whh1 = (const float*)d_in[17];
  const float* bih1 = (const float*)d_in[18];
  const float* bhh1 = (const float*)d_in[19];
  const float* lng1 = (const float*)d_in[20];
  const float* lnb1 = (const float*)d_in[21];
  const float* Wp1 = (const float*)d_in[22];
  const float* bp1 = (const float*)d_in[23];
  const float* Wout = (const float*)d_in[24];
  const float* bout = (const float*)d_in[25];

  char* ws = (char*)d_ws;
  int* flags = (int*)(ws + 0);        // 1 KB used (256 x int, 4B stride)
  u16* za = (u16*)(ws + 32768);       // 16x1024 bf16
  u16* zb = (u16*)(ws + 65536);
  u16* h0 = (u16*)(ws + 98304);
  u16* h1 = (u16*)(ws + 131072);
  float* b0 = (float*)(ws + 163840);  // bih0+bhh0
  u16* woutb = (u16*)(ws + 180224);
  u16* wpre1b = (u16*)(ws + 344064);
  u16* wpre2b = (u16*)(ws + 393216);
  u16* wih0b = (u16*)(ws + 524288);
  u16* whh0b = (u16*)(ws + 6815744);
  u16* wih1b = (u16*)(ws + 15204352);
  u16* whh1b = (u16*)(ws + 23592960);
  u16* wp0b = (u16*)(ws + 31981568);
  u16* wp1b = (u16*)(ws + 34078720);
  u16* prevp = (u16*)(ws + 36175872);  // (T*B,96)
  u16* hpre = (u16*)(ws + 39321600);   // (T*B,256)
  u16* xall = (u16*)(ws + 47710208);   // (T*B,768)
  u16* g0 = (u16*)(ws + 72876032);     // (T*B,4096)
  u16* zs = (u16*)(ws + 207093760);    // (T*B,1024)

  hipMemsetAsync(ws, 0, 98304, stream);  // flags + za + zb

  cvt_wpre1<<<96, 256, 0, stream>>>(Wpre1, wpre1b);
  cvt<<<64, 256, 0, stream>>>(Wpre2, wpre2b, 65536);
  cvt<<<3072, 256, 0, stream>>>(Wih0, wih0b, 3145728);
  cvt<<<4096, 256, 0, stream>>>(Whh0, whh0b, 4194304);
  cvt<<<4096, 256, 0, stream>>>(Wih1, wih1b, 4194304);
  cvt<<<4096, 256, 0, stream>>>(Whh1, whh1b, 4194304);
  cvt<<<1024, 256, 0, stream>>>(Wp0, wp0b, 1048576);
  cvt<<<1024, 256, 0, stream>>>(Wp1, wp1b, 1048576);
  cvt<<<80, 256, 0, stream>>>(Wout, woutb, 81920);
  bsum<<<16, 256, 0, stream>>>(bih0, bhh0, b0);
  pack_prev<<<6144, 256, 0, stream>>>(targets, tmean, tscale, prevp);
  pack_cond<<<8192, 256, 0, stream>>>(cond, xall);

  gemm_bt<<<dim3(256, 4), 256, 0, stream>>>(prevp, 96, wpre1b, 96, hpre, 256, bpre1, 96, 1);
  gemm_bt<<<dim3(256, 4), 256, 0, stream>>>(hpre, 256, wpre2b, 256, xall + 512, 768, bpre2, 256, 1);
  gemm_bt<<<dim3(256, 64), 256, 0, stream>>>(xall, 768, wih0b, 768, g0, 4096, b0, 768, 0);

  RecP rp;
  rp.g0 = g0;
  rp.whh0b = whh0b;
  rp.wih1b = wih1b;
  rp.whh1b = whh1b;
  rp.wp0b = wp0b;
  rp.wp1b = wp1b;
  rp.bih1 = bih1;
  rp.bhh1 = bhh1;
  rp.bp0 = bp0;
  rp.bp1 = bp1;
  rp.lng0 = lng0;
  rp.lnb0 = lnb0;
  rp.lng1 = lng1;
  rp.lnb1 = lnb1;
  rp.za = za;
  rp.zb = zb;
  rp.h0 = h0;
  rp.h1 = h1;
  rp.zs = zs;
  rp.flags = flags;

  hipFuncSetAttribute(reinterpret_cast<const void*>(recurrent), hipFuncAttributeMaxDynamicSharedMemorySize,
                      SMEM_BYTES);
  recurrent<<<dim3(256), dim3(256), SMEM_BYTES, stream>>>(rp);

  out_proj<<<1280, 256, 0, stream>>>(zs, woutb, bout, (float*)d_out);
}

// Round 4
// 19683.594 us; speedup vs baseline: 8.3736x; 1.8358x over previous
//
#include <hip/hip_runtime.h>

// LSTM decoder (B=16,T=1024,CI=512,AR=256,H=1024,DO=80) for MI355X.
// R4 = R3 (two-group pipelined persistent recurrence) + early-clobber (=&v)
// on ALL inline-asm outputs. R3 faulted because outputs could be allocated
// over the address-pair inputs (asm reads addresses after writing outputs).
//   WGs 0..127  = layer0: S1 (cell0, Whh0 LDS) -> S2 (LN+Wp0 LDS) -> za_all[t]
//   WGs 128..255= layer1: S3 (cell1, Wih1+Whh1 LDS) -> S4 (LN+Wp1 L2) -> zb, zs
// Cross-WG data via sc0+sc1 bypass (IF$ = device coherence point, R2-validated).

typedef unsigned short u16;
typedef short bf16x8 __attribute__((ext_vector_type(8)));
typedef float f32x4 __attribute__((ext_vector_type(4)));

#define MFMA16(a, b, c) __builtin_amdgcn_mfma_f32_16x16x32_bf16((a), (b), (c), 0, 0, 0)

__device__ __forceinline__ u16 f2bf(float x) {
  unsigned u = __float_as_uint(x);
  return (u16)((u + 0x7fffu + ((u >> 16) & 1u)) >> 16);  // RNE
}
__device__ __forceinline__ float bf2f(u16 h) { return __uint_as_float(((unsigned)h) << 16); }
__device__ __forceinline__ float sigf(float x) { return 1.f / (1.f + __expf(-x)); }

// 8 bypass loads, 64B stride (GEMM fragment walk), one wait. Early-clobber!
#define LOAD8_S(dst, base)                                                          \
  asm volatile("global_load_dwordx4 %0, %8, off sc0 sc1\n\t"                        \
               "global_load_dwordx4 %1, %8, off offset:64 sc0 sc1\n\t"              \
               "global_load_dwordx4 %2, %8, off offset:128 sc0 sc1\n\t"             \
               "global_load_dwordx4 %3, %8, off offset:192 sc0 sc1\n\t"             \
               "global_load_dwordx4 %4, %8, off offset:256 sc0 sc1\n\t"             \
               "global_load_dwordx4 %5, %8, off offset:320 sc0 sc1\n\t"             \
               "global_load_dwordx4 %6, %8, off offset:384 sc0 sc1\n\t"             \
               "global_load_dwordx4 %7, %8, off offset:448 sc0 sc1\n\t"             \
               "s_waitcnt vmcnt(0)"                                                 \
               : "=&v"(dst[0]), "=&v"(dst[1]), "=&v"(dst[2]), "=&v"(dst[3]),        \
                 "=&v"(dst[4]), "=&v"(dst[5]), "=&v"(dst[6]), "=&v"(dst[7])         \
               : "v"((const void*)(base))                                           \
               : "memory")

// two fragment walks (za + zb) in one asm block, single wait.
#define LOAD8x2_S(d0, d1, ba, bb)                                                   \
  asm volatile("global_load_dwordx4 %0, %16, off sc0 sc1\n\t"                       \
               "global_load_dwordx4 %1, %16, off offset:64 sc0 sc1\n\t"             \
               "global_load_dwordx4 %2, %16, off offset:128 sc0 sc1\n\t"            \
               "global_load_dwordx4 %3, %16, off offset:192 sc0 sc1\n\t"            \
               "global_load_dwordx4 %4, %16, off offset:256 sc0 sc1\n\t"            \
               "global_load_dwordx4 %5, %16, off offset:320 sc0 sc1\n\t"            \
               "global_load_dwordx4 %6, %16, off offset:384 sc0 sc1\n\t"            \
               "global_load_dwordx4 %7, %16, off offset:448 sc0 sc1\n\t"            \
               "global_load_dwordx4 %8, %17, off sc0 sc1\n\t"                       \
               "global_load_dwordx4 %9, %17, off offset:64 sc0 sc1\n\t"             \
               "global_load_dwordx4 %10, %17, off offset:128 sc0 sc1\n\t"           \
               "global_load_dwordx4 %11, %17, off offset:192 sc0 sc1\n\t"           \
               "global_load_dwordx4 %12, %17, off offset:256 sc0 sc1\n\t"           \
               "global_load_dwordx4 %13, %17, off offset:320 sc0 sc1\n\t"           \
               "global_load_dwordx4 %14, %17, off offset:384 sc0 sc1\n\t"           \
               "global_load_dwordx4 %15, %17, off offset:448 sc0 sc1\n\t"           \
               "s_waitcnt vmcnt(0)"                                                 \
               : "=&v"(d0[0]), "=&v"(d0[1]), "=&v"(d0[2]), "=&v"(d0[3]),            \
                 "=&v"(d0[4]), "=&v"(d0[5]), "=&v"(d0[6]), "=&v"(d0[7]),            \
                 "=&v"(d1[0]), "=&v"(d1[1]), "=&v"(d1[2]), "=&v"(d1[3]),            \
                 "=&v"(d1[4]), "=&v"(d1[5]), "=&v"(d1[6]), "=&v"(d1[7])             \
               : "v"((const void*)(ba)), "v"((const void*)(bb))                     \
               : "memory")

// 8 contiguous (stats, 128B) + 8 strided (fragment) in one asm block, one wait.
#define LOAD8C8S(dc, dsv, bc, bs)                                                   \
  asm volatile("global_load_dwordx4 %0, %16, off sc0 sc1\n\t"                       \
               "global_load_dwordx4 %1, %16, off offset:16 sc0 sc1\n\t"             \
               "global_load_dwordx4 %2, %16, off offset:32 sc0 sc1\n\t"             \
               "global_load_dwordx4 %3, %16, off offset:48 sc0 sc1\n\t"             \
               "global_load_dwordx4 %4, %16, off offset:64 sc0 sc1\n\t"             \
               "global_load_dwordx4 %5, %16, off offset:80 sc0 sc1\n\t"             \
               "global_load_dwordx4 %6, %16, off offset:96 sc0 sc1\n\t"             \
               "global_load_dwordx4 %7, %16, off offset:112 sc0 sc1\n\t"            \
               "global_load_dwordx4 %8, %17, off sc0 sc1\n\t"                       \
               "global_load_dwordx4 %9, %17, off offset:64 sc0 sc1\n\t"             \
               "global_load_dwordx4 %10, %17, off offset:128 sc0 sc1\n\t"           \
               "global_load_dwordx4 %11, %17, off offset:192 sc0 sc1\n\t"           \
               "global_load_dwordx4 %12, %17, off offset:256 sc0 sc1\n\t"           \
               "global_load_dwordx4 %13, %17, off offset:320 sc0 sc1\n\t"           \
               "global_load_dwordx4 %14, %17, off offset:384 sc0 sc1\n\t"           \
               "global_load_dwordx4 %15, %17, off offset:448 sc0 sc1\n\t"           \
               "s_waitcnt vmcnt(0)"                                                 \
               : "=&v"(dc[0]), "=&v"(dc[1]), "=&v"(dc[2]), "=&v"(dc[3]),            \
                 "=&v"(dc[4]), "=&v"(dc[5]), "=&v"(dc[6]), "=&v"(dc[7]),            \
                 "=&v"(dsv[0]), "=&v"(dsv[1]), "=&v"(dsv[2]), "=&v"(dsv[3]),        \
                 "=&v"(dsv[4]), "=&v"(dsv[5]), "=&v"(dsv[6]), "=&v"(dsv[7])         \
               : "v"((const void*)(bc)), "v"((const void*)(bs))                     \
               : "memory")

__device__ __forceinline__ void gstore16(u16* p, u16 v) {
  unsigned vv = v;
  asm volatile("global_store_short %0, %1, off sc0 sc1" ::"v"((void*)p), "v"(vv) : "memory");
}
__device__ __forceinline__ void gstore32(int* p, int v) {
  asm volatile("global_store_dword %0, %1, off sc0 sc1" ::"v"((void*)p), "v"(v) : "memory");
}

// Poll 128 packed flags (8 lines) with wave 0: 32 lanes x dwordx4, s_sleep pacing.
__device__ __forceinline__ void wait_flags(const int* flags, int e, int tid) {
  if (tid < 64) {
    const int4* fp = (const int4*)flags + (tid & 31);
    for (;;) {
      int4 f;
      asm volatile("global_load_dwordx4 %0, %1, off sc0 sc1\n\ts_waitcnt vmcnt(0)"
                   : "=&v"(f)
                   : "v"((const void*)fp)
                   : "memory");
      int ok = (f.x >= e) & (f.y >= e) & (f.z >= e) & (f.w >= e);
      if (__all(ok)) break;
      __builtin_amdgcn_s_sleep(2);
    }
  }
  __syncthreads();
}

// Intra-group barrier among 128 WGs: drain own stores, publish epoch, poll.
__device__ __forceinline__ void bar_grp(int* flags, int e, int wl, int tid) {
  asm volatile("s_waitcnt vmcnt(0)" ::: "memory");
  __syncthreads();
  if (tid == 0) gstore32(flags + wl, e);
  wait_flags(flags, e, tid);
}

// ---------------- prep kernels ----------------
__global__ __launch_bounds__(256) void cvt(const float* __restrict__ s, u16* __restrict__ d, int n) {
  int i = (blockIdx.x * 256 + threadIdx.x) * 4;
  if (i < n) {
    float4 v = *(const float4*)(s + i);
    unsigned lo = (unsigned)f2bf(v.x) | ((unsigned)f2bf(v.y) << 16);
    unsigned hi = (unsigned)f2bf(v.z) | ((unsigned)f2bf(v.w) << 16);
    *(uint2*)(d + i) = make_uint2(lo, hi);
  }
}

__global__ __launch_bounds__(256) void cvt_wpre1(const float* __restrict__ s, u16* __restrict__ d) {
  int i = blockIdx.x * 256 + threadIdx.x;  // < 256*96
  int r = i / 96, c = i - r * 96;
  d[i] = (c < 80) ? f2bf(s[r * 80 + c]) : (u16)0;
}

__global__ __launch_bounds__(256) void bsum(const float* __restrict__ a, const float* __restrict__ b,
                                            float* __restrict__ o) {
  int i = blockIdx.x * 256 + threadIdx.x;
  if (i < 4096) o[i] = a[i] + b[i];
}

__global__ __launch_bounds__(256) void pack_prev(const float* __restrict__ tg, const float* __restrict__ mean,
                                                 const float* __restrict__ scale, u16* __restrict__ prevp) {
  int i = blockIdx.x * 256 + threadIdx.x;  // < 16384*96
  int row = i / 96, c = i - row * 96;
  int t = row >> 4, b = row & 15;
  float v = 0.f;
  if (c < 80 && t > 0) v = (tg[((size_t)b * 1024 + (t - 1)) * 80 + c] - mean[c]) / scale[c];
  prevp[i] = f2bf(v);
}

__global__ __launch_bounds__(256) void pack_cond(const float* __restrict__ cond, u16* __restrict__ xall) {
  int i = (blockIdx.x * 256 + threadIdx.x) * 4;  // < 16384*512
  int row = i >> 9, c = i & 511;
  int t = row >> 4, b = row & 15;
  float4 v = *(const float4*)(cond + ((size_t)b * 1024 + t) * 512 + c);
  unsigned lo = (unsigned)f2bf(v.x) | ((unsigned)f2bf(v.y) << 16);
  unsigned hi = (unsigned)f2bf(v.z) | ((unsigned)f2bf(v.w) << 16);
  *(uint2*)(xall + (size_t)row * 768 + c) = make_uint2(lo, hi);
}

// ---------------- generic bf16 GEMM: C = act(A @ B^T + bias) ----------------
__global__ __launch_bounds__(256) void gemm_bt(const u16* __restrict__ A, int lda, const u16* __restrict__ B,
                                               int ldb, u16* __restrict__ C, int ldc,
                                               const float* __restrict__ bias, int K, int relu) {
  __shared__ u16 As[64 * 40];
  __shared__ u16 Bs[64 * 40];
  const int tid = threadIdx.x, lane = tid & 63, wv = tid >> 6;
  const int wr = wv >> 1, wc = wv & 1;
  const int m0 = blockIdx.x * 64, n0 = blockIdx.y * 64;
  const int lr = tid >> 2, lc = (tid & 3) * 8;
  f32x4 z = {0.f, 0.f, 0.f, 0.f};
  f32x4 acc[2][2] = {{z, z}, {z, z}};
  const u16* Ap = A + (size_t)(m0 + lr) * lda + lc;
  const u16* Bp = B + (size_t)(n0 + lr) * ldb + lc;
  for (int k0 = 0; k0 < K; k0 += 32) {
    int4 av = *(const int4*)(Ap + k0);
    int4 bv = *(const int4*)(Bp + k0);
    __syncthreads();
    *(int4*)(As + lr * 40 + lc) = av;
    *(int4*)(Bs + lr * 40 + lc) = bv;
    __syncthreads();
#pragma unroll
    for (int mi = 0; mi < 2; mi++) {
      bf16x8 af = *(const bf16x8*)(As + (wr * 32 + mi * 16 + (lane & 15)) * 40 + (lane >> 4) * 8);
#pragma unroll
      for (int ni = 0; ni < 2; ni++) {
        bf16x8 bf = *(const bf16x8*)(Bs + (wc * 32 + ni * 16 + (lane & 15)) * 40 + (lane >> 4) * 8);
        acc[mi][ni] = MFMA16(af, bf, acc[mi][ni]);
      }
    }
  }
#pragma unroll
  for (int mi = 0; mi < 2; mi++)
#pragma unroll
    for (int ni = 0; ni < 2; ni++) {
      int n = n0 + wc * 32 + ni * 16 + (lane & 15);
      float bs = bias ? bias[n] : 0.f;
#pragma unroll
      for (int r = 0; r < 4; r++) {
        int m = m0 + wr * 32 + mi * 16 + (lane >> 4) * 4 + r;
        float x = acc[mi][ni][r] + bs;
        if (relu) x = fmaxf(x, 0.f);
        C[(size_t)m * ldc + n] = f2bf(x);
      }
    }
}

// ---------------- final projection ----------------
__global__ __launch_bounds__(256) void out_proj(const u16* __restrict__ zs, const u16* __restrict__ Wb,
                                                const float* __restrict__ bout, float* __restrict__ out) {
  int wv = threadIdx.x >> 6, lane = threadIdx.x & 63;
  int tile = blockIdx.x * 4 + wv;  // 5120 tiles = 1024 m-tiles x 5 n-tiles
  int mt = tile / 5, nt = tile - mt * 5;
  int m0 = mt * 16, n0 = nt * 16;
  const u16* ap = zs + (size_t)(m0 + (lane & 15)) * 1024 + (lane >> 4) * 8;
  const u16* bp = Wb + (size_t)(n0 + (lane & 15)) * 1024 + (lane >> 4) * 8;
  f32x4 acc = {0.f, 0.f, 0.f, 0.f};
  for (int k = 0; k < 1024; k += 32) {
    bf16x8 a = *(const bf16x8*)(ap + k);
    bf16x8 b = *(const bf16x8*)(bp + k);
    acc = MFMA16(a, b, acc);
  }
  int n = n0 + (lane & 15);
  float bb = bout[n];
#pragma unroll
  for (int r = 0; r < 4; r++) {
    int m = m0 + (lane >> 4) * 4 + r;
    int t = m >> 4, b = m & 15;
    out[(size_t)b * 81920 + t * 80 + n] = acc[r] + bb;
  }
}

// ---------------- persistent recurrent kernel ----------------
struct RecP {
  const u16 *g0, *whh0b, *wih1b, *whh1b, *wp0b, *wp1b;
  const float *b1s, *bp0, *bp1, *lng0, *lnb0, *lng1, *lnb1;
  u16 *zb, *h0, *h1, *zs, *za_all;
  int *flag0, *flag1;
};

#define SLICE 1032
#define OFF_PARTIAL 132096
#define OFF_GATES 140288
#define OFF_RED1 142336
#define OFF_RED2 143360
#define OFF_MUSIG 144384
#define OFF_C 144512
#define SMEM_BYTES 145024

__global__ __launch_bounds__(256, 1) void recurrent(RecP p) {
  extern __shared__ char smem[];
  u16* wA = (u16*)smem;       // l0: Whh0 slice (32 rows) | l1: Wih1 slice
  u16* wB = wA + 32 * SLICE;  // l0: Wp0 slice (16 rows, 8 real) | l1: Whh1 slice
  float* partial = (float*)(smem + OFF_PARTIAL);  // 2048 f
  float* gates2 = (float*)(smem + OFF_GATES);     // 512 f
  float* red1 = (float*)(smem + OFF_RED1);        // 256 f
  float* red2 = (float*)(smem + OFF_RED2);        // 256 f
  float* musig = (float*)(smem + OFF_MUSIG);      // 32 f
  float* cs = (float*)(smem + OFF_C);             // 128 f

  const int w = blockIdx.x, tid = threadIdx.x;
  const int lane = tid & 63, wv = tid >> 6;
  const int bl = lane & 15, q = lane >> 4;
  const bool grp0 = (w < 128);
  const int wl = grp0 ? w : (w - 128);

  // ---- stage weights (once). WG owns hidden cols 8*wl..8*wl+7.
  {
    int r = tid >> 3, kp = tid & 7;  // 32 rows, 8 threads/row
    int gN = (r >> 3) * 1024 + (wl << 3) + (r & 7);
    const u16* srcA = grp0 ? p.whh0b : p.wih1b;
#pragma unroll
    for (int i = 0; i < 16; i++) {
      int k = kp * 128 + i * 8;
      *(int4*)(wA + r * SLICE + k) = *(const int4*)(srcA + (size_t)gN * 1024 + k);
    }
    if (!grp0) {
#pragma unroll
      for (int i = 0; i < 16; i++) {
        int k = kp * 128 + i * 8;
        *(int4*)(wB + r * SLICE + k) = *(const int4*)(p.whh1b + (size_t)gN * 1024 + k);
      }
    } else {
      int r2 = tid >> 4, kp2 = tid & 15;  // 16 rows (8 real + 8 zero), 16 thr/row
      int4 z4 = make_int4(0, 0, 0, 0);
#pragma unroll
      for (int i = 0; i < 8; i++) {
        int k = kp2 * 64 + i * 8;
        int4 v = z4;
        if (r2 < 8) v = *(const int4*)(p.wp0b + (size_t)((wl << 3) + r2) * 1024 + k);
        *(int4*)(wB + r2 * SLICE + k) = v;
      }
    }
    if (tid < 128) cs[tid] = 0.f;
  }
  __syncthreads();

  // per-thread invariants
  const int nl0 = tid >> 4, be = tid & 15;
  const int gN0 = (nl0 >> 3) * 1024 + (wl << 3) + (nl0 & 7);
  const int gN1 = ((nl0 + 16) >> 3) * 1024 + (wl << 3) + ((nl0 + 16) & 7);
  const float bp0v = p.bp0[(wl << 3) + ((tid >> 4) & 7)];
  const float bp1v = p.bp1[(wl << 3) + ((tid >> 4) & 7)];
  const float b1a = p.b1s[gN0], b1b = p.b1s[gN1];

  if (grp0) {
    // ================= layer 0 =================
    for (int t = 0; t < 1024; ++t) {
      // ---- S1: gates0 = G0[t] + za(t-1) @ Whh0^T ; cell0 -> h0
      if (t > 0) {
        const u16* zap = p.za_all + (size_t)(t - 1) * 16384 + bl * 1024 + (wv << 8) + (q << 3);
        bf16x8 av[8];
        LOAD8_S(av, zap);
        f32x4 acc0 = {0.f, 0.f, 0.f, 0.f}, acc1 = acc0;
#pragma unroll
        for (int c = 0; c < 8; c++) {
          int k = (wv << 8) + (c << 5) + (q << 3);
          acc0 = MFMA16(av[c], *(const bf16x8*)(wA + bl * SLICE + k), acc0);
          acc1 = MFMA16(av[c], *(const bf16x8*)(wA + (16 + bl) * SLICE + k), acc1);
        }
        *(f32x4*)(partial + (wv << 9) + (bl << 4) + (q << 2)) = acc0;
        *(f32x4*)(partial + (wv << 9) + ((16 + bl) << 4) + (q << 2)) = acc1;
      }
      u16 g0a = p.g0[(size_t)((t << 4) | be) * 4096 + gN0];  // prefetch
      u16 g0b = p.g0[(size_t)((t << 4) | be) * 4096 + gN1];
      __syncthreads();
      {
        float s0 = bf2f(g0a), s1 = bf2f(g0b);
        if (t > 0) {
          int e0 = tid, e1 = tid + 256;
          s0 += partial[e0] + partial[512 + e0] + partial[1024 + e0] + partial[1536 + e0];
          s1 += partial[e1] + partial[512 + e1] + partial[1024 + e1] + partial[1536 + e1];
        }
        gates2[tid] = s0;
        gates2[tid + 256] = s1;
      }
      __syncthreads();
      if (tid < 128) {
        int jj = tid >> 4, b = tid & 15;
        float xi = gates2[(jj)*16 + b];
        float xf = gates2[(8 + jj) * 16 + b];
        float xg = gates2[(16 + jj) * 16 + b];
        float xo = gates2[(24 + jj) * 16 + b];
        float c = cs[tid];
        float cn = sigf(xf) * c + sigf(xi) * tanhf(xg);
        cs[tid] = cn;
        gstore16(p.h0 + b * 1024 + (wl << 3) + jj, f2bf(sigf(xo) * tanhf(cn)));
      }
      bar_grp(p.flag0, 2 * t + 1, wl, tid);

      // ---- S2: za(t) = tanh(LN(h0) @ Wp0^T + bp0)
      {
        int sb = tid & 15, sg = tid >> 4;
        bf16x8 dc[8], dv[8];
        LOAD8C8S(dc, dv, p.h0 + sb * 1024 + (sg << 6), p.h0 + bl * 1024 + (wv << 8) + (q << 3));
        float sm = 0.f, sq = 0.f;
#pragma unroll
        for (int i = 0; i < 8; i++)
#pragma unroll
          for (int j = 0; j < 8; j++) {
            float x = bf2f((u16)dc[i][j]);
            sm += x;
            sq += x * x;
          }
        red1[sb * 16 + sg] = sm;
        red2[sb * 16 + sg] = sq;
        __syncthreads();
        if (tid < 64) {
          int b2 = tid >> 2, g2 = tid & 3;
          float s = red1[b2 * 16 + g2 * 4] + red1[b2 * 16 + g2 * 4 + 1] + red1[b2 * 16 + g2 * 4 + 2] +
                    red1[b2 * 16 + g2 * 4 + 3];
          float qq = red2[b2 * 16 + g2 * 4] + red2[b2 * 16 + g2 * 4 + 1] + red2[b2 * 16 + g2 * 4 + 2] +
                     red2[b2 * 16 + g2 * 4 + 3];
          s += __shfl_xor(s, 1);
          s += __shfl_xor(s, 2);
          qq += __shfl_xor(qq, 1);
          qq += __shfl_xor(qq, 2);
          if (g2 == 0) {
            float mu = s * (1.f / 1024.f);
            float var = qq * (1.f / 1024.f) - mu * mu;
            musig[b2] = mu;
            musig[16 + b2] = rsqrtf(var + 1e-5f);
          }
        }
        __syncthreads();
        float mu = musig[bl], rs = musig[16 + bl];
        f32x4 acc = {0.f, 0.f, 0.f, 0.f};
#pragma unroll
        for (int c = 0; c < 8; c++) {
          int k = (wv << 8) + (c << 5) + (q << 3);
          float4 ga = *(const float4*)(p.lng0 + k);
          float4 gb = *(const float4*)(p.lng0 + k + 4);
          float4 ba = *(const float4*)(p.lnb0 + k);
          float4 bb = *(const float4*)(p.lnb0 + k + 4);
          bf16x8 a;
          a[0] = (short)f2bf((bf2f((u16)dv[c][0]) - mu) * rs * ga.x + ba.x);
          a[1] = (short)f2bf((bf2f((u16)dv[c][1]) - mu) * rs * ga.y + ba.y);
          a[2] = (short)f2bf((bf2f((u16)dv[c][2]) - mu) * rs * ga.z + ba.z);
          a[3] = (short)f2bf((bf2f((u16)dv[c][3]) - mu) * rs * ga.w + ba.w);
          a[4] = (short)f2bf((bf2f((u16)dv[c][4]) - mu) * rs * gb.x + bb.x);
          a[5] = (short)f2bf((bf2f((u16)dv[c][5]) - mu) * rs * gb.y + bb.y);
          a[6] = (short)f2bf((bf2f((u16)dv[c][6]) - mu) * rs * gb.z + bb.z);
          a[7] = (short)f2bf((bf2f((u16)dv[c][7]) - mu) * rs * gb.w + bb.w);
          acc = MFMA16(a, *(const bf16x8*)(wB + bl * SLICE + k), acc);
        }
        *(f32x4*)(partial + (wv << 8) + (bl << 4) + (q << 2)) = acc;
      }
      __syncthreads();
      if (tid < 128) {
        int nl = tid >> 4, b = tid & 15;
        float s = partial[nl * 16 + b] + partial[256 + nl * 16 + b] + partial[512 + nl * 16 + b] +
                  partial[768 + nl * 16 + b] + bp0v;
        gstore16(p.za_all + (size_t)t * 16384 + b * 1024 + (wl << 3) + nl, f2bf(tanhf(s)));
      }
      bar_grp(p.flag0, 2 * t + 2, wl, tid);
    }
  } else {
    // ================= layer 1 =================
    for (int t = 0; t < 1024; ++t) {
      wait_flags(p.flag0, 2 * t + 2, tid);  // za(t) published by layer0

      // ---- S3: gates1 = za(t) @ Wih1^T + zb(t-1) @ Whh1^T + b ; cell1 -> h1
      {
        const u16* zap = p.za_all + (size_t)t * 16384 + bl * 1024 + (wv << 8) + (q << 3);
        const u16* zbp = p.zb + bl * 1024 + (wv << 8) + (q << 3);
        bf16x8 a1[8], a2[8];
        LOAD8x2_S(a1, a2, zap, zbp);
        f32x4 acc0 = {0.f, 0.f, 0.f, 0.f}, acc1 = acc0;
#pragma unroll
        for (int c = 0; c < 8; c++) {
          int k = (wv << 8) + (c << 5) + (q << 3);
          acc0 = MFMA16(a1[c], *(const bf16x8*)(wA + bl * SLICE + k), acc0);
          acc1 = MFMA16(a1[c], *(const bf16x8*)(wA + (16 + bl) * SLICE + k), acc1);
          acc0 = MFMA16(a2[c], *(const bf16x8*)(wB + bl * SLICE + k), acc0);
          acc1 = MFMA16(a2[c], *(const bf16x8*)(wB + (16 + bl) * SLICE + k), acc1);
        }
        *(f32x4*)(partial + (wv << 9) + (bl << 4) + (q << 2)) = acc0;
        *(f32x4*)(partial + (wv << 9) + ((16 + bl) << 4) + (q << 2)) = acc1;
      }
      __syncthreads();
      {
        int e0 = tid, e1 = tid + 256;
        float s0 = partial[e0] + partial[512 + e0] + partial[1024 + e0] + partial[1536 + e0] + b1a;
        float s1 = partial[e1] + partial[512 + e1] + partial[1024 + e1] + partial[1536 + e1] + b1b;
        gates2[e0] = s0;
        gates2[e1] = s1;
      }
      __syncthreads();
      if (tid < 128) {
        int jj = tid >> 4, b = tid & 15;
        float xi = gates2[(jj)*16 + b];
        float xf = gates2[(8 + jj) * 16 + b];
        float xg = gates2[(16 + jj) * 16 + b];
        float xo = gates2[(24 + jj) * 16 + b];
        float c = cs[tid];
        float cn = sigf(xf) * c + sigf(xi) * tanhf(xg);
        cs[tid] = cn;
        gstore16(p.h1 + b * 1024 + (wl << 3) + jj, f2bf(sigf(xo) * tanhf(cn)));
      }
      bar_grp(p.flag1, 2 * t + 1, wl, tid);

      // ---- S4: zb(t) = tanh(LN(h1) @ Wp1^T + bp1) ; zs[t] = zb
      {
        int sb = tid & 15, sg = tid >> 4;
        bf16x8 dc[8], dv[8];
        LOAD8C8S(dc, dv, p.h1 + sb * 1024 + (sg << 6), p.h1 + bl * 1024 + (wv << 8) + (q << 3));
        float sm = 0.f, sq = 0.f;
#pragma unroll
        for (int i = 0; i < 8; i++)
#pragma unroll
          for (int j = 0; j < 8; j++) {
            float x = bf2f((u16)dc[i][j]);
            sm += x;
            sq += x * x;
          }
        red1[sb * 16 + sg] = sm;
        red2[sb * 16 + sg] = sq;
        __syncthreads();
        if (tid < 64) {
          int b2 = tid >> 2, g2 = tid & 3;
          float s = red1[b2 * 16 + g2 * 4] + red1[b2 * 16 + g2 * 4 + 1] + red1[b2 * 16 + g2 * 4 + 2] +
                    red1[b2 * 16 + g2 * 4 + 3];
          float qq = red2[b2 * 16 + g2 * 4] + red2[b2 * 16 + g2 * 4 + 1] + red2[b2 * 16 + g2 * 4 + 2] +
                     red2[b2 * 16 + g2 * 4 + 3];
          s += __shfl_xor(s, 1);
          s += __shfl_xor(s, 2);
          qq += __shfl_xor(qq, 1);
          qq += __shfl_xor(qq, 2);
          if (g2 == 0) {
            float mu = s * (1.f / 1024.f);
            float var = qq * (1.f / 1024.f) - mu * mu;
            musig[b2] = mu;
            musig[16 + b2] = rsqrtf(var + 1e-5f);
          }
        }
        __syncthreads();
        float mu = musig[bl], rs = musig[16 + bl];
        f32x4 acc = {0.f, 0.f, 0.f, 0.f};
        const u16* wpp = p.wp1b + (size_t)((wl << 3) + (bl & 7)) * 1024;  // plain loads, L2-hot
        bf16x8 z8 = {0, 0, 0, 0, 0, 0, 0, 0};
#pragma unroll
        for (int c = 0; c < 8; c++) {
          int k = (wv << 8) + (c << 5) + (q << 3);
          float4 ga = *(const float4*)(p.lng1 + k);
          float4 gb = *(const float4*)(p.lng1 + k + 4);
          float4 ba = *(const float4*)(p.lnb1 + k);
          float4 bb = *(const float4*)(p.lnb1 + k + 4);
          bf16x8 a;
          a[0] = (short)f2bf((bf2f((u16)dv[c][0]) - mu) * rs * ga.x + ba.x);
          a[1] = (short)f2bf((bf2f((u16)dv[c][1]) - mu) * rs * ga.y + ba.y);
          a[2] = (short)f2bf((bf2f((u16)dv[c][2]) - mu) * rs * ga.z + ba.z);
          a[3] = (short)f2bf((bf2f((u16)dv[c][3]) - mu) * rs * ga.w + ba.w);
          a[4] = (short)f2bf((bf2f((u16)dv[c][4]) - mu) * rs * gb.x + bb.x);
          a[5] = (short)f2bf((bf2f((u16)dv[c][5]) - mu) * rs * gb.y + bb.y);
          a[6] = (short)f2bf((bf2f((u16)dv[c][6]) - mu) * rs * gb.z + bb.z);
          a[7] = (short)f2bf((bf2f((u16)dv[c][7]) - mu) * rs * gb.w + bb.w);
          bf16x8 bw = *(const bf16x8*)(wpp + k);
          if (bl >= 8) bw = z8;
          acc = MFMA16(a, bw, acc);
        }
        *(f32x4*)(partial + (wv << 8) + (bl << 4) + (q << 2)) = acc;
      }
      __syncthreads();
      if (tid < 128) {
        int nl = tid >> 4, b = tid & 15;
        float s = partial[nl * 16 + b] + partial[256 + nl * 16 + b] + partial[512 + nl * 16 + b] +
                  partial[768 + nl * 16 + b] + bp1v;
        u16 u = f2bf(tanhf(s));
        gstore16(p.zb + b * 1024 + (wl << 3) + nl, u);
        p.zs[(size_t)((t << 4) | b) * 1024 + (wl << 3) + nl] = u;  // plain: read post-kernel
      }
      bar_grp(p.flag1, 2 * t + 2, wl, tid);
    }
  }
}

// ---------------- host ----------------
extern "C" void kernel_launch(void* const* d_in, const int* in_sizes, int n_in, void* d_out, int out_size,
                              void* d_ws, size_t ws_size, hipStream_t stream) {
  const float* cond = (const float*)d_in[0];
  const float* targets = (const float*)d_in[1];
  const float* tmean = (const float*)d_in[2];
  const float* tscale = (const float*)d_in[3];
  const float* Wpre1 = (const float*)d_in[4];
  const float* bpre1 = (const float*)d_in[5];
  const float* Wpre2 = (const float*)d_in[6];
  const float* bpre2 = (const float*)d_in[7];
  const float* Wih0 = (const float*)d_in[8];
  const float* Whh0 = (const float*)d_in[9];
  const float* bih0 = (const float*)d_in[10];
  const float* bhh0 = (const float*)d_in[11];
  const float* lng0 = (const float*)d_in[12];
  const float* lnb0 = (const float*)d_in[13];
  const float* Wp0 = (const float*)d_in[14];
  const float* bp0 = (const float*)d_in[15];
  const float* Wih1 = (const float*)d_in[16];
  const float* Whh1 = (const float*)d_in[17];
  const float* bih1 = (const float*)d_in[18];
  const float* bhh1 = (const float*)d_in[19];
  const float* lng1 = (const float*)d_in[20];
  const float* lnb1 = (const float*)d_in[21];
  const float* Wp1 = (const float*)d_in[22];
  const float* bp1 = (const float*)d_in[23];
  const float* Wout = (const float*)d_in[24];
  const float* bout = (const float*)d_in[25];

  char* ws = (char*)d_ws;
  int* flag0 = (int*)(ws + 0);         // 512B
  int* flag1 = (int*)(ws + 1024);      // 512B
  u16* zb = (u16*)(ws + 4096);         // 32KB (memset -> zb(-1)=0)
  u16* h0 = (u16*)(ws + 36864);        // 32KB
  u16* h1 = (u16*)(ws + 69632);        // 32KB
  float* b0s = (float*)(ws + 102400);  // bih0+bhh0 (16KB)
  float* b1s = (float*)(ws + 118784);  // bih1+bhh1 (16KB)
  u16* woutb = (u16*)(ws + 135168);    // 160KB
  u16* wpre1b = (u16*)(ws + 299008);
  u16* wpre2b = (u16*)(ws + 348160);
  u16* wih0b = (u16*)(ws + 479232);
  u16* whh0b = (u16*)(ws + 6770688);
  u16* wih1b = (u16*)(ws + 15159296);
  u16* whh1b = (u16*)(ws + 23547904);
  u16* wp0b = (u16*)(ws + 31936512);
  u16* wp1b = (u16*)(ws + 34033664);
  u16* prevp = (u16*)(ws + 36130816);   // (T*B,96)  -- prep-only
  u16* hpre = (u16*)(ws + 39276544);    // (T*B,256) -- prep-only
  u16* xall = (u16*)(ws + 47665152);    // (T*B,768) -- prep-only
  u16* g0 = (u16*)(ws + 72830976);      // (T*B,4096)
  u16* zs = (u16*)(ws + 207048704);     // (T*B,1024)
  u16* za_all = (u16*)(ws + 36130816);  // 1024 x 32KB -- overlays prep buffers (dead by then)

  hipMemsetAsync(ws, 0, 36864, stream);  // flags + zb

  cvt_wpre1<<<96, 256, 0, stream>>>(Wpre1, wpre1b);
  cvt<<<64, 256, 0, stream>>>(Wpre2, wpre2b, 65536);
  cvt<<<3072, 256, 0, stream>>>(Wih0, wih0b, 3145728);
  cvt<<<4096, 256, 0, stream>>>(Whh0, whh0b, 4194304);
  cvt<<<4096, 256, 0, stream>>>(Wih1, wih1b, 4194304);
  cvt<<<4096, 256, 0, stream>>>(Whh1, whh1b, 4194304);
  cvt<<<1024, 256, 0, stream>>>(Wp0, wp0b, 1048576);
  cvt<<<1024, 256, 0, stream>>>(Wp1, wp1b, 1048576);
  cvt<<<80, 256, 0, stream>>>(Wout, woutb, 81920);
  bsum<<<16, 256, 0, stream>>>(bih0, bhh0, b0s);
  bsum<<<16, 256, 0, stream>>>(bih1, bhh1, b1s);
  pack_prev<<<6144, 256, 0, stream>>>(targets, tmean, tscale, prevp);
  pack_cond<<<8192, 256, 0, stream>>>(cond, xall);

  gemm_bt<<<dim3(256, 4), 256, 0, stream>>>(prevp, 96, wpre1b, 96, hpre, 256, bpre1, 96, 1);
  gemm_bt<<<dim3(256, 4), 256, 0, stream>>>(hpre, 256, wpre2b, 256, xall + 512, 768, bpre2, 256, 1);
  gemm_bt<<<dim3(256, 64), 256, 0, stream>>>(xall, 768, wih0b, 768, g0, 4096, b0s, 768, 0);

  RecP rp;
  rp.g0 = g0;
  rp.whh0b = whh0b;
  rp.wih1b = wih1b;
  rp.whh1b = whh1b;
  rp.wp0b = wp0b;
  rp.wp1b = wp1b;
  rp.b1s = b1s;
  rp.bp0 = bp0;
  rp.bp1 = bp1;
  rp.lng0 = lng0;
  rp.lnb0 = lnb0;
  rp.lng1 = lng1;
  rp.lnb1 = lnb1;
  rp.zb = zb;
  rp.h0 = h0;
  rp.h1 = h1;
  rp.zs = zs;
  rp.za_all = za_all;
  rp.flag0 = flag0;
  rp.flag1 = flag1;

  hipFuncSetAttribute(reinterpret_cast<const void*>(recurrent), hipFuncAttributeMaxDynamicSharedMemorySize,
                      SMEM_BYTES);
  recurrent<<<dim3(256), dim3(256), SMEM_BYTES, stream>>>(rp);

  out_proj<<<1280, 256, 0, stream>>>(zs, woutb, bout, (float*)d_out);
}

// Round 5
// 17425.632 us; speedup vs baseline: 9.4586x; 1.1296x over previous
//
#include <hip/hip_runtime.h>

// LSTM decoder (B=16,T=1024,CI=512,AR=256,H=1024,DO=80) for MI355X.
// R5: write-once activation streams => plain (L1/L2-cached) broadcast loads,
// no fences. h0/h1/zb live at hall[t] (overlaid on consumed g0[t-1] rows);
// za_all[t] as before. Producers store sc0+sc1 (write-through to memory);
// readers load plain AFTER flag detect — addresses are virgin, so no cache
// line can be stale. g0 reads are bypass (its rows get overwritten at t+1)
// and are prefetched one step ahead (barrier vmcnt(0) hides the latency).
// Flags/polls remain sc0+sc1 (must see memory truth).

typedef unsigned short u16;
typedef short bf16x8 __attribute__((ext_vector_type(8)));
typedef float f32x4 __attribute__((ext_vector_type(4)));

#define MFMA16(a, b, c) __builtin_amdgcn_mfma_f32_16x16x32_bf16((a), (b), (c), 0, 0, 0)

__device__ __forceinline__ u16 f2bf(float x) {
  unsigned u = __float_as_uint(x);
  return (u16)((u + 0x7fffu + ((u >> 16) & 1u)) >> 16);  // RNE
}
__device__ __forceinline__ float bf2f(u16 h) { return __uint_as_float(((unsigned)h) << 16); }
__device__ __forceinline__ float sigf(float x) { return 1.f / (1.f + __expf(-x)); }

__device__ __forceinline__ void gstore16(u16* p, u16 v) {
  unsigned vv = v;
  asm volatile("global_store_short %0, %1, off sc0 sc1" ::"v"((void*)p), "v"(vv) : "memory");
}
__device__ __forceinline__ void gstore32(int* p, int v) {
  asm volatile("global_store_dword %0, %1, off sc0 sc1" ::"v"((void*)p), "v"(v) : "memory");
}

// plain cached fragment loads: 8 x 16B at 64B stride (MFMA A-operand walk)
__device__ __forceinline__ void load8s(bf16x8 d[8], const u16* p) {
#pragma unroll
  for (int c = 0; c < 8; c++) d[c] = *(const bf16x8*)(p + (c << 5));
}
// plain cached contiguous scan: 8 x 16B at 16B stride (LN stats)
__device__ __forceinline__ void load8c(bf16x8 d[8], const u16* p) {
#pragma unroll
  for (int c = 0; c < 8; c++) d[c] = *(const bf16x8*)(p + (c << 3));
}

// Poll 128 packed flags (8 lines) with wave 0: 32 lanes x dwordx4, s_sleep pacing.
__device__ __forceinline__ void wait_flags(const int* flags, int e, int tid) {
  if (tid < 64) {
    const int4* fp = (const int4*)flags + (tid & 31);
    for (;;) {
      int4 f;
      asm volatile("global_load_dwordx4 %0, %1, off sc0 sc1\n\ts_waitcnt vmcnt(0)"
                   : "=&v"(f)
                   : "v"((const void*)fp)
                   : "memory");
      int ok = (f.x >= e) & (f.y >= e) & (f.z >= e) & (f.w >= e);
      if (__all(ok)) break;
      __builtin_amdgcn_s_sleep(2);
    }
  }
  __syncthreads();
}

// Intra-group barrier among 128 WGs: drain own stores, publish epoch, poll.
__device__ __forceinline__ void bar_grp(int* flags, int e, int wl, int tid) {
  asm volatile("s_waitcnt vmcnt(0)" ::: "memory");
  __syncthreads();
  if (tid == 0) gstore32(flags + wl, e);
  wait_flags(flags, e, tid);
}

// ---------------- prep kernels ----------------
__global__ __launch_bounds__(256) void cvt(const float* __restrict__ s, u16* __restrict__ d, int n) {
  int i = (blockIdx.x * 256 + threadIdx.x) * 4;
  if (i < n) {
    float4 v = *(const float4*)(s + i);
    unsigned lo = (unsigned)f2bf(v.x) | ((unsigned)f2bf(v.y) << 16);
    unsigned hi = (unsigned)f2bf(v.z) | ((unsigned)f2bf(v.w) << 16);
    *(uint2*)(d + i) = make_uint2(lo, hi);
  }
}

__global__ __launch_bounds__(256) void cvt_wpre1(const float* __restrict__ s, u16* __restrict__ d) {
  int i = blockIdx.x * 256 + threadIdx.x;  // < 256*96
  int r = i / 96, c = i - r * 96;
  d[i] = (c < 80) ? f2bf(s[r * 80 + c]) : (u16)0;
}

__global__ __launch_bounds__(256) void bsum(const float* __restrict__ a, const float* __restrict__ b,
                                            float* __restrict__ o) {
  int i = blockIdx.x * 256 + threadIdx.x;
  if (i < 4096) o[i] = a[i] + b[i];
}

__global__ __launch_bounds__(256) void pack_prev(const float* __restrict__ tg, const float* __restrict__ mean,
                                                 const float* __restrict__ scale, u16* __restrict__ prevp) {
  int i = blockIdx.x * 256 + threadIdx.x;  // < 16384*96
  int row = i / 96, c = i - row * 96;
  int t = row >> 4, b = row & 15;
  float v = 0.f;
  if (c < 80 && t > 0) v = (tg[((size_t)b * 1024 + (t - 1)) * 80 + c] - mean[c]) / scale[c];
  prevp[i] = f2bf(v);
}

__global__ __launch_bounds__(256) void pack_cond(const float* __restrict__ cond, u16* __restrict__ xall) {
  int i = (blockIdx.x * 256 + threadIdx.x) * 4;  // < 16384*512
  int row = i >> 9, c = i & 511;
  int t = row >> 4, b = row & 15;
  float4 v = *(const float4*)(cond + ((size_t)b * 1024 + t) * 512 + c);
  unsigned lo = (unsigned)f2bf(v.x) | ((unsigned)f2bf(v.y) << 16);
  unsigned hi = (unsigned)f2bf(v.z) | ((unsigned)f2bf(v.w) << 16);
  *(uint2*)(xall + (size_t)row * 768 + c) = make_uint2(lo, hi);
}

// ---------------- generic bf16 GEMM: C = act(A @ B^T + bias) ----------------
__global__ __launch_bounds__(256) void gemm_bt(const u16* __restrict__ A, int lda, const u16* __restrict__ B,
                                               int ldb, u16* __restrict__ C, int ldc,
                                               const float* __restrict__ bias, int K, int relu) {
  __shared__ u16 As[64 * 40];
  __shared__ u16 Bs[64 * 40];
  const int tid = threadIdx.x, lane = tid & 63, wv = tid >> 6;
  const int wr = wv >> 1, wc = wv & 1;
  const int m0 = blockIdx.x * 64, n0 = blockIdx.y * 64;
  const int lr = tid >> 2, lc = (tid & 3) * 8;
  f32x4 z = {0.f, 0.f, 0.f, 0.f};
  f32x4 acc[2][2] = {{z, z}, {z, z}};
  const u16* Ap = A + (size_t)(m0 + lr) * lda + lc;
  const u16* Bp = B + (size_t)(n0 + lr) * ldb + lc;
  for (int k0 = 0; k0 < K; k0 += 32) {
    int4 av = *(const int4*)(Ap + k0);
    int4 bv = *(const int4*)(Bp + k0);
    __syncthreads();
    *(int4*)(As + lr * 40 + lc) = av;
    *(int4*)(Bs + lr * 40 + lc) = bv;
    __syncthreads();
#pragma unroll
    for (int mi = 0; mi < 2; mi++) {
      bf16x8 af = *(const bf16x8*)(As + (wr * 32 + mi * 16 + (lane & 15)) * 40 + (lane >> 4) * 8);
#pragma unroll
      for (int ni = 0; ni < 2; ni++) {
        bf16x8 bf = *(const bf16x8*)(Bs + (wc * 32 + ni * 16 + (lane & 15)) * 40 + (lane >> 4) * 8);
        acc[mi][ni] = MFMA16(af, bf, acc[mi][ni]);
      }
    }
  }
#pragma unroll
  for (int mi = 0; mi < 2; mi++)
#pragma unroll
    for (int ni = 0; ni < 2; ni++) {
      int n = n0 + wc * 32 + ni * 16 + (lane & 15);
      float bs = bias ? bias[n] : 0.f;
#pragma unroll
      for (int r = 0; r < 4; r++) {
        int m = m0 + wr * 32 + mi * 16 + (lane >> 4) * 4 + r;
        float x = acc[mi][ni][r] + bs;
        if (relu) x = fmaxf(x, 0.f);
        C[(size_t)m * ldc + n] = f2bf(x);
      }
    }
}

// ---------------- final projection ----------------
__global__ __launch_bounds__(256) void out_proj(const u16* __restrict__ zs, const u16* __restrict__ Wb,
                                                const float* __restrict__ bout, float* __restrict__ out) {
  int wv = threadIdx.x >> 6, lane = threadIdx.x & 63;
  int tile = blockIdx.x * 4 + wv;  // 5120 tiles = 1024 m-tiles x 5 n-tiles
  int mt = tile / 5, nt = tile - mt * 5;
  int m0 = mt * 16, n0 = nt * 16;
  const u16* ap = zs + (size_t)(m0 + (lane & 15)) * 1024 + (lane >> 4) * 8;
  const u16* bp = Wb + (size_t)(n0 + (lane & 15)) * 1024 + (lane >> 4) * 8;
  f32x4 acc = {0.f, 0.f, 0.f, 0.f};
  for (int k = 0; k < 1024; k += 32) {
    bf16x8 a = *(const bf16x8*)(ap + k);
    bf16x8 b = *(const bf16x8*)(bp + k);
    acc = MFMA16(a, b, acc);
  }
  int n = n0 + (lane & 15);
  float bb = bout[n];
#pragma unroll
  for (int r = 0; r < 4; r++) {
    int m = m0 + (lane >> 4) * 4 + r;
    int t = m >> 4, b = m & 15;
    out[(size_t)b * 81920 + t * 80 + n] = acc[r] + bb;
  }
}

// ---------------- persistent recurrent kernel ----------------
struct RecP {
  const u16 *g0, *whh0b, *wih1b, *whh1b, *wp0b, *wp1b;
  const float *b1s, *bp0, *bp1, *lng0, *lnb0, *lng1, *lnb1;
  u16 *zs, *za_all, *hall;  // hall row t (131072B): h0 @+0, h1 @+16384, zb @+32768 (u16 elems)
  int *flag0, *flag1;
};

#define SLICE 1032
#define OFF_PARTIAL 132096
#define OFF_GATES 140288
#define OFF_RED1 142336
#define OFF_RED2 143360
#define OFF_MUSIG 144384
#define OFF_C 144512
#define SMEM_BYTES 145024

__global__ __launch_bounds__(256, 1) void recurrent(RecP p) {
  extern __shared__ char smem[];
  u16* wA = (u16*)smem;       // l0: Whh0 slice (32 rows) | l1: Wih1 slice
  u16* wB = wA + 32 * SLICE;  // l0: Wp0 slice (16 rows, 8 real) | l1: Whh1 slice
  float* partial = (float*)(smem + OFF_PARTIAL);  // 2048 f
  float* gates2 = (float*)(smem + OFF_GATES);     // 512 f
  float* red1 = (float*)(smem + OFF_RED1);        // 256 f
  float* red2 = (float*)(smem + OFF_RED2);        // 256 f
  float* musig = (float*)(smem + OFF_MUSIG);      // 32 f
  float* cs = (float*)(smem + OFF_C);             // 128 f

  const int w = blockIdx.x, tid = threadIdx.x;
  const int lane = tid & 63, wv = tid >> 6;
  const int bl = lane & 15, q = lane >> 4;
  const bool grp0 = (w < 128);
  const int wl = grp0 ? w : (w - 128);

  // ---- stage weights (once). WG owns hidden cols 8*wl..8*wl+7.
  {
    int r = tid >> 3, kp = tid & 7;  // 32 rows, 8 threads/row
    int gN = (r >> 3) * 1024 + (wl << 3) + (r & 7);
    const u16* srcA = grp0 ? p.whh0b : p.wih1b;
#pragma unroll
    for (int i = 0; i < 16; i++) {
      int k = kp * 128 + i * 8;
      *(int4*)(wA + r * SLICE + k) = *(const int4*)(srcA + (size_t)gN * 1024 + k);
    }
    if (!grp0) {
#pragma unroll
      for (int i = 0; i < 16; i++) {
        int k = kp * 128 + i * 8;
        *(int4*)(wB + r * SLICE + k) = *(const int4*)(p.whh1b + (size_t)gN * 1024 + k);
      }
    } else {
      int r2 = tid >> 4, kp2 = tid & 15;  // 16 rows (8 real + 8 zero), 16 thr/row
      int4 z4 = make_int4(0, 0, 0, 0);
#pragma unroll
      for (int i = 0; i < 8; i++) {
        int k = kp2 * 64 + i * 8;
        int4 v = z4;
        if (r2 < 8) v = *(const int4*)(p.wp0b + (size_t)((wl << 3) + r2) * 1024 + k);
        *(int4*)(wB + r2 * SLICE + k) = v;
      }
    }
    if (tid < 128) cs[tid] = 0.f;
  }
  __syncthreads();

  // per-thread invariants
  const int nl0 = tid >> 4, be = tid & 15;
  const int gN0 = (nl0 >> 3) * 1024 + (wl << 3) + (nl0 & 7);
  const int gN1 = ((nl0 + 16) >> 3) * 1024 + (wl << 3) + ((nl0 + 16) & 7);
  const float bp0v = p.bp0[(wl << 3) + ((tid >> 4) & 7)];
  const float bp1v = p.bp1[(wl << 3) + ((tid >> 4) & 7)];
  const float b1a = p.b1s[gN0], b1b = p.b1s[gN1];

  if (grp0) {
    // ================= layer 0 =================
    // g0 software pipeline: bypass loads (g0 rows get overwritten at t+1 by
    // hall[t] — must never be cached). Prefetch t+1 during S1(t); the barrier's
    // vmcnt(0) guarantees arrival before use.
    unsigned gc0 = 0, gc1 = 0, gn0 = 0, gn1 = 0;
    asm volatile("global_load_ushort %0, %2, off sc0 sc1\n\t"
                 "global_load_ushort %1, %3, off sc0 sc1\n\t"
                 "s_waitcnt vmcnt(0)"
                 : "=&v"(gc0), "=&v"(gc1)
                 : "v"((const void*)(p.g0 + (size_t)be * 4096 + gN0)),
                   "v"((const void*)(p.g0 + (size_t)be * 4096 + gN1))
                 : "memory");

    for (int t = 0; t < 1024; ++t) {
      u16* hx0 = p.hall + (size_t)t * 65536;  // h0 stream row t

      // ---- S1: gates0 = G0[t] + za(t-1) @ Whh0^T ; cell0 -> h0
      if (t > 0) {
        const u16* zap = p.za_all + (size_t)(t - 1) * 16384 + bl * 1024 + (wv << 8) + (q << 3);
        bf16x8 av[8];
        load8s(av, zap);
        f32x4 acc0 = {0.f, 0.f, 0.f, 0.f}, acc1 = acc0;
#pragma unroll
        for (int c = 0; c < 8; c++) {
          int k = (wv << 8) + (c << 5) + (q << 3);
          acc0 = MFMA16(av[c], *(const bf16x8*)(wA + bl * SLICE + k), acc0);
          acc1 = MFMA16(av[c], *(const bf16x8*)(wA + (16 + bl) * SLICE + k), acc1);
        }
        *(f32x4*)(partial + (wv << 9) + (bl << 4) + (q << 2)) = acc0;
        *(f32x4*)(partial + (wv << 9) + ((16 + bl) << 4) + (q << 2)) = acc1;
      }
      if (t < 1023) {
        asm volatile("global_load_ushort %0, %2, off sc0 sc1\n\t"
                     "global_load_ushort %1, %3, off sc0 sc1"
                     : "=&v"(gn0), "=&v"(gn1)
                     : "v"((const void*)(p.g0 + (size_t)(((t + 1) << 4) | be) * 4096 + gN0)),
                       "v"((const void*)(p.g0 + (size_t)(((t + 1) << 4) | be) * 4096 + gN1))
                     : "memory");
      }
      __syncthreads();
      {
        float s0 = bf2f((u16)gc0), s1 = bf2f((u16)gc1);
        if (t > 0) {
          int e0 = tid, e1 = tid + 256;
          s0 += partial[e0] + partial[512 + e0] + partial[1024 + e0] + partial[1536 + e0];
          s1 += partial[e1] + partial[512 + e1] + partial[1024 + e1] + partial[1536 + e1];
        }
        gates2[tid] = s0;
        gates2[tid + 256] = s1;
      }
      __syncthreads();
      if (tid < 128) {
        int jj = tid >> 4, b = tid & 15;
        float xi = gates2[(jj)*16 + b];
        float xf = gates2[(8 + jj) * 16 + b];
        float xg = gates2[(16 + jj) * 16 + b];
        float xo = gates2[(24 + jj) * 16 + b];
        float c = cs[tid];
        float cn = sigf(xf) * c + sigf(xi) * tanhf(xg);
        cs[tid] = cn;
        gstore16(hx0 + b * 1024 + (wl << 3) + jj, f2bf(sigf(xo) * tanhf(cn)));
      }
      bar_grp(p.flag0, 2 * t + 1, wl, tid);  // vmcnt(0) inside also retires gn*

      // ---- S2: za(t) = tanh(LN(h0) @ Wp0^T + bp0)
      {
        int sb = tid & 15, sg = tid >> 4;
        bf16x8 dc[8], dv[8];
        load8c(dc, hx0 + sb * 1024 + (sg << 6));
        load8s(dv, hx0 + bl * 1024 + (wv << 8) + (q << 3));
        float sm = 0.f, sq = 0.f;
#pragma unroll
        for (int i = 0; i < 8; i++)
#pragma unroll
          for (int j = 0; j < 8; j++) {
            float x = bf2f((u16)dc[i][j]);
            sm += x;
            sq += x * x;
          }
        red1[sb * 16 + sg] = sm;
        red2[sb * 16 + sg] = sq;
        __syncthreads();
        if (tid < 64) {
          int b2 = tid >> 2, g2 = tid & 3;
          float s = red1[b2 * 16 + g2 * 4] + red1[b2 * 16 + g2 * 4 + 1] + red1[b2 * 16 + g2 * 4 + 2] +
                    red1[b2 * 16 + g2 * 4 + 3];
          float qq = red2[b2 * 16 + g2 * 4] + red2[b2 * 16 + g2 * 4 + 1] + red2[b2 * 16 + g2 * 4 + 2] +
                     red2[b2 * 16 + g2 * 4 + 3];
          s += __shfl_xor(s, 1);
          s += __shfl_xor(s, 2);
          qq += __shfl_xor(qq, 1);
          qq += __shfl_xor(qq, 2);
          if (g2 == 0) {
            float mu = s * (1.f / 1024.f);
            float var = qq * (1.f / 1024.f) - mu * mu;
            musig[b2] = mu;
            musig[16 + b2] = rsqrtf(var + 1e-5f);
          }
        }
        __syncthreads();
        float mu = musig[bl], rs = musig[16 + bl];
        f32x4 acc = {0.f, 0.f, 0.f, 0.f};
#pragma unroll
        for (int c = 0; c < 8; c++) {
          int k = (wv << 8) + (c << 5) + (q << 3);
          float4 ga = *(const float4*)(p.lng0 + k);
          float4 gb = *(const float4*)(p.lng0 + k + 4);
          float4 ba = *(const float4*)(p.lnb0 + k);
          float4 bb = *(const float4*)(p.lnb0 + k + 4);
          bf16x8 a;
          a[0] = (short)f2bf((bf2f((u16)dv[c][0]) - mu) * rs * ga.x + ba.x);
          a[1] = (short)f2bf((bf2f((u16)dv[c][1]) - mu) * rs * ga.y + ba.y);
          a[2] = (short)f2bf((bf2f((u16)dv[c][2]) - mu) * rs * ga.z + ba.z);
          a[3] = (short)f2bf((bf2f((u16)dv[c][3]) - mu) * rs * ga.w + ba.w);
          a[4] = (short)f2bf((bf2f((u16)dv[c][4]) - mu) * rs * gb.x + bb.x);
          a[5] = (short)f2bf((bf2f((u16)dv[c][5]) - mu) * rs * gb.y + bb.y);
          a[6] = (short)f2bf((bf2f((u16)dv[c][6]) - mu) * rs * gb.z + bb.z);
          a[7] = (short)f2bf((bf2f((u16)dv[c][7]) - mu) * rs * gb.w + bb.w);
          acc = MFMA16(a, *(const bf16x8*)(wB + bl * SLICE + k), acc);
        }
        *(f32x4*)(partial + (wv << 8) + (bl << 4) + (q << 2)) = acc;
      }
      __syncthreads();
      if (tid < 128) {
        int nl = tid >> 4, b = tid & 15;
        float s = partial[nl * 16 + b] + partial[256 + nl * 16 + b] + partial[512 + nl * 16 + b] +
                  partial[768 + nl * 16 + b] + bp0v;
        gstore16(p.za_all + (size_t)t * 16384 + b * 1024 + (wl << 3) + nl, f2bf(tanhf(s)));
      }
      bar_grp(p.flag0, 2 * t + 2, wl, tid);
      gc0 = gn0;
      gc1 = gn1;
    }
  } else {
    // ================= layer 1 =================
    for (int t = 0; t < 1024; ++t) {
      u16* hx = p.hall + (size_t)t * 65536;  // h1 @+16384, zb @+32768
      wait_flags(p.flag0, 2 * t + 2, tid);   // za(t) published by layer0

      // ---- S3: gates1 = za(t) @ Wih1^T + zb(t-1) @ Whh1^T + b ; cell1 -> h1
      {
        const u16* zap = p.za_all + (size_t)t * 16384 + bl * 1024 + (wv << 8) + (q << 3);
        bf16x8 a1[8];
        load8s(a1, zap);
        f32x4 acc0 = {0.f, 0.f, 0.f, 0.f}, acc1 = acc0;
        if (t > 0) {
          const u16* zbp = p.hall + (size_t)(t - 1) * 65536 + 32768 + bl * 1024 + (wv << 8) + (q << 3);
          bf16x8 a2[8];
          load8s(a2, zbp);
#pragma unroll
          for (int c = 0; c < 8; c++) {
            int k = (wv << 8) + (c << 5) + (q << 3);
            acc0 = MFMA16(a1[c], *(const bf16x8*)(wA + bl * SLICE + k), acc0);
            acc1 = MFMA16(a1[c], *(const bf16x8*)(wA + (16 + bl) * SLICE + k), acc1);
            acc0 = MFMA16(a2[c], *(const bf16x8*)(wB + bl * SLICE + k), acc0);
            acc1 = MFMA16(a2[c], *(const bf16x8*)(wB + (16 + bl) * SLICE + k), acc1);
          }
        } else {
#pragma unroll
          for (int c = 0; c < 8; c++) {
            int k = (wv << 8) + (c << 5) + (q << 3);
            acc0 = MFMA16(a1[c], *(const bf16x8*)(wA + bl * SLICE + k), acc0);
            acc1 = MFMA16(a1[c], *(const bf16x8*)(wA + (16 + bl) * SLICE + k), acc1);
          }
        }
        *(f32x4*)(partial + (wv << 9) + (bl << 4) + (q << 2)) = acc0;
        *(f32x4*)(partial + (wv << 9) + ((16 + bl) << 4) + (q << 2)) = acc1;
      }
      __syncthreads();
      {
        int e0 = tid, e1 = tid + 256;
        float s0 = partial[e0] + partial[512 + e0] + partial[1024 + e0] + partial[1536 + e0] + b1a;
        float s1 = partial[e1] + partial[512 + e1] + partial[1024 + e1] + partial[1536 + e1] + b1b;
        gates2[e0] = s0;
        gates2[e1] = s1;
      }
      __syncthreads();
      if (tid < 128) {
        int jj = tid >> 4, b = tid & 15;
        float xi = gates2[(jj)*16 + b];
        float xf = gates2[(8 + jj) * 16 + b];
        float xg = gates2[(16 + jj) * 16 + b];
        float xo = gates2[(24 + jj) * 16 + b];
        float c = cs[tid];
        float cn = sigf(xf) * c + sigf(xi) * tanhf(xg);
        cs[tid] = cn;
        gstore16(hx + 16384 + b * 1024 + (wl << 3) + jj, f2bf(sigf(xo) * tanhf(cn)));
      }
      bar_grp(p.flag1, 2 * t + 1, wl, tid);

      // ---- S4: zb(t) = tanh(LN(h1) @ Wp1^T + bp1) ; zs[t] = zb
      {
        int sb = tid & 15, sg = tid >> 4;
        const u16* h1p = hx + 16384;
        bf16x8 dc[8], dv[8];
        load8c(dc, h1p + sb * 1024 + (sg << 6));
        load8s(dv, h1p + bl * 1024 + (wv << 8) + (q << 3));
        float sm = 0.f, sq = 0.f;
#pragma unroll
        for (int i = 0; i < 8; i++)
#pragma unroll
          for (int j = 0; j < 8; j++) {
            float x = bf2f((u16)dc[i][j]);
            sm += x;
            sq += x * x;
          }
        red1[sb * 16 + sg] = sm;
        red2[sb * 16 + sg] = sq;
        __syncthreads();
        if (tid < 64) {
          int b2 = tid >> 2, g2 = tid & 3;
          float s = red1[b2 * 16 + g2 * 4] + red1[b2 * 16 + g2 * 4 + 1] + red1[b2 * 16 + g2 * 4 + 2] +
                    red1[b2 * 16 + g2 * 4 + 3];
          float qq = red2[b2 * 16 + g2 * 4] + red2[b2 * 16 + g2 * 4 + 1] + red2[b2 * 16 + g2 * 4 + 2] +
                     red2[b2 * 16 + g2 * 4 + 3];
          s += __shfl_xor(s, 1);
          s += __shfl_xor(s, 2);
          qq += __shfl_xor(qq, 1);
          qq += __shfl_xor(qq, 2);
          if (g2 == 0) {
            float mu = s * (1.f / 1024.f);
            float var = qq * (1.f / 1024.f) - mu * mu;
            musig[b2] = mu;
            musig[16 + b2] = rsqrtf(var + 1e-5f);
          }
        }
        __syncthreads();
        float mu = musig[bl], rs = musig[16 + bl];
        f32x4 acc = {0.f, 0.f, 0.f, 0.f};
        const u16* wpp = p.wp1b + (size_t)((wl << 3) + (bl & 7)) * 1024;  // plain loads, L2-hot
        bf16x8 z8 = {0, 0, 0, 0, 0, 0, 0, 0};
#pragma unroll
        for (int c = 0; c < 8; c++) {
          int k = (wv << 8) + (c << 5) + (q << 3);
          float4 ga = *(const float4*)(p.lng1 + k);
          float4 gb = *(const float4*)(p.lng1 + k + 4);
          float4 ba = *(const float4*)(p.lnb1 + k);
          float4 bb = *(const float4*)(p.lnb1 + k + 4);
          bf16x8 a;
          a[0] = (short)f2bf((bf2f((u16)dv[c][0]) - mu) * rs * ga.x + ba.x);
          a[1] = (short)f2bf((bf2f((u16)dv[c][1]) - mu) * rs * ga.y + ba.y);
          a[2] = (short)f2bf((bf2f((u16)dv[c][2]) - mu) * rs * ga.z + ba.z);
          a[3] = (short)f2bf((bf2f((u16)dv[c][3]) - mu) * rs * ga.w + ba.w);
          a[4] = (short)f2bf((bf2f((u16)dv[c][4]) - mu) * rs * gb.x + bb.x);
          a[5] = (short)f2bf((bf2f((u16)dv[c][5]) - mu) * rs * gb.y + bb.y);
          a[6] = (short)f2bf((bf2f((u16)dv[c][6]) - mu) * rs * gb.z + bb.z);
          a[7] = (short)f2bf((bf2f((u16)dv[c][7]) - mu) * rs * gb.w + bb.w);
          bf16x8 bw = *(const bf16x8*)(wpp + k);
          if (bl >= 8) bw = z8;
          acc = MFMA16(a, bw, acc);
        }
        *(f32x4*)(partial + (wv << 8) + (bl << 4) + (q << 2)) = acc;
      }
      __syncthreads();
      if (tid < 128) {
        int nl = tid >> 4, b = tid & 15;
        float s = partial[nl * 16 + b] + partial[256 + nl * 16 + b] + partial[512 + nl * 16 + b] +
                  partial[768 + nl * 16 + b] + bp1v;
        u16 u = f2bf(tanhf(s));
        gstore16(hx + 32768 + b * 1024 + (wl << 3) + nl, u);        // zb stream row t
        p.zs[(size_t)((t << 4) | b) * 1024 + (wl << 3) + nl] = u;   // plain: read post-kernel
      }
      bar_grp(p.flag1, 2 * t + 2, wl, tid);
    }
  }
}

// ---------------- host ----------------
extern "C" void kernel_launch(void* const* d_in, const int* in_sizes, int n_in, void* d_out, int out_size,
                              void* d_ws, size_t ws_size, hipStream_t stream) {
  const float* cond = (const float*)d_in[0];
  const float* targets = (const float*)d_in[1];
  const float* tmean = (const float*)d_in[2];
  const float* tscale = (const float*)d_in[3];
  const float* Wpre1 = (const float*)d_in[4];
  const float* bpre1 = (const float*)d_in[5];
  const float* Wpre2 = (const float*)d_in[6];
  const float* bpre2 = (const float*)d_in[7];
  const float* Wih0 = (const float*)d_in[8];
  const float* Whh0 = (const float*)d_in[9];
  const float* bih0 = (const float*)d_in[10];
  const float* bhh0 = (const float*)d_in[11];
  const float* lng0 = (const float*)d_in[12];
  const float* lnb0 = (const float*)d_in[13];
  const float* Wp0 = (const float*)d_in[14];
  const float* bp0 = (const float*)d_in[15];
  const float* Wih1 = (const float*)d_in[16];
  const float* Whh1 = (const float*)d_in[17];
  const float* bih1 = (const float*)d_in[18];
  const float* bhh1 = (const float*)d_in[19];
  const float* lng1 = (const float*)d_in[20];
  const float* lnb1 = (const float*)d_in[21];
  const float* Wp1 = (const float*)d_in[22];
  const float* bp1 = (const float*)d_in[23];
  const float* Wout = (const float*)d_in[24];
  const float* bout = (const float*)d_in[25];

  char* ws = (char*)d_ws;
  int* flag0 = (int*)(ws + 0);         // 512B
  int* flag1 = (int*)(ws + 1024);      // 512B
  float* b0s = (float*)(ws + 102400);  // bih0+bhh0 (16KB)
  float* b1s = (float*)(ws + 118784);  // bih1+bhh1 (16KB)
  u16* woutb = (u16*)(ws + 135168);    // 160KB
  u16* wpre1b = (u16*)(ws + 299008);
  u16* wpre2b = (u16*)(ws + 348160);
  u16* wih0b = (u16*)(ws + 479232);
  u16* whh0b = (u16*)(ws + 6770688);
  u16* wih1b = (u16*)(ws + 15159296);
  u16* whh1b = (u16*)(ws + 23547904);
  u16* wp0b = (u16*)(ws + 31936512);
  u16* wp1b = (u16*)(ws + 34033664);
  u16* prevp = (u16*)(ws + 36130816);   // (T*B,96)  -- prep-only
  u16* hpre = (u16*)(ws + 39276544);    // (T*B,256) -- prep-only
  u16* xall = (u16*)(ws + 47665152);    // (T*B,768) -- prep-only
  u16* g0 = (u16*)(ws + 72830976);      // (T*B,4096)
  u16* zs = (u16*)(ws + 207048704);     // (T*B,1024)
  u16* za_all = (u16*)(ws + 36130816);  // 1024 x 32KB -- overlays prep buffers (dead by then)
  u16* hall = (u16*)(ws + 72699904);    // row t = g0 row t-1 (128KB, consumed at t-1)

  hipMemsetAsync(ws, 0, 4096, stream);  // flags

  cvt_wpre1<<<96, 256, 0, stream>>>(Wpre1, wpre1b);
  cvt<<<64, 256, 0, stream>>>(Wpre2, wpre2b, 65536);
  cvt<<<3072, 256, 0, stream>>>(Wih0, wih0b, 3145728);
  cvt<<<4096, 256, 0, stream>>>(Whh0, whh0b, 4194304);
  cvt<<<4096, 256, 0, stream>>>(Wih1, wih1b, 4194304);
  cvt<<<4096, 256, 0, stream>>>(Whh1, whh1b, 4194304);
  cvt<<<1024, 256, 0, stream>>>(Wp0, wp0b, 1048576);
  cvt<<<1024, 256, 0, stream>>>(Wp1, wp1b, 1048576);
  cvt<<<80, 256, 0, stream>>>(Wout, woutb, 81920);
  bsum<<<16, 256, 0, stream>>>(bih0, bhh0, b0s);
  bsum<<<16, 256, 0, stream>>>(bih1, bhh1, b1s);
  pack_prev<<<6144, 256, 0, stream>>>(targets, tmean, tscale, prevp);
  pack_cond<<<8192, 256, 0, stream>>>(cond, xall);

  gemm_bt<<<dim3(256, 4), 256, 0, stream>>>(prevp, 96, wpre1b, 96, hpre, 256, bpre1, 96, 1);
  gemm_bt<<<dim3(256, 4), 256, 0, stream>>>(hpre, 256, wpre2b, 256, xall + 512, 768, bpre2, 256, 1);
  gemm_bt<<<dim3(256, 64), 256, 0, stream>>>(xall, 768, wih0b, 768, g0, 4096, b0s, 768, 0);

  RecP rp;
  rp.g0 = g0;
  rp.whh0b = whh0b;
  rp.wih1b = wih1b;
  rp.whh1b = whh1b;
  rp.wp0b = wp0b;
  rp.wp1b = wp1b;
  rp.b1s = b1s;
  rp.bp0 = bp0;
  rp.bp1 = bp1;
  rp.lng0 = lng0;
  rp.lnb0 = lnb0;
  rp.lng1 = lng1;
  rp.lnb1 = lnb1;
  rp.zs = zs;
  rp.za_all = za_all;
  rp.hall = hall;
  rp.flag0 = flag0;
  rp.flag1 = flag1;

  hipFuncSetAttribute(reinterpret_cast<const void*>(recurrent), hipFuncAttributeMaxDynamicSharedMemorySize,
                      SMEM_BYTES);
  recurrent<<<dim3(256), dim3(256), SMEM_BYTES, stream>>>(rp);

  out_proj<<<1280, 256, 0, stream>>>(zs, woutb, bout, (float*)d_out);
}

// Round 7
// 15804.909 us; speedup vs baseline: 10.4286x; 1.1025x over previous
//
#include <hip/hip_runtime.h>

// LSTM decoder (B=16,T=1024,CI=512,AR=256,H=1024,DO=80) for MI355X.
// R7 = R6 with the asm type fix: 128-bit asm operands use a native
// ext_vector_type(4) int (i32x4) — HIP's struct int4 is rejected as an
// inline-asm INPUT ("indirect register inputs", gfx950 clang).
// R6 changes under test: packed 16B cross-WG publishes (LDS transpose ->
// 16 dwordx4 stores/WG vs 128 scattered 2B), vectorized g0 tile loads
// (64x16B via LDS, software-pipelined), LN stats folded into dv fragments.
//   WGs 0..127  = layer0: S1 (cell0, Whh0 LDS) -> S2 (LN+Wp0 LDS) -> za_all[t]
//   WGs 128..255= layer1: S3 (cell1, Wih1+Whh1 LDS) -> S4 (LN+Wp1 L2) -> zb, zs
// Cross-WG data: producers store sc0+sc1 (write-through to IF$ = coherence
// point), readers load plain cached AFTER flag detect (write-once streams).

typedef unsigned short u16;
typedef short bf16x8 __attribute__((ext_vector_type(8)));
typedef float f32x4 __attribute__((ext_vector_type(4)));
typedef int i32x4 __attribute__((ext_vector_type(4)));

#define MFMA16(a, b, c) __builtin_amdgcn_mfma_f32_16x16x32_bf16((a), (b), (c), 0, 0, 0)

__device__ __forceinline__ u16 f2bf(float x) {
  unsigned u = __float_as_uint(x);
  return (u16)((u + 0x7fffu + ((u >> 16) & 1u)) >> 16);  // RNE
}
__device__ __forceinline__ float bf2f(u16 h) { return __uint_as_float(((unsigned)h) << 16); }
__device__ __forceinline__ float sigf(float x) { return 1.f / (1.f + __expf(-x)); }

__device__ __forceinline__ void gstore32(int* p, int v) {
  asm volatile("global_store_dword %0, %1, off sc0 sc1" ::"v"((void*)p), "v"(v) : "memory");
}
__device__ __forceinline__ void gstore128(u16* p, i32x4 v) {
  asm volatile("global_store_dwordx4 %0, %1, off sc0 sc1" ::"v"((void*)p), "v"(v) : "memory");
}

// plain cached fragment loads: 8 x 16B at 64B stride (MFMA A-operand walk)
__device__ __forceinline__ void load8s(bf16x8 d[8], const u16* p) {
#pragma unroll
  for (int c = 0; c < 8; c++) d[c] = *(const bf16x8*)(p + (c << 5));
}

// Poll 128 packed flags (8 lines) with wave 0: 32 lanes x dwordx4, s_sleep pacing.
__device__ __forceinline__ void wait_flags(const int* flags, int e, int tid) {
  if (tid < 64) {
    const i32x4* fp = (const i32x4*)flags + (tid & 31);
    for (;;) {
      i32x4 f;
      asm volatile("global_load_dwordx4 %0, %1, off sc0 sc1\n\ts_waitcnt vmcnt(0)"
                   : "=&v"(f)
                   : "v"((const void*)fp)
                   : "memory");
      int ok = (f[0] >= e) & (f[1] >= e) & (f[2] >= e) & (f[3] >= e);
      if (__all(ok)) break;
      __builtin_amdgcn_s_sleep(2);
    }
  }
  __syncthreads();
}

// Intra-group barrier among 128 WGs: drain own stores, publish epoch, poll.
__device__ __forceinline__ void bar_grp(int* flags, int e, int wl, int tid) {
  asm volatile("s_waitcnt vmcnt(0)" ::: "memory");
  __syncthreads();
  if (tid == 0) gstore32(flags + wl, e);
  wait_flags(flags, e, tid);
}

// ---------------- prep kernels ----------------
__global__ __launch_bounds__(256) void cvt(const float* __restrict__ s, u16* __restrict__ d, int n) {
  int i = (blockIdx.x * 256 + threadIdx.x) * 4;
  if (i < n) {
    float4 v = *(const float4*)(s + i);
    unsigned lo = (unsigned)f2bf(v.x) | ((unsigned)f2bf(v.y) << 16);
    unsigned hi = (unsigned)f2bf(v.z) | ((unsigned)f2bf(v.w) << 16);
    *(uint2*)(d + i) = make_uint2(lo, hi);
  }
}

__global__ __launch_bounds__(256) void cvt_wpre1(const float* __restrict__ s, u16* __restrict__ d) {
  int i = blockIdx.x * 256 + threadIdx.x;  // < 256*96
  int r = i / 96, c = i - r * 96;
  d[i] = (c < 80) ? f2bf(s[r * 80 + c]) : (u16)0;
}

__global__ __launch_bounds__(256) void bsum(const float* __restrict__ a, const float* __restrict__ b,
                                            float* __restrict__ o) {
  int i = blockIdx.x * 256 + threadIdx.x;
  if (i < 4096) o[i] = a[i] + b[i];
}

__global__ __launch_bounds__(256) void pack_prev(const float* __restrict__ tg, const float* __restrict__ mean,
                                                 const float* __restrict__ scale, u16* __restrict__ prevp) {
  int i = blockIdx.x * 256 + threadIdx.x;  // < 16384*96
  int row = i / 96, c = i - row * 96;
  int t = row >> 4, b = row & 15;
  float v = 0.f;
  if (c < 80 && t > 0) v = (tg[((size_t)b * 1024 + (t - 1)) * 80 + c] - mean[c]) / scale[c];
  prevp[i] = f2bf(v);
}

__global__ __launch_bounds__(256) void pack_cond(const float* __restrict__ cond, u16* __restrict__ xall) {
  int i = (blockIdx.x * 256 + threadIdx.x) * 4;  // < 16384*512
  int row = i >> 9, c = i & 511;
  int t = row >> 4, b = row & 15;
  float4 v = *(const float4*)(cond + ((size_t)b * 1024 + t) * 512 + c);
  unsigned lo = (unsigned)f2bf(v.x) | ((unsigned)f2bf(v.y) << 16);
  unsigned hi = (unsigned)f2bf(v.z) | ((unsigned)f2bf(v.w) << 16);
  *(uint2*)(xall + (size_t)row * 768 + c) = make_uint2(lo, hi);
}

// ---------------- generic bf16 GEMM: C = act(A @ B^T + bias) ----------------
__global__ __launch_bounds__(256) void gemm_bt(const u16* __restrict__ A, int lda, const u16* __restrict__ B,
                                               int ldb, u16* __restrict__ C, int ldc,
                                               const float* __restrict__ bias, int K, int relu) {
  __shared__ u16 As[64 * 40];
  __shared__ u16 Bs[64 * 40];
  const int tid = threadIdx.x, lane = tid & 63, wv = tid >> 6;
  const int wr = wv >> 1, wc = wv & 1;
  const int m0 = blockIdx.x * 64, n0 = blockIdx.y * 64;
  const int lr = tid >> 2, lc = (tid & 3) * 8;
  f32x4 z = {0.f, 0.f, 0.f, 0.f};
  f32x4 acc[2][2] = {{z, z}, {z, z}};
  const u16* Ap = A + (size_t)(m0 + lr) * lda + lc;
  const u16* Bp = B + (size_t)(n0 + lr) * ldb + lc;
  for (int k0 = 0; k0 < K; k0 += 32) {
    int4 av = *(const int4*)(Ap + k0);
    int4 bv = *(const int4*)(Bp + k0);
    __syncthreads();
    *(int4*)(As + lr * 40 + lc) = av;
    *(int4*)(Bs + lr * 40 + lc) = bv;
    __syncthreads();
#pragma unroll
    for (int mi = 0; mi < 2; mi++) {
      bf16x8 af = *(const bf16x8*)(As + (wr * 32 + mi * 16 + (lane & 15)) * 40 + (lane >> 4) * 8);
#pragma unroll
      for (int ni = 0; ni < 2; ni++) {
        bf16x8 bf = *(const bf16x8*)(Bs + (wc * 32 + ni * 16 + (lane & 15)) * 40 + (lane >> 4) * 8);
        acc[mi][ni] = MFMA16(af, bf, acc[mi][ni]);
      }
    }
  }
#pragma unroll
  for (int mi = 0; mi < 2; mi++)
#pragma unroll
    for (int ni = 0; ni < 2; ni++) {
      int n = n0 + wc * 32 + ni * 16 + (lane & 15);
      float bs = bias ? bias[n] : 0.f;
#pragma unroll
      for (int r = 0; r < 4; r++) {
        int m = m0 + wr * 32 + mi * 16 + (lane >> 4) * 4 + r;
        float x = acc[mi][ni][r] + bs;
        if (relu) x = fmaxf(x, 0.f);
        C[(size_t)m * ldc + n] = f2bf(x);
      }
    }
}

// ---------------- final projection ----------------
__global__ __launch_bounds__(256) void out_proj(const u16* __restrict__ zs, const u16* __restrict__ Wb,
                                                const float* __restrict__ bout, float* __restrict__ out) {
  int wv = threadIdx.x >> 6, lane = threadIdx.x & 63;
  int tile = blockIdx.x * 4 + wv;  // 5120 tiles = 1024 m-tiles x 5 n-tiles
  int mt = tile / 5, nt = tile - mt * 5;
  int m0 = mt * 16, n0 = nt * 16;
  const u16* ap = zs + (size_t)(m0 + (lane & 15)) * 1024 + (lane >> 4) * 8;
  const u16* bp = Wb + (size_t)(n0 + (lane & 15)) * 1024 + (lane >> 4) * 8;
  f32x4 acc = {0.f, 0.f, 0.f, 0.f};
  for (int k = 0; k < 1024; k += 32) {
    bf16x8 a = *(const bf16x8*)(ap + k);
    bf16x8 b = *(const bf16x8*)(bp + k);
    acc = MFMA16(a, b, acc);
  }
  int n = n0 + (lane & 15);
  float bb = bout[n];
#pragma unroll
  for (int r = 0; r < 4; r++) {
    int m = m0 + (lane >> 4) * 4 + r;
    int t = m >> 4, b = m & 15;
    out[(size_t)b * 81920 + t * 80 + n] = acc[r] + bb;
  }
}

// ---------------- persistent recurrent kernel ----------------
struct RecP {
  const u16 *g0, *whh0b, *wih1b, *whh1b, *wp0b, *wp1b;
  const float *b1s, *bp0, *bp1, *lng0, *lnb0, *lng1, *lnb1;
  u16 *zs, *za_all, *hall;  // hall row t (131072B): h0 @u16+0, h1 @u16+16384, zb @u16+32768
  int *flag0, *flag1;
};

#define SLICE 1032
#define OFF_PARTIAL 132096
#define OFF_GATES 140288
#define OFF_RED1 142336
#define OFF_RED2 143360
#define OFF_MUSIG 144384
#define OFF_C 144512
#define OFF_G0S 145024  // 512 u16 (4 gates x 16 b x 8 cols)
#define OFF_HT 146048   // 128 u16 pack tile
#define SMEM_BYTES 146304

__global__ __launch_bounds__(256, 1) void recurrent(RecP p) {
  extern __shared__ char smem[];
  u16* wA = (u16*)smem;       // l0: Whh0 slice (32 rows) | l1: Wih1 slice
  u16* wB = wA + 32 * SLICE;  // l0: Wp0 slice (16 rows, 8 real) | l1: Whh1 slice
  float* partial = (float*)(smem + OFF_PARTIAL);  // 2048 f
  float* gates2 = (float*)(smem + OFF_GATES);     // 512 f
  float* red1 = (float*)(smem + OFF_RED1);        // 256 f
  float* red2 = (float*)(smem + OFF_RED2);        // 256 f
  float* musig = (float*)(smem + OFF_MUSIG);      // 32 f
  float* cs = (float*)(smem + OFF_C);             // 128 f
  u16* g0s = (u16*)(smem + OFF_G0S);              // 512 u16
  u16* htile = (u16*)(smem + OFF_HT);             // 128 u16

  const int w = blockIdx.x, tid = threadIdx.x;
  const int lane = tid & 63, wv = tid >> 6;
  const int bl = lane & 15, q = lane >> 4;
  const bool grp0 = (w < 128);
  const int wl = grp0 ? w : (w - 128);

  // ---- stage weights (once). WG owns hidden cols 8*wl..8*wl+7.
  {
    int r = tid >> 3, kp = tid & 7;  // 32 rows, 8 threads/row
    int gN = (r >> 3) * 1024 + (wl << 3) + (r & 7);
    const u16* srcA = grp0 ? p.whh0b : p.wih1b;
#pragma unroll
    for (int i = 0; i < 16; i++) {
      int k = kp * 128 + i * 8;
      *(int4*)(wA + r * SLICE + k) = *(const int4*)(srcA + (size_t)gN * 1024 + k);
    }
    if (!grp0) {
#pragma unroll
      for (int i = 0; i < 16; i++) {
        int k = kp * 128 + i * 8;
        *(int4*)(wB + r * SLICE + k) = *(const int4*)(p.whh1b + (size_t)gN * 1024 + k);
      }
    } else {
      int r2 = tid >> 4, kp2 = tid & 15;  // 16 rows (8 real + 8 zero), 16 thr/row
      int4 z4 = make_int4(0, 0, 0, 0);
#pragma unroll
      for (int i = 0; i < 8; i++) {
        int k = kp2 * 64 + i * 8;
        int4 v = z4;
        if (r2 < 8) v = *(const int4*)(p.wp0b + (size_t)((wl << 3) + r2) * 1024 + k);
        *(int4*)(wB + r2 * SLICE + k) = v;
      }
    }
    if (tid < 128) cs[tid] = 0.f;
  }
  __syncthreads();

  // per-thread invariants
  const int nl0 = tid >> 4, be = tid & 15;
  const int gN0 = (nl0 >> 3) * 1024 + (wl << 3) + (nl0 & 7);
  const int gN1 = ((nl0 + 16) >> 3) * 1024 + (wl << 3) + ((nl0 + 16) & 7);
  const float bp0v = p.bp0[(wl << 3) + ((tid >> 4) & 7)];
  const float bp1v = p.bp1[(wl << 3) + ((tid >> 4) & 7)];
  const float b1a = p.b1s[gN0], b1b = p.b1s[gN1];
  // g0s read indices (gate group from nl0; col nl0&7; batch be)
  const int g0i0 = (((nl0 >> 3) << 4) + be) * 8 + (nl0 & 7);
  const int g0i1 = ((((nl0 >> 3) + 2) << 4) + be) * 8 + (nl0 & 7);

  if (grp0) {
    // ================= layer 0 =================
    i32x4 gcur = {0, 0, 0, 0}, gnext = {0, 0, 0, 0};
    if (tid < 64) {  // tile load: thread (g,b) -> 8 cols of gate-group g
      int g = tid >> 4, b = tid & 15;
      const u16* gp = p.g0 + (size_t)b * 4096 + g * 1024 + (wl << 3);
      asm volatile("global_load_dwordx4 %0, %1, off sc0 sc1\n\ts_waitcnt vmcnt(0)"
                   : "=&v"(gcur)
                   : "v"((const void*)gp)
                   : "memory");
    }

    for (int t = 0; t < 1024; ++t) {
      u16* hx0 = p.hall + (size_t)t * 65536;  // h0 stream row t

      // ---- S1: gates0 = G0[t] + za(t-1) @ Whh0^T ; cell0 -> h0
      if (t > 0) {
        const u16* zap = p.za_all + (size_t)(t - 1) * 16384 + bl * 1024 + (wv << 8) + (q << 3);
        bf16x8 av[8];
        load8s(av, zap);
        f32x4 acc0 = {0.f, 0.f, 0.f, 0.f}, acc1 = acc0;
#pragma unroll
        for (int c = 0; c < 8; c++) {
          int k = (wv << 8) + (c << 5) + (q << 3);
          acc0 = MFMA16(av[c], *(const bf16x8*)(wA + bl * SLICE + k), acc0);
          acc1 = MFMA16(av[c], *(const bf16x8*)(wA + (16 + bl) * SLICE + k), acc1);
        }
        *(f32x4*)(partial + (wv << 9) + (bl << 4) + (q << 2)) = acc0;
        *(f32x4*)(partial + (wv << 9) + ((16 + bl) << 4) + (q << 2)) = acc1;
      }
      if (tid < 64) *(i32x4*)(g0s + (tid << 3)) = gcur;  // distribute g0 tile
      if (t < 1023 && tid < 64) {                         // prefetch next (no wait; bar_grp drains)
        int g = tid >> 4, b = tid & 15;
        const u16* gp = p.g0 + (size_t)(((t + 1) << 4) | b) * 4096 + g * 1024 + (wl << 3);
        asm volatile("global_load_dwordx4 %0, %1, off sc0 sc1"
                     : "=&v"(gnext)
                     : "v"((const void*)gp)
                     : "memory");
      }
      __syncthreads();
      {
        float s0 = bf2f(g0s[g0i0]), s1 = bf2f(g0s[g0i1]);
        if (t > 0) {
          int e0 = tid, e1 = tid + 256;
          s0 += partial[e0] + partial[512 + e0] + partial[1024 + e0] + partial[1536 + e0];
          s1 += partial[e1] + partial[512 + e1] + partial[1024 + e1] + partial[1536 + e1];
        }
        gates2[tid] = s0;
        gates2[tid + 256] = s1;
      }
      __syncthreads();
      if (tid < 128) {
        int jj = tid >> 4, b = tid & 15;
        float xi = gates2[(jj)*16 + b];
        float xf = gates2[(8 + jj) * 16 + b];
        float xg = gates2[(16 + jj) * 16 + b];
        float xo = gates2[(24 + jj) * 16 + b];
        float c = cs[tid];
        float cn = sigf(xf) * c + sigf(xi) * tanhf(xg);
        cs[tid] = cn;
        htile[(b << 3) + jj] = f2bf(sigf(xo) * tanhf(cn));
      }
      __syncthreads();
      if (tid < 16) gstore128(hx0 + tid * 1024 + (wl << 3), *(const i32x4*)(htile + (tid << 3)));
      bar_grp(p.flag0, 2 * t + 1, wl, tid);

      // ---- S2: za(t) = tanh(LN(h0) @ Wp0^T + bp0)
      {
        bf16x8 dv[8];
        load8s(dv, hx0 + bl * 1024 + (wv << 8) + (q << 3));
        float sm = 0.f, sq = 0.f;
#pragma unroll
        for (int i = 0; i < 8; i++)
#pragma unroll
          for (int j = 0; j < 8; j++) {
            float x = bf2f((u16)dv[i][j]);
            sm += x;
            sq += x * x;
          }
        red1[(bl << 4) + (wv << 2) + q] = sm;  // dv fragments tile the full row per bl
        red2[(bl << 4) + (wv << 2) + q] = sq;
        __syncthreads();
        if (tid < 64) {
          int b2 = tid >> 2, g2 = tid & 3;
          float s = red1[b2 * 16 + g2 * 4] + red1[b2 * 16 + g2 * 4 + 1] + red1[b2 * 16 + g2 * 4 + 2] +
                    red1[b2 * 16 + g2 * 4 + 3];
          float qq = red2[b2 * 16 + g2 * 4] + red2[b2 * 16 + g2 * 4 + 1] + red2[b2 * 16 + g2 * 4 + 2] +
                     red2[b2 * 16 + g2 * 4 + 3];
          s += __shfl_xor(s, 1);
          s += __shfl_xor(s, 2);
          qq += __shfl_xor(qq, 1);
          qq += __shfl_xor(qq, 2);
          if (g2 == 0) {
            float mu = s * (1.f / 1024.f);
            float var = qq * (1.f / 1024.f) - mu * mu;
            musig[b2] = mu;
            musig[16 + b2] = rsqrtf(var + 1e-5f);
          }
        }
        __syncthreads();
        float mu = musig[bl], rs = musig[16 + bl];
        f32x4 acc = {0.f, 0.f, 0.f, 0.f};
#pragma unroll
        for (int c = 0; c < 8; c++) {
          int k = (wv << 8) + (c << 5) + (q << 3);
          float4 ga = *(const float4*)(p.lng0 + k);
          float4 gb = *(const float4*)(p.lng0 + k + 4);
          float4 ba = *(const float4*)(p.lnb0 + k);
          float4 bb = *(const float4*)(p.lnb0 + k + 4);
          bf16x8 a;
          a[0] = (short)f2bf((bf2f((u16)dv[c][0]) - mu) * rs * ga.x + ba.x);
          a[1] = (short)f2bf((bf2f((u16)dv[c][1]) - mu) * rs * ga.y + ba.y);
          a[2] = (short)f2bf((bf2f((u16)dv[c][2]) - mu) * rs * ga.z + ba.z);
          a[3] = (short)f2bf((bf2f((u16)dv[c][3]) - mu) * rs * ga.w + ba.w);
          a[4] = (short)f2bf((bf2f((u16)dv[c][4]) - mu) * rs * gb.x + bb.x);
          a[5] = (short)f2bf((bf2f((u16)dv[c][5]) - mu) * rs * gb.y + bb.y);
          a[6] = (short)f2bf((bf2f((u16)dv[c][6]) - mu) * rs * gb.z + bb.z);
          a[7] = (short)f2bf((bf2f((u16)dv[c][7]) - mu) * rs * gb.w + bb.w);
          acc = MFMA16(a, *(const bf16x8*)(wB + bl * SLICE + k), acc);
        }
        *(f32x4*)(partial + (wv << 8) + (bl << 4) + (q << 2)) = acc;
      }
      __syncthreads();
      if (tid < 128) {
        int nl = tid >> 4, b = tid & 15;
        float s = partial[nl * 16 + b] + partial[256 + nl * 16 + b] + partial[512 + nl * 16 + b] +
                  partial[768 + nl * 16 + b] + bp0v;
        htile[(b << 3) + nl] = f2bf(tanhf(s));
      }
      __syncthreads();
      if (tid < 16)
        gstore128(p.za_all + (size_t)t * 16384 + tid * 1024 + (wl << 3), *(const i32x4*)(htile + (tid << 3)));
      bar_grp(p.flag0, 2 * t + 2, wl, tid);
      gcur = gnext;
    }
  } else {
    // ================= layer 1 =================
    for (int t = 0; t < 1024; ++t) {
      u16* hx = p.hall + (size_t)t * 65536;  // h1 @u16+16384, zb @u16+32768
      wait_flags(p.flag0, 2 * t + 2, tid);   // za(t) published by layer0

      // ---- S3: gates1 = za(t) @ Wih1^T + zb(t-1) @ Whh1^T + b ; cell1 -> h1
      {
        const u16* zap = p.za_all + (size_t)t * 16384 + bl * 1024 + (wv << 8) + (q << 3);
        bf16x8 a1[8];
        load8s(a1, zap);
        f32x4 acc0 = {0.f, 0.f, 0.f, 0.f}, acc1 = acc0;
        if (t > 0) {
          const u16* zbp = p.hall + (size_t)(t - 1) * 65536 + 32768 + bl * 1024 + (wv << 8) + (q << 3);
          bf16x8 a2[8];
          load8s(a2, zbp);
#pragma unroll
          for (int c = 0; c < 8; c++) {
            int k = (wv << 8) + (c << 5) + (q << 3);
            acc0 = MFMA16(a1[c], *(const bf16x8*)(wA + bl * SLICE + k), acc0);
            acc1 = MFMA16(a1[c], *(const bf16x8*)(wA + (16 + bl) * SLICE + k), acc1);
            acc0 = MFMA16(a2[c], *(const bf16x8*)(wB + bl * SLICE + k), acc0);
            acc1 = MFMA16(a2[c], *(const bf16x8*)(wB + (16 + bl) * SLICE + k), acc1);
          }
        } else {
#pragma unroll
          for (int c = 0; c < 8; c++) {
            int k = (wv << 8) + (c << 5) + (q << 3);
            acc0 = MFMA16(a1[c], *(const bf16x8*)(wA + bl * SLICE + k), acc0);
            acc1 = MFMA16(a1[c], *(const bf16x8*)(wA + (16 + bl) * SLICE + k), acc1);
          }
        }
        *(f32x4*)(partial + (wv << 9) + (bl << 4) + (q << 2)) = acc0;
        *(f32x4*)(partial + (wv << 9) + ((16 + bl) << 4) + (q << 2)) = acc1;
      }
      __syncthreads();
      {
        int e0 = tid, e1 = tid + 256;
        float s0 = partial[e0] + partial[512 + e0] + partial[1024 + e0] + partial[1536 + e0] + b1a;
        float s1 = partial[e1] + partial[512 + e1] + partial[1024 + e1] + partial[1536 + e1] + b1b;
        gates2[e0] = s0;
        gates2[e1] = s1;
      }
      __syncthreads();
      if (tid < 128) {
        int jj = tid >> 4, b = tid & 15;
        float xi = gates2[(jj)*16 + b];
        float xf = gates2[(8 + jj) * 16 + b];
        float xg = gates2[(16 + jj) * 16 + b];
        float xo = gates2[(24 + jj) * 16 + b];
        float c = cs[tid];
        float cn = sigf(xf) * c + sigf(xi) * tanhf(xg);
        cs[tid] = cn;
        htile[(b << 3) + jj] = f2bf(sigf(xo) * tanhf(cn));
      }
      __syncthreads();
      if (tid < 16) gstore128(hx + 16384 + tid * 1024 + (wl << 3), *(const i32x4*)(htile + (tid << 3)));
      bar_grp(p.flag1, 2 * t + 1, wl, tid);

      // ---- S4: zb(t) = tanh(LN(h1) @ Wp1^T + bp1) ; zs[t] = zb
      {
        const u16* h1p = hx + 16384;
        bf16x8 dv[8];
        load8s(dv, h1p + bl * 1024 + (wv << 8) + (q << 3));
        float sm = 0.f, sq = 0.f;
#pragma unroll
        for (int i = 0; i < 8; i++)
#pragma unroll
          for (int j = 0; j < 8; j++) {
            float x = bf2f((u16)dv[i][j]);
            sm += x;
            sq += x * x;
          }
        red1[(bl << 4) + (wv << 2) + q] = sm;
        red2[(bl << 4) + (wv << 2) + q] = sq;
        __syncthreads();
        if (tid < 64) {
          int b2 = tid >> 2, g2 = tid & 3;
          float s = red1[b2 * 16 + g2 * 4] + red1[b2 * 16 + g2 * 4 + 1] + red1[b2 * 16 + g2 * 4 + 2] +
                    red1[b2 * 16 + g2 * 4 + 3];
          float qq = red2[b2 * 16 + g2 * 4] + red2[b2 * 16 + g2 * 4 + 1] + red2[b2 * 16 + g2 * 4 + 2] +
                     red2[b2 * 16 + g2 * 4 + 3];
          s += __shfl_xor(s, 1);
          s += __shfl_xor(s, 2);
          qq += __shfl_xor(qq, 1);
          qq += __shfl_xor(qq, 2);
          if (g2 == 0) {
            float mu = s * (1.f / 1024.f);
            float var = qq * (1.f / 1024.f) - mu * mu;
            musig[b2] = mu;
            musig[16 + b2] = rsqrtf(var + 1e-5f);
          }
        }
        __syncthreads();
        float mu = musig[bl], rs = musig[16 + bl];
        f32x4 acc = {0.f, 0.f, 0.f, 0.f};
        const u16* wpp = p.wp1b + (size_t)((wl << 3) + (bl & 7)) * 1024;  // plain loads, L2-hot
        bf16x8 z8 = {0, 0, 0, 0, 0, 0, 0, 0};
#pragma unroll
        for (int c = 0; c < 8; c++) {
          int k = (wv << 8) + (c << 5) + (q << 3);
          float4 ga = *(const float4*)(p.lng1 + k);
          float4 gb = *(const float4*)(p.lng1 + k + 4);
          float4 ba = *(const float4*)(p.lnb1 + k);
          float4 bb = *(const float4*)(p.lnb1 + k + 4);
          bf16x8 a;
          a[0] = (short)f2bf((bf2f((u16)dv[c][0]) - mu) * rs * ga.x + ba.x);
          a[1] = (short)f2bf((bf2f((u16)dv[c][1]) - mu) * rs * ga.y + ba.y);
          a[2] = (short)f2bf((bf2f((u16)dv[c][2]) - mu) * rs * ga.z + ba.z);
          a[3] = (short)f2bf((bf2f((u16)dv[c][3]) - mu) * rs * ga.w + ba.w);
          a[4] = (short)f2bf((bf2f((u16)dv[c][4]) - mu) * rs * gb.x + bb.x);
          a[5] = (short)f2bf((bf2f((u16)dv[c][5]) - mu) * rs * gb.y + bb.y);
          a[6] = (short)f2bf((bf2f((u16)dv[c][6]) - mu) * rs * gb.z + bb.z);
          a[7] = (short)f2bf((bf2f((u16)dv[c][7]) - mu) * rs * gb.w + bb.w);
          bf16x8 bw = *(const bf16x8*)(wpp + k);
          if (bl >= 8) bw = z8;
          acc = MFMA16(a, bw, acc);
        }
        *(f32x4*)(partial + (wv << 8) + (bl << 4) + (q << 2)) = acc;
      }
      __syncthreads();
      if (tid < 128) {
        int nl = tid >> 4, b = tid & 15;
        float s = partial[nl * 16 + b] + partial[256 + nl * 16 + b] + partial[512 + nl * 16 + b] +
                  partial[768 + nl * 16 + b] + bp1v;
        htile[(b << 3) + nl] = f2bf(tanhf(s));
      }
      __syncthreads();
      if (tid < 16) {
        i32x4 v = *(const i32x4*)(htile + (tid << 3));
        gstore128(hx + 32768 + tid * 1024 + (wl << 3), v);                 // zb stream row t (bypass)
        *(i32x4*)(p.zs + (size_t)((t << 4) | tid) * 1024 + (wl << 3)) = v;  // plain: read post-kernel
      }
      bar_grp(p.flag1, 2 * t + 2, wl, tid);
    }
  }
}

// ---------------- host ----------------
extern "C" void kernel_launch(void* const* d_in, const int* in_sizes, int n_in, void* d_out, int out_size,
                              void* d_ws, size_t ws_size, hipStream_t stream) {
  const float* cond = (const float*)d_in[0];
  const float* targets = (const float*)d_in[1];
  const float* tmean = (const float*)d_in[2];
  const float* tscale = (const float*)d_in[3];
  const float* Wpre1 = (const float*)d_in[4];
  const float* bpre1 = (const float*)d_in[5];
  const float* Wpre2 = (const float*)d_in[6];
  const float* bpre2 = (const float*)d_in[7];
  const float* Wih0 = (const float*)d_in[8];
  const float* Whh0 = (const float*)d_in[9];
  const float* bih0 = (const float*)d_in[10];
  const float* bhh0 = (const float*)d_in[11];
  const float* lng0 = (const float*)d_in[12];
  const float* lnb0 = (const float*)d_in[13];
  const float* Wp0 = (const float*)d_in[14];
  const float* bp0 = (const float*)d_in[15];
  const float* Wih1 = (const float*)d_in[16];
  const float* Whh1 = (const float*)d_in[17];
  const float* bih1 = (const float*)d_in[18];
  const float* bhh1 = (const float*)d_in[19];
  const float* lng1 = (const float*)d_in[20];
  const float* lnb1 = (const float*)d_in[21];
  const float* Wp1 = (const float*)d_in[22];
  const float* bp1 = (const float*)d_in[23];
  const float* Wout = (const float*)d_in[24];
  const float* bout = (const float*)d_in[25];

  char* ws = (char*)d_ws;
  int* flag0 = (int*)(ws + 0);         // 512B
  int* flag1 = (int*)(ws + 1024);      // 512B
  float* b0s = (float*)(ws + 102400);  // bih0+bhh0 (16KB)
  float* b1s = (float*)(ws + 118784);  // bih1+bhh1 (16KB)
  u16* woutb = (u16*)(ws + 135168);    // 160KB
  u16* wpre1b = (u16*)(ws + 299008);
  u16* wpre2b = (u16*)(ws + 348160);
  u16* wih0b = (u16*)(ws + 479232);
  u16* whh0b = (u16*)(ws + 6770688);
  u16* wih1b = (u16*)(ws + 15159296);
  u16* whh1b = (u16*)(ws + 23547904);
  u16* wp0b = (u16*)(ws + 31936512);
  u16* wp1b = (u16*)(ws + 34033664);
  u16* prevp = (u16*)(ws + 36130816);   // (T*B,96)  -- prep-only
  u16* hpre = (u16*)(ws + 39276544);    // (T*B,256) -- prep-only
  u16* xall = (u16*)(ws + 47665152);    // (T*B,768) -- prep-only
  u16* g0 = (u16*)(ws + 72830976);      // (T*B,4096)
  u16* zs = (u16*)(ws + 207048704);     // (T*B,1024)
  u16* za_all = (u16*)(ws + 36130816);  // 1024 x 32KB -- overlays prep buffers (dead by then)
  u16* hall = (u16*)(ws + 72699904);    // row t = g0 row t-1 (128KB, consumed at t-1)

  hipMemsetAsync(ws, 0, 4096, stream);  // flags

  cvt_wpre1<<<96, 256, 0, stream>>>(Wpre1, wpre1b);
  cvt<<<64, 256, 0, stream>>>(Wpre2, wpre2b, 65536);
  cvt<<<3072, 256, 0, stream>>>(Wih0, wih0b, 3145728);
  cvt<<<4096, 256, 0, stream>>>(Whh0, whh0b, 4194304);
  cvt<<<4096, 256, 0, stream>>>(Wih1, wih1b, 4194304);
  cvt<<<4096, 256, 0, stream>>>(Whh1, whh1b, 4194304);
  cvt<<<1024, 256, 0, stream>>>(Wp0, wp0b, 1048576);
  cvt<<<1024, 256, 0, stream>>>(Wp1, wp1b, 1048576);
  cvt<<<80, 256, 0, stream>>>(Wout, woutb, 81920);
  bsum<<<16, 256, 0, stream>>>(bih0, bhh0, b0s);
  bsum<<<16, 256, 0, stream>>>(bih1, bhh1, b1s);
  pack_prev<<<6144, 256, 0, stream>>>(targets, tmean, tscale, prevp);
  pack_cond<<<8192, 256, 0, stream>>>(cond, xall);

  gemm_bt<<<dim3(256, 4), 256, 0, stream>>>(prevp, 96, wpre1b, 96, hpre, 256, bpre1, 96, 1);
  gemm_bt<<<dim3(256, 4), 256, 0, stream>>>(hpre, 256, wpre2b, 256, xall + 512, 768, bpre2, 256, 1);
  gemm_bt<<<dim3(256, 64), 256, 0, stream>>>(xall, 768, wih0b, 768, g0, 4096, b0s, 768, 0);

  RecP rp;
  rp.g0 = g0;
  rp.whh0b = whh0b;
  rp.wih1b = wih1b;
  rp.whh1b = whh1b;
  rp.wp0b = wp0b;
  rp.wp1b = wp1b;
  rp.b1s = b1s;
  rp.bp0 = bp0;
  rp.bp1 = bp1;
  rp.lng0 = lng0;
  rp.lnb0 = lnb0;
  rp.lng1 = lng1;
  rp.lnb1 = lnb1;
  rp.zs = zs;
  rp.za_all = za_all;
  rp.hall = hall;
  rp.flag0 = flag0;
  rp.flag1 = flag1;

  hipFuncSetAttribute(reinterpret_cast<const void*>(recurrent), hipFuncAttributeMaxDynamicSharedMemorySize,
                      SMEM_BYTES);
  recurrent<<<dim3(256), dim3(256), SMEM_BYTES, stream>>>(rp);

  out_proj<<<1280, 256, 0, stream>>>(zs, woutb, bout, (float*)d_out);
}

// Round 10
// 12780.504 us; speedup vs baseline: 12.8964x; 1.2366x over previous
//
#include <hip/hip_runtime.h>

// LSTM decoder (B=16,T=1024,CI=512,AR=256,H=1024,DO=80) for MI355X.
// R10 = R7 data path + arrival-counter barrier (R8/R9's hierarchical barrier
// hung twice; abandoned). Barrier: each WG drains stores (vmcnt0), does ONE
// device-scope atomicAdd on a per-group counter (executes at IF$ = coherence
// point), and only tid==0 polls the counter line (sc0 sc1) until 128*epoch.
// Poll fan-in drops 64x vs R7 (16384 -> 256 in-flight line requests).
//   WGs 0..127  = layer0: S1 (cell0, Whh0 LDS) -> S2 (LN+Wp0 LDS) -> za_all[t]
//   WGs 128..255= layer1: S3 (cell1, Wih1+Whh1 LDS) -> S4 (LN+Wp1 L2) -> zb, zs
// Cross-WG data: producers store sc0+sc1 (write-through to IF$), readers load
// plain cached AFTER the counter says all 128 arrivals of this epoch are in
// (write-once streams -> no stale-line hazard).

typedef unsigned short u16;
typedef short bf16x8 __attribute__((ext_vector_type(8)));
typedef float f32x4 __attribute__((ext_vector_type(4)));
typedef int i32x4 __attribute__((ext_vector_type(4)));

#define MFMA16(a, b, c) __builtin_amdgcn_mfma_f32_16x16x32_bf16((a), (b), (c), 0, 0, 0)

__device__ __forceinline__ u16 f2bf(float x) {
  unsigned u = __float_as_uint(x);
  return (u16)((u + 0x7fffu + ((u >> 16) & 1u)) >> 16);  // RNE
}
__device__ __forceinline__ float bf2f(u16 h) { return __uint_as_float(((unsigned)h) << 16); }
__device__ __forceinline__ float sigf(float x) { return 1.f / (1.f + __expf(-x)); }

__device__ __forceinline__ void gstore128(u16* p, i32x4 v) {
  asm volatile("global_store_dwordx4 %0, %1, off sc0 sc1" ::"v"((void*)p), "v"(v) : "memory");
}

// plain cached fragment loads: 8 x 16B at 64B stride (MFMA A-operand walk)
__device__ __forceinline__ void load8s(bf16x8 d[8], const u16* p) {
#pragma unroll
  for (int c = 0; c < 8; c++) d[c] = *(const bf16x8*)(p + (c << 5));
}

// Arrival-counter barrier among 128 WGs. Monotone counter; epoch e complete
// when ctr >= 128*e. atomicAdd is device-scope (executes at the memory-side
// coherence point) and is issued only after vmcnt(0) drained this WG's
// sc0sc1 data stores -> counter observation implies data visibility.
__device__ __forceinline__ void cbar(int* ctr, int e, int tid) {
  asm volatile("s_waitcnt vmcnt(0)" ::: "memory");
  __syncthreads();
  if (tid == 0) {
    atomicAdd(ctr, 1);
    const int target = e << 7;
    for (;;) {
      int v;
      asm volatile("global_load_dword %0, %1, off sc0 sc1\n\ts_waitcnt vmcnt(0)"
                   : "=&v"(v)
                   : "v"((const void*)ctr)
                   : "memory");
      if (v >= target) break;
      __builtin_amdgcn_s_sleep(2);
    }
  }
  __syncthreads();
}

// passive wait on another group's counter
__device__ __forceinline__ void wait_c(const int* ctr, int target, int tid) {
  if (tid == 0) {
    for (;;) {
      int v;
      asm volatile("global_load_dword %0, %1, off sc0 sc1\n\ts_waitcnt vmcnt(0)"
                   : "=&v"(v)
                   : "v"((const void*)ctr)
                   : "memory");
      if (v >= target) break;
      __builtin_amdgcn_s_sleep(2);
    }
  }
  __syncthreads();
}

// ---------------- prep kernels ----------------
__global__ __launch_bounds__(256) void cvt(const float* __restrict__ s, u16* __restrict__ d, int n) {
  int i = (blockIdx.x * 256 + threadIdx.x) * 4;
  if (i < n) {
    float4 v = *(const float4*)(s + i);
    unsigned lo = (unsigned)f2bf(v.x) | ((unsigned)f2bf(v.y) << 16);
    unsigned hi = (unsigned)f2bf(v.z) | ((unsigned)f2bf(v.w) << 16);
    *(uint2*)(d + i) = make_uint2(lo, hi);
  }
}

__global__ __launch_bounds__(256) void cvt_wpre1(const float* __restrict__ s, u16* __restrict__ d) {
  int i = blockIdx.x * 256 + threadIdx.x;  // < 256*96
  int r = i / 96, c = i - r * 96;
  d[i] = (c < 80) ? f2bf(s[r * 80 + c]) : (u16)0;
}

__global__ __launch_bounds__(256) void bsum(const float* __restrict__ a, const float* __restrict__ b,
                                            float* __restrict__ o) {
  int i = blockIdx.x * 256 + threadIdx.x;
  if (i < 4096) o[i] = a[i] + b[i];
}

__global__ __launch_bounds__(256) void pack_prev(const float* __restrict__ tg, const float* __restrict__ mean,
                                                 const float* __restrict__ scale, u16* __restrict__ prevp) {
  int i = blockIdx.x * 256 + threadIdx.x;  // < 16384*96
  int row = i / 96, c = i - row * 96;
  int t = row >> 4, b = row & 15;
  float v = 0.f;
  if (c < 80 && t > 0) v = (tg[((size_t)b * 1024 + (t - 1)) * 80 + c] - mean[c]) / scale[c];
  prevp[i] = f2bf(v);
}

__global__ __launch_bounds__(256) void pack_cond(const float* __restrict__ cond, u16* __restrict__ xall) {
  int i = (blockIdx.x * 256 + threadIdx.x) * 4;  // < 16384*512
  int row = i >> 9, c = i & 511;
  int t = row >> 4, b = row & 15;
  float4 v = *(const float4*)(cond + ((size_t)b * 1024 + t) * 512 + c);
  unsigned lo = (unsigned)f2bf(v.x) | ((unsigned)f2bf(v.y) << 16);
  unsigned hi = (unsigned)f2bf(v.z) | ((unsigned)f2bf(v.w) << 16);
  *(uint2*)(xall + (size_t)row * 768 + c) = make_uint2(lo, hi);
}

// ---------------- generic bf16 GEMM: C = act(A @ B^T + bias) ----------------
__global__ __launch_bounds__(256) void gemm_bt(const u16* __restrict__ A, int lda, const u16* __restrict__ B,
                                               int ldb, u16* __restrict__ C, int ldc,
                                               const float* __restrict__ bias, int K, int relu) {
  __shared__ u16 As[64 * 40];
  __shared__ u16 Bs[64 * 40];
  const int tid = threadIdx.x, lane = tid & 63, wv = tid >> 6;
  const int wr = wv >> 1, wc = wv & 1;
  const int m0 = blockIdx.x * 64, n0 = blockIdx.y * 64;
  const int lr = tid >> 2, lc = (tid & 3) * 8;
  f32x4 z = {0.f, 0.f, 0.f, 0.f};
  f32x4 acc[2][2] = {{z, z}, {z, z}};
  const u16* Ap = A + (size_t)(m0 + lr) * lda + lc;
  const u16* Bp = B + (size_t)(n0 + lr) * ldb + lc;
  for (int k0 = 0; k0 < K; k0 += 32) {
    int4 av = *(const int4*)(Ap + k0);
    int4 bv = *(const int4*)(Bp + k0);
    __syncthreads();
    *(int4*)(As + lr * 40 + lc) = av;
    *(int4*)(Bs + lr * 40 + lc) = bv;
    __syncthreads();
#pragma unroll
    for (int mi = 0; mi < 2; mi++) {
      bf16x8 af = *(const bf16x8*)(As + (wr * 32 + mi * 16 + (lane & 15)) * 40 + (lane >> 4) * 8);
#pragma unroll
      for (int ni = 0; ni < 2; ni++) {
        bf16x8 bf = *(const bf16x8*)(Bs + (wc * 32 + ni * 16 + (lane & 15)) * 40 + (lane >> 4) * 8);
        acc[mi][ni] = MFMA16(af, bf, acc[mi][ni]);
      }
    }
  }
#pragma unroll
  for (int mi = 0; mi < 2; mi++)
#pragma unroll
    for (int ni = 0; ni < 2; ni++) {
      int n = n0 + wc * 32 + ni * 16 + (lane & 15);
      float bs = bias ? bias[n] : 0.f;
#pragma unroll
      for (int r = 0; r < 4; r++) {
        int m = m0 + wr * 32 + mi * 16 + (lane >> 4) * 4 + r;
        float x = acc[mi][ni][r] + bs;
        if (relu) x = fmaxf(x, 0.f);
        C[(size_t)m * ldc + n] = f2bf(x);
      }
    }
}

// ---------------- final projection ----------------
__global__ __launch_bounds__(256) void out_proj(const u16* __restrict__ zs, const u16* __restrict__ Wb,
                                                const float* __restrict__ bout, float* __restrict__ out) {
  int wv = threadIdx.x >> 6, lane = threadIdx.x & 63;
  int tile = blockIdx.x * 4 + wv;  // 5120 tiles = 1024 m-tiles x 5 n-tiles
  int mt = tile / 5, nt = tile - mt * 5;
  int m0 = mt * 16, n0 = nt * 16;
  const u16* ap = zs + (size_t)(m0 + (lane & 15)) * 1024 + (lane >> 4) * 8;
  const u16* bp = Wb + (size_t)(n0 + (lane & 15)) * 1024 + (lane >> 4) * 8;
  f32x4 acc = {0.f, 0.f, 0.f, 0.f};
  for (int k = 0; k < 1024; k += 32) {
    bf16x8 a = *(const bf16x8*)(ap + k);
    bf16x8 b = *(const bf16x8*)(bp + k);
    acc = MFMA16(a, b, acc);
  }
  int n = n0 + (lane & 15);
  float bb = bout[n];
#pragma unroll
  for (int r = 0; r < 4; r++) {
    int m = m0 + (lane >> 4) * 4 + r;
    int t = m >> 4, b = m & 15;
    out[(size_t)b * 81920 + t * 80 + n] = acc[r] + bb;
  }
}

// ---------------- persistent recurrent kernel ----------------
struct RecP {
  const u16 *g0, *whh0b, *wih1b, *whh1b, *wp0b, *wp1b;
  const float *b1s, *bp0, *bp1, *lng0, *lnb0, *lng1, *lnb1;
  u16 *zs, *za_all, *hall;  // hall row t (131072B): h0 @u16+0, h1 @u16+16384, zb @u16+32768
  int *ctr0, *ctr1;         // per-group arrival counters (monotone)
};

#define SLICE 1032
#define OFF_PARTIAL 132096
#define OFF_GATES 140288
#define OFF_RED1 142336
#define OFF_RED2 143360
#define OFF_MUSIG 144384
#define OFF_C 144512
#define OFF_G0S 145024  // 512 u16 (4 gates x 16 b x 8 cols)
#define OFF_HT 146048   // 128 u16 pack tile
#define SMEM_BYTES 146304

__global__ __launch_bounds__(256, 1) void recurrent(RecP p) {
  extern __shared__ char smem[];
  u16* wA = (u16*)smem;       // l0: Whh0 slice (32 rows) | l1: Wih1 slice
  u16* wB = wA + 32 * SLICE;  // l0: Wp0 slice (16 rows, 8 real) | l1: Whh1 slice
  float* partial = (float*)(smem + OFF_PARTIAL);  // 2048 f
  float* gates2 = (float*)(smem + OFF_GATES);     // 512 f
  float* red1 = (float*)(smem + OFF_RED1);        // 256 f
  float* red2 = (float*)(smem + OFF_RED2);        // 256 f
  float* musig = (float*)(smem + OFF_MUSIG);      // 32 f
  float* cs = (float*)(smem + OFF_C);             // 128 f
  u16* g0s = (u16*)(smem + OFF_G0S);              // 512 u16
  u16* htile = (u16*)(smem + OFF_HT);             // 128 u16

  const int w = blockIdx.x, tid = threadIdx.x;
  const int lane = tid & 63, wv = tid >> 6;
  const int bl = lane & 15, q = lane >> 4;
  const bool grp0 = (w < 128);
  const int wl = grp0 ? w : (w - 128);
  int* ctr = grp0 ? p.ctr0 : p.ctr1;

  // ---- stage weights (once). WG owns hidden cols 8*wl..8*wl+7.
  {
    int r = tid >> 3, kp = tid & 7;  // 32 rows, 8 threads/row
    int gN = (r >> 3) * 1024 + (wl << 3) + (r & 7);
    const u16* srcA = grp0 ? p.whh0b : p.wih1b;
#pragma unroll
    for (int i = 0; i < 16; i++) {
      int k = kp * 128 + i * 8;
      *(int4*)(wA + r * SLICE + k) = *(const int4*)(srcA + (size_t)gN * 1024 + k);
    }
    if (!grp0) {
#pragma unroll
      for (int i = 0; i < 16; i++) {
        int k = kp * 128 + i * 8;
        *(int4*)(wB + r * SLICE + k) = *(const int4*)(p.whh1b + (size_t)gN * 1024 + k);
      }
    } else {
      int r2 = tid >> 4, kp2 = tid & 15;  // 16 rows (8 real + 8 zero), 16 thr/row
      int4 z4 = make_int4(0, 0, 0, 0);
#pragma unroll
      for (int i = 0; i < 8; i++) {
        int k = kp2 * 64 + i * 8;
        int4 v = z4;
        if (r2 < 8) v = *(const int4*)(p.wp0b + (size_t)((wl << 3) + r2) * 1024 + k);
        *(int4*)(wB + r2 * SLICE + k) = v;
      }
    }
    if (tid < 128) cs[tid] = 0.f;
  }
  __syncthreads();

  // per-thread invariants
  const int nl0 = tid >> 4, be = tid & 15;
  const int gN0 = (nl0 >> 3) * 1024 + (wl << 3) + (nl0 & 7);
  const int gN1 = ((nl0 + 16) >> 3) * 1024 + (wl << 3) + ((nl0 + 16) & 7);
  const float bp0v = p.bp0[(wl << 3) + ((tid >> 4) & 7)];
  const float bp1v = p.bp1[(wl << 3) + ((tid >> 4) & 7)];
  const float b1a = p.b1s[gN0], b1b = p.b1s[gN1];
  // g0s read indices (gate group from nl0; col nl0&7; batch be)
  const int g0i0 = (((nl0 >> 3) << 4) + be) * 8 + (nl0 & 7);
  const int g0i1 = ((((nl0 >> 3) + 2) << 4) + be) * 8 + (nl0 & 7);

  if (grp0) {
    // ================= layer 0 =================
    i32x4 gcur = {0, 0, 0, 0}, gnext = {0, 0, 0, 0};
    if (tid < 64) {  // tile load: thread (g,b) -> 8 cols of gate-group g
      int g = tid >> 4, b = tid & 15;
      const u16* gp = p.g0 + (size_t)b * 4096 + g * 1024 + (wl << 3);
      asm volatile("global_load_dwordx4 %0, %1, off sc0 sc1\n\ts_waitcnt vmcnt(0)"
                   : "=&v"(gcur)
                   : "v"((const void*)gp)
                   : "memory");
    }

    for (int t = 0; t < 1024; ++t) {
      u16* hx0 = p.hall + (size_t)t * 65536;  // h0 stream row t

      // ---- S1: gates0 = G0[t] + za(t-1) @ Whh0^T ; cell0 -> h0
      if (t > 0) {
        const u16* zap = p.za_all + (size_t)(t - 1) * 16384 + bl * 1024 + (wv << 8) + (q << 3);
        bf16x8 av[8];
        load8s(av, zap);
        f32x4 acc0 = {0.f, 0.f, 0.f, 0.f}, acc1 = acc0;
#pragma unroll
        for (int c = 0; c < 8; c++) {
          int k = (wv << 8) + (c << 5) + (q << 3);
          acc0 = MFMA16(av[c], *(const bf16x8*)(wA + bl * SLICE + k), acc0);
          acc1 = MFMA16(av[c], *(const bf16x8*)(wA + (16 + bl) * SLICE + k), acc1);
        }
        *(f32x4*)(partial + (wv << 9) + (bl << 4) + (q << 2)) = acc0;
        *(f32x4*)(partial + (wv << 9) + ((16 + bl) << 4) + (q << 2)) = acc1;
      }
      if (tid < 64) *(i32x4*)(g0s + (tid << 3)) = gcur;  // distribute g0 tile
      if (t < 1023 && tid < 64) {                         // prefetch next (cbar's vmcnt drains)
        int g = tid >> 4, b = tid & 15;
        const u16* gp = p.g0 + (size_t)(((t + 1) << 4) | b) * 4096 + g * 1024 + (wl << 3);
        asm volatile("global_load_dwordx4 %0, %1, off sc0 sc1"
                     : "=&v"(gnext)
                     : "v"((const void*)gp)
                     : "memory");
      }
      __syncthreads();
      {
        float s0 = bf2f(g0s[g0i0]), s1 = bf2f(g0s[g0i1]);
        if (t > 0) {
          int e0 = tid, e1 = tid + 256;
          s0 += partial[e0] + partial[512 + e0] + partial[1024 + e0] + partial[1536 + e0];
          s1 += partial[e1] + partial[512 + e1] + partial[1024 + e1] + partial[1536 + e1];
        }
        gates2[tid] = s0;
        gates2[tid + 256] = s1;
      }
      __syncthreads();
      if (tid < 128) {
        int jj = tid >> 4, b = tid & 15;
        float xi = gates2[(jj)*16 + b];
        float xf = gates2[(8 + jj) * 16 + b];
        float xg = gates2[(16 + jj) * 16 + b];
        float xo = gates2[(24 + jj) * 16 + b];
        float c = cs[tid];
        float cn = sigf(xf) * c + sigf(xi) * tanhf(xg);
        cs[tid] = cn;
        htile[(b << 3) + jj] = f2bf(sigf(xo) * tanhf(cn));
      }
      __syncthreads();
      if (tid < 16) gstore128(hx0 + tid * 1024 + (wl << 3), *(const i32x4*)(htile + (tid << 3)));
      cbar(ctr, 2 * t + 1, tid);

      // ---- S2: za(t) = tanh(LN(h0) @ Wp0^T + bp0)
      {
        bf16x8 dv[8];
        load8s(dv, hx0 + bl * 1024 + (wv << 8) + (q << 3));
        float sm = 0.f, sq = 0.f;
#pragma unroll
        for (int i = 0; i < 8; i++)
#pragma unroll
          for (int j = 0; j < 8; j++) {
            float x = bf2f((u16)dv[i][j]);
            sm += x;
            sq += x * x;
          }
        red1[(bl << 4) + (wv << 2) + q] = sm;  // dv fragments tile the full row per bl
        red2[(bl << 4) + (wv << 2) + q] = sq;
        __syncthreads();
        if (tid < 64) {
          int b2 = tid >> 2, g2 = tid & 3;
          float s = red1[b2 * 16 + g2 * 4] + red1[b2 * 16 + g2 * 4 + 1] + red1[b2 * 16 + g2 * 4 + 2] +
                    red1[b2 * 16 + g2 * 4 + 3];
          float qq = red2[b2 * 16 + g2 * 4] + red2[b2 * 16 + g2 * 4 + 1] + red2[b2 * 16 + g2 * 4 + 2] +
                     red2[b2 * 16 + g2 * 4 + 3];
          s += __shfl_xor(s, 1);
          s += __shfl_xor(s, 2);
          qq += __shfl_xor(qq, 1);
          qq += __shfl_xor(qq, 2);
          if (g2 == 0) {
            float mu = s * (1.f / 1024.f);
            float var = qq * (1.f / 1024.f) - mu * mu;
            musig[b2] = mu;
            musig[16 + b2] = rsqrtf(var + 1e-5f);
          }
        }
        __syncthreads();
        float mu = musig[bl], rs = musig[16 + bl];
        f32x4 acc = {0.f, 0.f, 0.f, 0.f};
#pragma unroll
        for (int c = 0; c < 8; c++) {
          int k = (wv << 8) + (c << 5) + (q << 3);
          float4 ga = *(const float4*)(p.lng0 + k);
          float4 gb = *(const float4*)(p.lng0 + k + 4);
          float4 ba = *(const float4*)(p.lnb0 + k);
          float4 bb = *(const float4*)(p.lnb0 + k + 4);
          bf16x8 a;
          a[0] = (short)f2bf((bf2f((u16)dv[c][0]) - mu) * rs * ga.x + ba.x);
          a[1] = (short)f2bf((bf2f((u16)dv[c][1]) - mu) * rs * ga.y + ba.y);
          a[2] = (short)f2bf((bf2f((u16)dv[c][2]) - mu) * rs * ga.z + ba.z);
          a[3] = (short)f2bf((bf2f((u16)dv[c][3]) - mu) * rs * ga.w + ba.w);
          a[4] = (short)f2bf((bf2f((u16)dv[c][4]) - mu) * rs * gb.x + bb.x);
          a[5] = (short)f2bf((bf2f((u16)dv[c][5]) - mu) * rs * gb.y + bb.y);
          a[6] = (short)f2bf((bf2f((u16)dv[c][6]) - mu) * rs * gb.z + bb.z);
          a[7] = (short)f2bf((bf2f((u16)dv[c][7]) - mu) * rs * gb.w + bb.w);
          acc = MFMA16(a, *(const bf16x8*)(wB + bl * SLICE + k), acc);
        }
        *(f32x4*)(partial + (wv << 8) + (bl << 4) + (q << 2)) = acc;
      }
      __syncthreads();
      if (tid < 128) {
        int nl = tid >> 4, b = tid & 15;
        float s = partial[nl * 16 + b] + partial[256 + nl * 16 + b] + partial[512 + nl * 16 + b] +
                  partial[768 + nl * 16 + b] + bp0v;
        htile[(b << 3) + nl] = f2bf(tanhf(s));
      }
      __syncthreads();
      if (tid < 16)
        gstore128(p.za_all + (size_t)t * 16384 + tid * 1024 + (wl << 3), *(const i32x4*)(htile + (tid << 3)));
      cbar(ctr, 2 * t + 2, tid);
      gcur = gnext;
    }
  } else {
    // ================= layer 1 =================
    for (int t = 0; t < 1024; ++t) {
      u16* hx = p.hall + (size_t)t * 65536;       // h1 @u16+16384, zb @u16+32768
      wait_c(p.ctr0, (2 * t + 2) << 7, tid);      // za(t) published by layer0

      // ---- S3: gates1 = za(t) @ Wih1^T + zb(t-1) @ Whh1^T + b ; cell1 -> h1
      {
        const u16* zap = p.za_all + (size_t)t * 16384 + bl * 1024 + (wv << 8) + (q << 3);
        bf16x8 a1[8];
        load8s(a1, zap);
        f32x4 acc0 = {0.f, 0.f, 0.f, 0.f}, acc1 = acc0;
        if (t > 0) {
          const u16* zbp = p.hall + (size_t)(t - 1) * 65536 + 32768 + bl * 1024 + (wv << 8) + (q << 3);
          bf16x8 a2[8];
          load8s(a2, zbp);
#pragma unroll
          for (int c = 0; c < 8; c++) {
            int k = (wv << 8) + (c << 5) + (q << 3);
            acc0 = MFMA16(a1[c], *(const bf16x8*)(wA + bl * SLICE + k), acc0);
            acc1 = MFMA16(a1[c], *(const bf16x8*)(wA + (16 + bl) * SLICE + k), acc1);
            acc0 = MFMA16(a2[c], *(const bf16x8*)(wB + bl * SLICE + k), acc0);
            acc1 = MFMA16(a2[c], *(const bf16x8*)(wB + (16 + bl) * SLICE + k), acc1);
          }
        } else {
#pragma unroll
          for (int c = 0; c < 8; c++) {
            int k = (wv << 8) + (c << 5) + (q << 3);
            acc0 = MFMA16(a1[c], *(const bf16x8*)(wA + bl * SLICE + k), acc0);
            acc1 = MFMA16(a1[c], *(const bf16x8*)(wA + (16 + bl) * SLICE + k), acc1);
          }
        }
        *(f32x4*)(partial + (wv << 9) + (bl << 4) + (q << 2)) = acc0;
        *(f32x4*)(partial + (wv << 9) + ((16 + bl) << 4) + (q << 2)) = acc1;
      }
      __syncthreads();
      {
        int e0 = tid, e1 = tid + 256;
        float s0 = partial[e0] + partial[512 + e0] + partial[1024 + e0] + partial[1536 + e0] + b1a;
        float s1 = partial[e1] + partial[512 + e1] + partial[1024 + e1] + partial[1536 + e1] + b1b;
        gates2[e0] = s0;
        gates2[e1] = s1;
      }
      __syncthreads();
      if (tid < 128) {
        int jj = tid >> 4, b = tid & 15;
        float xi = gates2[(jj)*16 + b];
        float xf = gates2[(8 + jj) * 16 + b];
        float xg = gates2[(16 + jj) * 16 + b];
        float xo = gates2[(24 + jj) * 16 + b];
        float c = cs[tid];
        float cn = sigf(xf) * c + sigf(xi) * tanhf(xg);
        cs[tid] = cn;
        htile[(b << 3) + jj] = f2bf(sigf(xo) * tanhf(cn));
      }
      __syncthreads();
      if (tid < 16) gstore128(hx + 16384 + tid * 1024 + (wl << 3), *(const i32x4*)(htile + (tid << 3)));
      cbar(ctr, 2 * t + 1, tid);

      // ---- S4: zb(t) = tanh(LN(h1) @ Wp1^T + bp1) ; zs[t] = zb
      {
        const u16* h1p = hx + 16384;
        bf16x8 dv[8];
        load8s(dv, h1p + bl * 1024 + (wv << 8) + (q << 3));
        float sm = 0.f, sq = 0.f;
#pragma unroll
        for (int i = 0; i < 8; i++)
#pragma unroll
          for (int j = 0; j < 8; j++) {
            float x = bf2f((u16)dv[i][j]);
            sm += x;
            sq += x * x;
          }
        red1[(bl << 4) + (wv << 2) + q] = sm;
        red2[(bl << 4) + (wv << 2) + q] = sq;
        __syncthreads();
        if (tid < 64) {
          int b2 = tid >> 2, g2 = tid & 3;
          float s = red1[b2 * 16 + g2 * 4] + red1[b2 * 16 + g2 * 4 + 1] + red1[b2 * 16 + g2 * 4 + 2] +
                    red1[b2 * 16 + g2 * 4 + 3];
          float qq = red2[b2 * 16 + g2 * 4] + red2[b2 * 16 + g2 * 4 + 1] + red2[b2 * 16 + g2 * 4 + 2] +
                     red2[b2 * 16 + g2 * 4 + 3];
          s += __shfl_xor(s, 1);
          s += __shfl_xor(s, 2);
          qq += __shfl_xor(qq, 1);
          qq += __shfl_xor(qq, 2);
          if (g2 == 0) {
            float mu = s * (1.f / 1024.f);
            float var = qq * (1.f / 1024.f) - mu * mu;
            musig[b2] = mu;
            musig[16 + b2] = rsqrtf(var + 1e-5f);
          }
        }
        __syncthreads();
        float mu = musig[bl], rs = musig[16 + bl];
        f32x4 acc = {0.f, 0.f, 0.f, 0.f};
        const u16* wpp = p.wp1b + (size_t)((wl << 3) + (bl & 7)) * 1024;  // plain loads, L2-hot
        bf16x8 z8 = {0, 0, 0, 0, 0, 0, 0, 0};
#pragma unroll
        for (int c = 0; c < 8; c++) {
          int k = (wv << 8) + (c << 5) + (q << 3);
          float4 ga = *(const float4*)(p.lng1 + k);
          float4 gb = *(const float4*)(p.lng1 + k + 4);
          float4 ba = *(const float4*)(p.lnb1 + k);
          float4 bb = *(const float4*)(p.lnb1 + k + 4);
          bf16x8 a;
          a[0] = (short)f2bf((bf2f((u16)dv[c][0]) - mu) * rs * ga.x + ba.x);
          a[1] = (short)f2bf((bf2f((u16)dv[c][1]) - mu) * rs * ga.y + ba.y);
          a[2] = (short)f2bf((bf2f((u16)dv[c][2]) - mu) * rs * ga.z + ba.z);
          a[3] = (short)f2bf((bf2f((u16)dv[c][3]) - mu) * rs * ga.w + ba.w);
          a[4] = (short)f2bf((bf2f((u16)dv[c][4]) - mu) * rs * gb.x + bb.x);
          a[5] = (short)f2bf((bf2f((u16)dv[c][5]) - mu) * rs * gb.y + bb.y);
          a[6] = (short)f2bf((bf2f((u16)dv[c][6]) - mu) * rs * gb.z + bb.z);
          a[7] = (short)f2bf((bf2f((u16)dv[c][7]) - mu) * rs * gb.w + bb.w);
          bf16x8 bw = *(const bf16x8*)(wpp + k);
          if (bl >= 8) bw = z8;
          acc = MFMA16(a, bw, acc);
        }
        *(f32x4*)(partial + (wv << 8) + (bl << 4) + (q << 2)) = acc;
      }
      __syncthreads();
      if (tid < 128) {
        int nl = tid >> 4, b = tid & 15;
        float s = partial[nl * 16 + b] + partial[256 + nl * 16 + b] + partial[512 + nl * 16 + b] +
                  partial[768 + nl * 16 + b] + bp1v;
        htile[(b << 3) + nl] = f2bf(tanhf(s));
      }
      __syncthreads();
      if (tid < 16) {
        i32x4 v = *(const i32x4*)(htile + (tid << 3));
        gstore128(hx + 32768 + tid * 1024 + (wl << 3), v);                  // zb stream row t
        *(i32x4*)(p.zs + (size_t)((t << 4) | tid) * 1024 + (wl << 3)) = v;  // plain: post-kernel
      }
      cbar(ctr, 2 * t + 2, tid);
    }
  }
}

// ---------------- host ----------------
extern "C" void kernel_launch(void* const* d_in, const int* in_sizes, int n_in, void* d_out, int out_size,
                              void* d_ws, size_t ws_size, hipStream_t stream) {
  const float* cond = (const float*)d_in[0];
  const float* targets = (const float*)d_in[1];
  const float* tmean = (const float*)d_in[2];
  const float* tscale = (const float*)d_in[3];
  const float* Wpre1 = (const float*)d_in[4];
  const float* bpre1 = (const float*)d_in[5];
  const float* Wpre2 = (const float*)d_in[6];
  const float* bpre2 = (const float*)d_in[7];
  const float* Wih0 = (const float*)d_in[8];
  const float* Whh0 = (const float*)d_in[9];
  const float* bih0 = (const float*)d_in[10];
  const float* bhh0 = (const float*)d_in[11];
  const float* lng0 = (const float*)d_in[12];
  const float* lnb0 = (const float*)d_in[13];
  const float* Wp0 = (const float*)d_in[14];
  const float* bp0 = (const float*)d_in[15];
  const float* Wih1 = (const float*)d_in[16];
  const float* Whh1 = (const float*)d_in[17];
  const float* bih1 = (const float*)d_in[18];
  const float* bhh1 = (const float*)d_in[19];
  const float* lng1 = (const float*)d_in[20];
  const float* lnb1 = (const float*)d_in[21];
  const float* Wp1 = (const float*)d_in[22];
  const float* bp1 = (const float*)d_in[23];
  const float* Wout = (const float*)d_in[24];
  const float* bout = (const float*)d_in[25];

  char* ws = (char*)d_ws;
  int* ctr0 = (int*)(ws + 0);    // own 64B line
  int* ctr1 = (int*)(ws + 128);  // own 64B line
  float* b0s = (float*)(ws + 102400);  // bih0+bhh0 (16KB)
  float* b1s = (float*)(ws + 118784);  // bih1+bhh1 (16KB)
  u16* woutb = (u16*)(ws + 135168);    // 160KB
  u16* wpre1b = (u16*)(ws + 299008);
  u16* wpre2b = (u16*)(ws + 348160);
  u16* wih0b = (u16*)(ws + 479232);
  u16* whh0b = (u16*)(ws + 6770688);
  u16* wih1b = (u16*)(ws + 15159296);
  u16* whh1b = (u16*)(ws + 23547904);
  u16* wp0b = (u16*)(ws + 31936512);
  u16* wp1b = (u16*)(ws + 34033664);
  u16* prevp = (u16*)(ws + 36130816);   // (T*B,96)  -- prep-only
  u16* hpre = (u16*)(ws + 39276544);    // (T*B,256) -- prep-only
  u16* xall = (u16*)(ws + 47665152);    // (T*B,768) -- prep-only
  u16* g0 = (u16*)(ws + 72830976);      // (T*B,4096)
  u16* zs = (u16*)(ws + 207048704);     // (T*B,1024)
  u16* za_all = (u16*)(ws + 36130816);  // 1024 x 32KB -- overlays prep buffers (dead by then)
  u16* hall = (u16*)(ws + 72699904);    // row t = g0 row t-1 (128KB, consumed at t-1)

  hipMemsetAsync(ws, 0, 4096, stream);  // counters

  cvt_wpre1<<<96, 256, 0, stream>>>(Wpre1, wpre1b);
  cvt<<<64, 256, 0, stream>>>(Wpre2, wpre2b, 65536);
  cvt<<<3072, 256, 0, stream>>>(Wih0, wih0b, 3145728);
  cvt<<<4096, 256, 0, stream>>>(Whh0, whh0b, 4194304);
  cvt<<<4096, 256, 0, stream>>>(Wih1, wih1b, 4194304);
  cvt<<<4096, 256, 0, stream>>>(Whh1, whh1b, 4194304);
  cvt<<<1024, 256, 0, stream>>>(Wp0, wp0b, 1048576);
  cvt<<<1024, 256, 0, stream>>>(Wp1, wp1b, 1048576);
  cvt<<<80, 256, 0, stream>>>(Wout, woutb, 81920);
  bsum<<<16, 256, 0, stream>>>(bih0, bhh0, b0s);
  bsum<<<16, 256, 0, stream>>>(bih1, bhh1, b1s);
  pack_prev<<<6144, 256, 0, stream>>>(targets, tmean, tscale, prevp);
  pack_cond<<<8192, 256, 0, stream>>>(cond, xall);

  gemm_bt<<<dim3(256, 4), 256, 0, stream>>>(prevp, 96, wpre1b, 96, hpre, 256, bpre1, 96, 1);
  gemm_bt<<<dim3(256, 4), 256, 0, stream>>>(hpre, 256, wpre2b, 256, xall + 512, 768, bpre2, 256, 1);
  gemm_bt<<<dim3(256, 64), 256, 0, stream>>>(xall, 768, wih0b, 768, g0, 4096, b0s, 768, 0);

  RecP rp;
  rp.g0 = g0;
  rp.whh0b = whh0b;
  rp.wih1b = wih1b;
  rp.whh1b = whh1b;
  rp.wp0b = wp0b;
  rp.wp1b = wp1b;
  rp.b1s = b1s;
  rp.bp0 = bp0;
  rp.bp1 = bp1;
  rp.lng0 = lng0;
  rp.lnb0 = lnb0;
  rp.lng1 = lng1;
  rp.lnb1 = lnb1;
  rp.zs = zs;
  rp.za_all = za_all;
  rp.hall = hall;
  rp.ctr0 = ctr0;
  rp.ctr1 = ctr1;

  hipFuncSetAttribute(reinterpret_cast<const void*>(recurrent), hipFuncAttributeMaxDynamicSharedMemorySize,
                      SMEM_BYTES);
  recurrent<<<dim3(256), dim3(256), SMEM_BYTES, stream>>>(rp);

  out_proj<<<1280, 256, 0, stream>>>(zs, woutb, bout, (float*)d_out);
}